// Round 8
// baseline (621.588 us; speedup 1.0000x reference)
//
#include <hip/hip_runtime.h>
#include <hip/hip_bf16.h>
#include <cstddef>

#define SEQ 2048
#define DM  512
#define DI  1024   // d_inner
#define DR  32     // dt_rank
#define DS  64     // d_state
#define NCHUNK 8
#define CHUNK  256 // SEQ / NCHUNK

typedef __attribute__((ext_vector_type(4))) float f32x4;
typedef __attribute__((ext_vector_type(8))) short frag8;

// round-to-nearest-even f32 -> bf16 (finite inputs)
__device__ __forceinline__ short f2bf(float f) {
    unsigned u = __float_as_uint(f);
    unsigned r = (u + 0x7fffu + ((u >> 16) & 1u)) >> 16;
    return (short)r;
}

// p + dpp_permute(p) with compile-time DPP control
template <int CTRL>
__device__ __forceinline__ float dppadd(float p) {
    return p + __int_as_float(
        __builtin_amdgcn_update_dpp(0, __float_as_int(p), CTRL, 0xF, 0xF, true));
}

// ---------------- LayerNorm: one block (256 thr) per token ----------------
__global__ void ln_kernel(const float* __restrict__ x, const float* __restrict__ g,
                          const float* __restrict__ b, float* __restrict__ xn) {
    int l = blockIdx.x;
    int t = threadIdx.x;
    __shared__ float red[256];
    float v0 = x[l * DM + t];
    float v1 = x[l * DM + t + 256];
    red[t] = v0 + v1;
    __syncthreads();
    for (int o = 128; o > 0; o >>= 1) { if (t < o) red[t] += red[t + o]; __syncthreads(); }
    float mu = red[0] * (1.f / DM);
    __syncthreads();
    float c0 = v0 - mu, c1 = v1 - mu;
    red[t] = c0 * c0 + c1 * c1;
    __syncthreads();
    for (int o = 128; o > 0; o >>= 1) { if (t < o) red[t] += red[t + o]; __syncthreads(); }
    float rstd = rsqrtf(red[0] * (1.f / DM) + 1e-5f);
    xn[l * DM + t]       = c0 * rstd * g[t]       + b[t];
    xn[l * DM + t + 256] = c1 * rstd * g[t + 256] + b[t + 256];
}

// ---------------- MFMA GEMM: C[M,N] = A[M,K] * B[N,K]^T -------------------
// Tile 128x64, BK=32, 256 thr = 4 waves, each wave 64x32 (4x2 tiles of 16x16).
// M multiple of 128; N guarded. EPI: 0=store, 1=silu(v), 2=v+residual.
// TOUT: store transposed out[n*ldo + m] as float4 (4 consecutive m = 4 acc regs).
#define LDK 40   // padded row length (shorts)
template <int EPI, bool TOUT>
__global__ void gemm_mfma(const float* __restrict__ A, int lda,
                          const float* __restrict__ B, int ldb,
                          int N, int K,
                          float* __restrict__ out,
                          const float* __restrict__ res, int ldo) {
    __shared__ short As[128 * LDK];
    __shared__ short Bs[64 * LDK];
    int t = threadIdx.x;
    int lane = t & 63;
    int wv = t >> 6;
    int wm = (wv >> 1) * 64;
    int wn = (wv & 1) * 32;
    int m0 = blockIdx.x * 128, n0 = blockIdx.y * 64;

    f32x4 acc[4][2];
#pragma unroll
    for (int i = 0; i < 4; i++)
#pragma unroll
        for (int j = 0; j < 2; j++) acc[i][j] = (f32x4){0.f, 0.f, 0.f, 0.f};

    int lm = lane & 15;
    int kq = (lane >> 4) * 8;

    for (int k0 = 0; k0 < K; k0 += 32) {
#pragma unroll
        for (int j = 0; j < 4; j++) {
            int c = t + j * 256;
            int m = c >> 3;
            int k = (c & 7) * 4;
            float4 v = *(const float4*)(A + (size_t)(m0 + m) * lda + k0 + k);
            short4 s = make_short4(f2bf(v.x), f2bf(v.y), f2bf(v.z), f2bf(v.w));
            *(short4*)(&As[m * LDK + k]) = s;
        }
#pragma unroll
        for (int j = 0; j < 2; j++) {
            int c = t + j * 256;
            int n = c >> 3;
            int k = (c & 7) * 4;
            short4 s = make_short4(0, 0, 0, 0);
            int gn = n0 + n;
            if (gn < N) {
                float4 v = *(const float4*)(B + (size_t)gn * ldb + k0 + k);
                s = make_short4(f2bf(v.x), f2bf(v.y), f2bf(v.z), f2bf(v.w));
            }
            *(short4*)(&Bs[n * LDK + k]) = s;
        }
        __syncthreads();

        frag8 af[4], bfr[2];
#pragma unroll
        for (int mt = 0; mt < 4; mt++)
            af[mt] = *(const frag8*)(&As[(wm + mt * 16 + lm) * LDK + kq]);
#pragma unroll
        for (int nt = 0; nt < 2; nt++)
            bfr[nt] = *(const frag8*)(&Bs[(wn + nt * 16 + lm) * LDK + kq]);
#pragma unroll
        for (int mt = 0; mt < 4; mt++)
#pragma unroll
            for (int nt = 0; nt < 2; nt++)
                acc[mt][nt] = __builtin_amdgcn_mfma_f32_16x16x32_bf16(
                    af[mt], bfr[nt], acc[mt][nt], 0, 0, 0);
        __syncthreads();
    }

    // epilogue: C/D layout col=lane&15, row=(lane>>4)*4+reg
    int rbase = (lane >> 4) * 4;
#pragma unroll
    for (int mt = 0; mt < 4; mt++) {
#pragma unroll
        for (int nt = 0; nt < 2; nt++) {
            int n = n0 + wn + nt * 16 + lm;
            if (n < N) {
                int mb = m0 + wm + mt * 16 + rbase;
                if (TOUT) {
                    float4 o;
#pragma unroll
                    for (int r = 0; r < 4; r++) {
                        float v = acc[mt][nt][r];
                        if (EPI == 1) v = v / (1.f + __expf(-v));
                        (&o.x)[r] = v;
                    }
                    *(float4*)(out + (size_t)n * ldo + mb) = o;
                } else {
#pragma unroll
                    for (int r = 0; r < 4; r++) {
                        float v = acc[mt][nt][r];
                        if (EPI == 1) v = v / (1.f + __expf(-v));
                        else if (EPI == 2) v += res[(size_t)(mb + r) * ldo + n];
                        out[(size_t)(mb + r) * ldo + n] = v;
                    }
                }
            }
        }
    }
}

// ---------------- K-N vector GEMM for dt-proj ------------------------------
// deltaT[m][n] = softplus( sum_k Wdt[m][k] * dbcT[k][n] + bdt[m] )
// m over DI (channels), n over SEQ, K = DR = 32.
__global__ void gemm_dt_kn(const float* __restrict__ A,   // Wdt [DI][DR]
                           const float* __restrict__ Bm,  // dbcT rows 0..DR-1, ld SEQ
                           const float* __restrict__ bias,
                           float* __restrict__ outT) {    // deltaT [DI][SEQ]
    __shared__ float As[16][65];  // [k][m]
    __shared__ float Bs[16][65];  // [k][n]
    int tid = threadIdx.x;
    int tx = tid & 15, ty = tid >> 4;
    int bm = blockIdx.x * 64, bn = blockIdx.y * 64;
    float acc[4][4] = {};
    for (int k0 = 0; k0 < DR; k0 += 16) {
        {
            int kk = tid & 15, mm = tid >> 4;
#pragma unroll
            for (int i = 0; i < 4; i++)
                As[kk][mm + 16 * i] = A[(size_t)(bm + mm + 16 * i) * DR + k0 + kk];
        }
        {
            int kk = tid >> 4; int nn4 = (tid & 15) * 4;
            float4 v = *(const float4*)(Bm + (size_t)(k0 + kk) * SEQ + bn + nn4);
            Bs[kk][nn4] = v.x; Bs[kk][nn4 + 1] = v.y;
            Bs[kk][nn4 + 2] = v.z; Bs[kk][nn4 + 3] = v.w;
        }
        __syncthreads();
#pragma unroll
        for (int k = 0; k < 16; k++) {
            float a[4], bb[4];
#pragma unroll
            for (int i = 0; i < 4; i++) a[i] = As[k][ty * 4 + i];
#pragma unroll
            for (int j = 0; j < 4; j++) bb[j] = Bs[k][tx * 4 + j];
#pragma unroll
            for (int i = 0; i < 4; i++)
#pragma unroll
                for (int j = 0; j < 4; j++)
                    acc[i][j] = fmaf(a[i], bb[j], acc[i][j]);
        }
        __syncthreads();
    }
#pragma unroll
    for (int i = 0; i < 4; i++) {
        int m = bm + ty * 4 + i;
        float bv = bias[m];
        float4 o;
#pragma unroll
        for (int j = 0; j < 4; j++) {
            float v = acc[i][j] + bv;
            v = (v > 20.f) ? v : __logf(1.f + __expf(v));
            (&o.x)[j] = v;
        }
        *(float4*)(outT + (size_t)m * SEQ + bn + tx * 4) = o;
    }
}

// ---------------- Causal depthwise conv (width 4) + bias + SiLU -----------
__global__ void conv_kernel(const float* __restrict__ xi_raw, const float* __restrict__ w,
                            const float* __restrict__ cb, float* __restrict__ xi2) {
    int idx = blockIdx.x * 256 + threadIdx.x;
    int e = idx & (DI - 1);
    int l = idx >> 10;
    float acc = cb[e];
#pragma unroll
    for (int j = 0; j < 4; j++) {
        int ls = l - 3 + j;
        if (ls >= 0) acc = fmaf(w[e * 4 + j], xi_raw[(size_t)ls * DI + e], acc);
    }
    float sig = 1.f / (1.f + __expf(-acc));
    xi2[idx] = acc * sig;
}

// ---------------- LDS-tiled transpose: in[R][C] -> out[C][R] --------------
__global__ void transpose_kernel(const float* __restrict__ in, float* __restrict__ outp,
                                 int R, int C) {
    __shared__ float tile[64][65];
    int r0 = blockIdx.x * 64, c0 = blockIdx.y * 64;
    int t = threadIdx.x;
    int col4 = (t & 15) * 4;
    int row  = t >> 4;
#pragma unroll
    for (int i = 0; i < 4; i++) {
        int r = row + i * 16;
        float4 v = *(const float4*)(in + (size_t)(r0 + r) * C + c0 + col4);
        tile[r][col4] = v.x; tile[r][col4 + 1] = v.y;
        tile[r][col4 + 2] = v.z; tile[r][col4 + 3] = v.w;
    }
    __syncthreads();
    int r4 = (t & 15) * 4;
    int crow = t >> 4;
#pragma unroll
    for (int i = 0; i < 4; i++) {
        int c = crow + i * 16;
        float4 v = make_float4(tile[r4][c], tile[r4 + 1][c], tile[r4 + 2][c], tile[r4 + 3][c]);
        *(float4*)(outp + (size_t)(c0 + c) * R + r0 + r4) = v;
    }
}

// ---------------- Chunked selective scan (transposed operands) ------------
// Pass A: local scan, h_in = 0. All loads are float4 over 4 consecutive steps.
__global__ void scan_passA(const float* __restrict__ deltaT, const float* __restrict__ xi2T,
                           const float* __restrict__ dbcT, const float* __restrict__ A_log,
                           float* __restrict__ P, float* __restrict__ hend) {
    int wid = blockIdx.x * 4 + (threadIdx.x >> 6);
    int e = wid & (DI - 1);
    int c = wid >> 10;
    int n = threadIdx.x & 63;
    float Ae = -__expf(A_log[e * DS + n]);
    float h = 0.f, sum_d = 0.f;
    int l0 = c * CHUNK;
    const float4* d4 = (const float4*)(deltaT + (size_t)e * SEQ + l0);
    const float4* x4 = (const float4*)(xi2T + (size_t)e * SEQ + l0);
    const float4* B4 = (const float4*)(dbcT + (size_t)(DR + n) * SEQ + l0);
    for (int g = 0; g < CHUNK / 4; g++) {
        float4 dd = d4[g], xx = x4[g], bb = B4[g];
#pragma unroll
        for (int j = 0; j < 4; j++) {
            float dj = (&dd.x)[j];
            float dA = __expf(dj * Ae);
            h = fmaf(dA, h, (dj * (&xx.x)[j]) * (&bb.x)[j]);
            sum_d += dj;
        }
    }
    int idx = (c * DI + e) * DS + n;
    P[idx] = __expf(Ae * sum_d);
    hend[idx] = h;
}

__global__ void scan_carry(float* __restrict__ P, const float* __restrict__ hend) {
    int e = blockIdx.x * 4 + (threadIdx.x >> 6);
    int n = threadIdx.x & 63;
    float h = 0.f;
    for (int c = 0; c < NCHUNK; c++) {
        int idx = (c * DI + e) * DS + n;
        float p  = P[idx];
        float he = hend[idx];
        P[idx] = h;
        h = fmaf(p, h, he);
    }
}

// Pass B: szyT holds silu(z)^T on input; lane 0 overwrites with y^T (float4,
// read-before-write within the owning wave; rows are wave-exclusive per l-range).
__global__ void scan_passB(const float* __restrict__ deltaT, const float* __restrict__ xi2T,
                           const float* __restrict__ dbcT, float* __restrict__ szyT,
                           const float* __restrict__ A_log, const float* __restrict__ Dp,
                           const float* __restrict__ hin) {
    int wid = blockIdx.x * 4 + (threadIdx.x >> 6);
    int e = wid & (DI - 1);
    int c = wid >> 10;
    int n = threadIdx.x & 63;
    float Ae = -__expf(A_log[e * DS + n]);
    float dp = Dp[e];
    float h = hin[(c * DI + e) * DS + n];
    int l0 = c * CHUNK;
    const float4* d4 = (const float4*)(deltaT + (size_t)e * SEQ + l0);
    const float4* x4 = (const float4*)(xi2T + (size_t)e * SEQ + l0);
    float4* s4       = (float4*)(szyT + (size_t)e * SEQ + l0);
    const float4* B4 = (const float4*)(dbcT + (size_t)(DR + n) * SEQ + l0);
    const float4* C4 = (const float4*)(dbcT + (size_t)(DR + DS + n) * SEQ + l0);
    for (int g = 0; g < CHUNK / 4; g++) {
        float4 dd = d4[g], xx = x4[g], zz = s4[g], bb = B4[g], cc = C4[g];
        float4 yv;
#pragma unroll
        for (int j = 0; j < 4; j++) {
            float dj = (&dd.x)[j], xj = (&xx.x)[j];
            float dA = __expf(dj * Ae);
            h = fmaf(dA, h, (dj * xj) * (&bb.x)[j]);
            float p = h * (&cc.x)[j];
            p = dppadd<0xB1>(p);
            p = dppadd<0x4E>(p);
            p = dppadd<0x141>(p);
            p = dppadd<0x140>(p);
            float s1 = __int_as_float(__builtin_amdgcn_readlane(__float_as_int(p), 16));
            float s2 = __int_as_float(__builtin_amdgcn_readlane(__float_as_int(p), 32));
            float s3 = __int_as_float(__builtin_amdgcn_readlane(__float_as_int(p), 48));
            (&yv.x)[j] = (p + s1 + s2 + s3 + dp * xj) * (&zz.x)[j];
        }
        if (n == 0) s4[g] = yv;
    }
}

extern "C" void kernel_launch(void* const* d_in, const int* in_sizes, int n_in,
                              void* d_out, int out_size, void* d_ws, size_t ws_size,
                              hipStream_t stream) {
    const float* x      = (const float*)d_in[0];
    const float* ln_g   = (const float*)d_in[1];
    const float* ln_b   = (const float*)d_in[2];
    const float* Win    = (const float*)d_in[3];
    const float* conv_w = (const float*)d_in[4];
    const float* conv_b = (const float*)d_in[5];
    const float* Wx     = (const float*)d_in[6];
    const float* Wdt    = (const float*)d_in[7];
    const float* bdt    = (const float*)d_in[8];
    const float* A_log  = (const float*)d_in[9];
    const float* Dp     = (const float*)d_in[10];
    const float* Wout   = (const float*)d_in[11];
    float* out = (float*)d_out;

    // Workspace: 30 MB, same footprint as the proven R4/R5/R7 layout.
    float* ws   = (float*)d_ws;
    float* bufA = ws;                            // 1,048,576 f: xn -> dbcT + P
    float* bufB = bufA + (size_t)SEQ * DM;       // 2,097,152 f: xi_raw -> xi2T
    float* bufC = bufB + (size_t)SEQ * DI;       // 2,097,152 f: szT -> yT (in-place)
    float* bufD = bufC + (size_t)SEQ * DI;       // 2,097,152 f: xi2 -> deltaT -> y
    float* hend = bufD + (size_t)SEQ * DI;       //   524,288 f

    float* xn     = bufA;
    float* dbcT   = bufA;                        // [160][SEQ], after xn dies
    float* Pbuf   = bufA + (size_t)160 * SEQ;    // bufA tail
    float* xi_raw = bufB;
    float* xi2T   = bufB;                        // after xi_raw dies
    float* szT    = bufC;
    float* xi2    = bufD;
    float* deltaT = bufD;                        // after xi2 dies
    float* ybuf   = bufD;                        // after deltaT dies

    // 1. LayerNorm
    ln_kernel<<<SEQ, 256, 0, stream>>>(x, ln_g, ln_b, xn);

    // 2a. xi_raw = xn @ Win[0:DI]^T   (normal out [SEQ][DI])
    gemm_mfma<0, false><<<dim3(SEQ / 128, DI / 64), 256, 0, stream>>>(
        xn, DM, Win, DM, DI, DM, xi_raw, nullptr, DI);
    // 2b. szT = silu(xn @ Win[DI:2DI]^T)^T  (transposed out [DI][SEQ])
    gemm_mfma<1, true><<<dim3(SEQ / 128, DI / 64), 256, 0, stream>>>(
        xn, DM, Win + (size_t)DI * DM, DM, DI, DM, szT, nullptr, SEQ);

    // 3. conv + SiLU -> xi2 [SEQ][DI]
    conv_kernel<<<(SEQ * DI) / 256, 256, 0, stream>>>(xi_raw, conv_w, conv_b, xi2);

    // 4. xi2T = xi2^T  (bufB, xi_raw dead)
    transpose_kernel<<<dim3(SEQ / 64, DI / 64), 256, 0, stream>>>(xi2, xi2T, SEQ, DI);

    // 5. dbcT = (xi2 @ Wx^T)^T  [160][SEQ]  (bufA, xn dead)
    gemm_mfma<0, true><<<dim3(SEQ / 128, (160 + 63) / 64), 256, 0, stream>>>(
        xi2, DI, Wx, DI, 160, DI, dbcT, nullptr, SEQ);

    // 6. deltaT = softplus(Wdt @ dbcT[0:32] + bdt)  [DI][SEQ]  (bufD, xi2 dead)
    gemm_dt_kn<<<dim3(DI / 64, SEQ / 64), 256, 0, stream>>>(Wdt, dbcT, bdt, deltaT);

    // 7. chunked scan: A (local) -> carry -> B (y^T in-place over szT)
    scan_passA<<<(DI * NCHUNK) / 4, 256, 0, stream>>>(deltaT, xi2T, dbcT, A_log, Pbuf, hend);
    scan_carry<<<DI / 4, 256, 0, stream>>>(Pbuf, hend);
    scan_passB<<<(DI * NCHUNK) / 4, 256, 0, stream>>>(deltaT, xi2T, dbcT, szT, A_log, Dp, Pbuf);

    // 8. y = yT^T  (bufD, deltaT dead)
    transpose_kernel<<<dim3(DI / 64, SEQ / 64), 256, 0, stream>>>(szT, ybuf, DI, SEQ);

    // 9. out = y @ Wout^T + x  (normal out, fused residual)
    gemm_mfma<2, false><<<dim3(SEQ / 128, DM / 64), 256, 0, stream>>>(
        ybuf, DI, Wout, DI, DM, DI, out, x, DM);
}

// Round 9
// 478.279 us; speedup vs baseline: 1.2996x; 1.2996x over previous
//
#include <hip/hip_runtime.h>
#include <hip/hip_bf16.h>
#include <cstddef>

#define SEQ 2048
#define DM  512
#define DI  1024   // d_inner
#define DR  32     // dt_rank
#define DS  64     // d_state
#define NCHUNK 8
#define CHUNK  256 // SEQ / NCHUNK

typedef __attribute__((ext_vector_type(4))) float f32x4;
typedef __attribute__((ext_vector_type(8))) short frag8;

// round-to-nearest-even f32 -> bf16 (finite inputs)
__device__ __forceinline__ short f2bf(float f) {
    unsigned u = __float_as_uint(f);
    unsigned r = (u + 0x7fffu + ((u >> 16) & 1u)) >> 16;
    return (short)r;
}

// p + dpp_permute(p) with compile-time DPP control (bound_ctrl: invalid -> 0)
template <int CTRL>
__device__ __forceinline__ float dppadd(float p) {
    return p + __int_as_float(
        __builtin_amdgcn_update_dpp(0, __float_as_int(p), CTRL, 0xF, 0xF, true));
}

// ---------------- LayerNorm: one block (256 thr) per token ----------------
__global__ void ln_kernel(const float* __restrict__ x, const float* __restrict__ g,
                          const float* __restrict__ b, float* __restrict__ xn) {
    int l = blockIdx.x;
    int t = threadIdx.x;
    __shared__ float red[256];
    float v0 = x[l * DM + t];
    float v1 = x[l * DM + t + 256];
    red[t] = v0 + v1;
    __syncthreads();
    for (int o = 128; o > 0; o >>= 1) { if (t < o) red[t] += red[t + o]; __syncthreads(); }
    float mu = red[0] * (1.f / DM);
    __syncthreads();
    float c0 = v0 - mu, c1 = v1 - mu;
    red[t] = c0 * c0 + c1 * c1;
    __syncthreads();
    for (int o = 128; o > 0; o >>= 1) { if (t < o) red[t] += red[t + o]; __syncthreads(); }
    float rstd = rsqrtf(red[0] * (1.f / DM) + 1e-5f);
    xn[l * DM + t]       = c0 * rstd * g[t]       + b[t];
    xn[l * DM + t + 256] = c1 * rstd * g[t + 256] + b[t + 256];
}

// ---------------- MFMA GEMM: C[M,N] = A[M,K] * B[N,K]^T -------------------
// Tile 128x64, BK=32, 256 thr = 4 waves, each wave 64x32 (4x2 tiles of 16x16).
// M multiple of 128; N guarded. EPI: 0=store, 1=silu(v), 2=v+residual.
// TOUT: store transposed out[n*ldo + m] as float4 (4 consecutive m = 4 acc regs).
#define LDK 40   // padded row length (shorts)
template <int EPI, bool TOUT>
__global__ void gemm_mfma(const float* __restrict__ A, int lda,
                          const float* __restrict__ B, int ldb,
                          int N, int K,
                          float* __restrict__ out,
                          const float* __restrict__ res, int ldo) {
    __shared__ short As[128 * LDK];
    __shared__ short Bs[64 * LDK];
    int t = threadIdx.x;
    int lane = t & 63;
    int wv = t >> 6;
    int wm = (wv >> 1) * 64;
    int wn = (wv & 1) * 32;
    int m0 = blockIdx.x * 128, n0 = blockIdx.y * 64;

    f32x4 acc[4][2];
#pragma unroll
    for (int i = 0; i < 4; i++)
#pragma unroll
        for (int j = 0; j < 2; j++) acc[i][j] = (f32x4){0.f, 0.f, 0.f, 0.f};

    int lm = lane & 15;
    int kq = (lane >> 4) * 8;

    for (int k0 = 0; k0 < K; k0 += 32) {
#pragma unroll
        for (int j = 0; j < 4; j++) {
            int c = t + j * 256;
            int m = c >> 3;
            int k = (c & 7) * 4;
            float4 v = *(const float4*)(A + (size_t)(m0 + m) * lda + k0 + k);
            short4 s = make_short4(f2bf(v.x), f2bf(v.y), f2bf(v.z), f2bf(v.w));
            *(short4*)(&As[m * LDK + k]) = s;
        }
#pragma unroll
        for (int j = 0; j < 2; j++) {
            int c = t + j * 256;
            int n = c >> 3;
            int k = (c & 7) * 4;
            short4 s = make_short4(0, 0, 0, 0);
            int gn = n0 + n;
            if (gn < N) {
                float4 v = *(const float4*)(B + (size_t)gn * ldb + k0 + k);
                s = make_short4(f2bf(v.x), f2bf(v.y), f2bf(v.z), f2bf(v.w));
            }
            *(short4*)(&Bs[n * LDK + k]) = s;
        }
        __syncthreads();

        frag8 af[4], bfr[2];
#pragma unroll
        for (int mt = 0; mt < 4; mt++)
            af[mt] = *(const frag8*)(&As[(wm + mt * 16 + lm) * LDK + kq]);
#pragma unroll
        for (int nt = 0; nt < 2; nt++)
            bfr[nt] = *(const frag8*)(&Bs[(wn + nt * 16 + lm) * LDK + kq]);
#pragma unroll
        for (int mt = 0; mt < 4; mt++)
#pragma unroll
            for (int nt = 0; nt < 2; nt++)
                acc[mt][nt] = __builtin_amdgcn_mfma_f32_16x16x32_bf16(
                    af[mt], bfr[nt], acc[mt][nt], 0, 0, 0);
        __syncthreads();
    }

    // epilogue: C/D layout col=lane&15, row=(lane>>4)*4+reg
    int rbase = (lane >> 4) * 4;
#pragma unroll
    for (int mt = 0; mt < 4; mt++) {
#pragma unroll
        for (int nt = 0; nt < 2; nt++) {
            int n = n0 + wn + nt * 16 + lm;
            if (n < N) {
                int mb = m0 + wm + mt * 16 + rbase;
                if (TOUT) {
                    float4 o;
#pragma unroll
                    for (int r = 0; r < 4; r++) {
                        float v = acc[mt][nt][r];
                        if (EPI == 1) v = v / (1.f + __expf(-v));
                        (&o.x)[r] = v;
                    }
                    *(float4*)(out + (size_t)n * ldo + mb) = o;
                } else {
#pragma unroll
                    for (int r = 0; r < 4; r++) {
                        float v = acc[mt][nt][r];
                        if (EPI == 1) v = v / (1.f + __expf(-v));
                        else if (EPI == 2) v += res[(size_t)(mb + r) * ldo + n];
                        out[(size_t)(mb + r) * ldo + n] = v;
                    }
                }
            }
        }
    }
}

// ---------------- dt-proj vector GEMM, transposed store --------------------
// deltaT[e][l] = softplus( dbc[l,:32] . Wdt[e,:] + bdt[e] ), out [DI][SEQ].
__global__ void gemm_dt_t(const float* __restrict__ A,   // dbc [SEQ][160]
                          const float* __restrict__ B,   // Wdt [DI][DR]
                          const float* __restrict__ bias,
                          float* __restrict__ outT) {    // deltaT [DI][SEQ]
    __shared__ float As[16][65];
    __shared__ float Bs[16][65];
    int tid = threadIdx.x;
    int tx = tid & 15, ty = tid >> 4;
    int bm = blockIdx.x * 64, bn = blockIdx.y * 64;   // bm: l, bn: e
    float acc[4][4] = {};
    int kk = tid & 15;
    int rr = tid >> 4;
    for (int k0 = 0; k0 < DR; k0 += 16) {
#pragma unroll
        for (int i = 0; i < 4; i++)
            As[kk][rr + 16 * i] = A[(size_t)(bm + rr + 16 * i) * 160 + k0 + kk];
#pragma unroll
        for (int i = 0; i < 4; i++)
            Bs[kk][rr + 16 * i] = B[(size_t)(bn + rr + 16 * i) * DR + k0 + kk];
        __syncthreads();
#pragma unroll
        for (int k = 0; k < 16; k++) {
            float a[4], bb[4];
#pragma unroll
            for (int i = 0; i < 4; i++) a[i] = As[k][ty * 4 + i];
#pragma unroll
            for (int j = 0; j < 4; j++) bb[j] = Bs[k][tx * 4 + j];
#pragma unroll
            for (int i = 0; i < 4; i++)
#pragma unroll
                for (int j = 0; j < 4; j++)
                    acc[i][j] = fmaf(a[i], bb[j], acc[i][j]);
        }
        __syncthreads();
    }
#pragma unroll
    for (int j = 0; j < 4; j++) {
        int e = bn + tx * 4 + j;
        float bv = bias[e];
        float4 o;
#pragma unroll
        for (int i = 0; i < 4; i++) {
            float v = acc[i][j] + bv;
            v = (v > 20.f) ? v : __logf(1.f + __expf(v));
            (&o.x)[i] = v;
        }
        *(float4*)(outT + (size_t)e * SEQ + bm + ty * 4) = o;
    }
}

// ---------------- Causal depthwise conv (width 4) + bias + SiLU -----------
__global__ void conv_kernel(const float* __restrict__ xi_raw, const float* __restrict__ w,
                            const float* __restrict__ cb, float* __restrict__ xi2) {
    int idx = blockIdx.x * 256 + threadIdx.x;
    int e = idx & (DI - 1);
    int l = idx >> 10;
    float acc = cb[e];
#pragma unroll
    for (int j = 0; j < 4; j++) {
        int ls = l - 3 + j;
        if (ls >= 0) acc = fmaf(w[e * 4 + j], xi_raw[(size_t)ls * DI + e], acc);
    }
    float sig = 1.f / (1.f + __expf(-acc));
    xi2[idx] = acc * sig;
}

// ---------------- LDS-tiled transpose: in[R][C] -> out[C][R] --------------
__global__ void transpose_kernel(const float* __restrict__ in, float* __restrict__ outp,
                                 int R, int C) {
    __shared__ float tile[64][65];
    int r0 = blockIdx.x * 64, c0 = blockIdx.y * 64;
    int t = threadIdx.x;
    int col4 = (t & 15) * 4;
    int row  = t >> 4;
#pragma unroll
    for (int i = 0; i < 4; i++) {
        int r = row + i * 16;
        float4 v = *(const float4*)(in + (size_t)(r0 + r) * C + c0 + col4);
        tile[r][col4] = v.x; tile[r][col4 + 1] = v.y;
        tile[r][col4 + 2] = v.z; tile[r][col4 + 3] = v.w;
    }
    __syncthreads();
    int r4 = (t & 15) * 4;
    int crow = t >> 4;
#pragma unroll
    for (int i = 0; i < 4; i++) {
        int c = crow + i * 16;
        float4 v = make_float4(tile[r4][c], tile[r4 + 1][c], tile[r4 + 2][c], tile[r4 + 3][c]);
        *(float4*)(outp + (size_t)(c0 + c) * R + r0 + r4) = v;
    }
}

// ---------------- Chunked selective scan (hybrid layout) ------------------
// deltaT/xi2T/szT: [DI][SEQ] (uniform float4 loads). dbc: [SEQ][160]
// (coalesced per-lane B/C loads, immediate offsets within a 4-step group).
__global__ void scan_passA(const float* __restrict__ deltaT, const float* __restrict__ xi2T,
                           const float* __restrict__ dbc, const float* __restrict__ A_log,
                           float* __restrict__ P, float* __restrict__ hend) {
    int wid = blockIdx.x * 4 + (threadIdx.x >> 6);
    int e = wid & (DI - 1);
    int c = wid >> 10;
    int n = threadIdx.x & 63;
    float Ae = -__expf(A_log[e * DS + n]);
    float h = 0.f, sum_d = 0.f;
    int l0 = c * CHUNK;
    const float4* d4 = (const float4*)(deltaT + (size_t)e * SEQ + l0);
    const float4* x4 = (const float4*)(xi2T + (size_t)e * SEQ + l0);
    const float* dbg = dbc + (size_t)l0 * 160 + DR + n;
    for (int g = 0; g < CHUNK / 4; g++) {
        float4 dd = d4[g], xx = x4[g];
#pragma unroll
        for (int j = 0; j < 4; j++) {
            float Bn = dbg[j * 160];
            float dj = (&dd.x)[j];
            float dA = __expf(dj * Ae);
            h = fmaf(dA, h, (dj * (&xx.x)[j]) * Bn);
            sum_d += dj;
        }
        dbg += 640;
    }
    int idx = (c * DI + e) * DS + n;
    P[idx] = __expf(Ae * sum_d);
    hend[idx] = h;
}

__global__ void scan_carry(float* __restrict__ P, const float* __restrict__ hend) {
    int e = blockIdx.x * 4 + (threadIdx.x >> 6);
    int n = threadIdx.x & 63;
    float h = 0.f;
    for (int c = 0; c < NCHUNK; c++) {
        int idx = (c * DI + e) * DS + n;
        float p  = P[idx];
        float he = hend[idx];
        P[idx] = h;
        h = fmaf(p, h, he);
    }
}

// Pass B: 6-DPP wave64 reduce (quad perms + row mirrors + row_bcast15/31),
// total lands in lane 63, which applies Dp-skip + silu(z) gate and stores y^T.
__global__ void scan_passB(const float* __restrict__ deltaT, const float* __restrict__ xi2T,
                           const float* __restrict__ dbc, float* __restrict__ szyT,
                           const float* __restrict__ A_log, const float* __restrict__ Dp,
                           const float* __restrict__ hin) {
    int wid = blockIdx.x * 4 + (threadIdx.x >> 6);
    int e = wid & (DI - 1);
    int c = wid >> 10;
    int n = threadIdx.x & 63;
    float Ae = -__expf(A_log[e * DS + n]);
    float dp = Dp[e];
    float h = hin[(c * DI + e) * DS + n];
    int l0 = c * CHUNK;
    const float4* d4 = (const float4*)(deltaT + (size_t)e * SEQ + l0);
    const float4* x4 = (const float4*)(xi2T + (size_t)e * SEQ + l0);
    float4* s4       = (float4*)(szyT + (size_t)e * SEQ + l0);
    const float* dbg = dbc + (size_t)l0 * 160 + DR + n;
    for (int g = 0; g < CHUNK / 4; g++) {
        float4 dd = d4[g], xx = x4[g], zz = s4[g];
        float4 yv;
#pragma unroll
        for (int j = 0; j < 4; j++) {
            float Bn = dbg[j * 160];
            float Cn = dbg[j * 160 + DS];
            float dj = (&dd.x)[j], xj = (&xx.x)[j];
            float dA = __expf(dj * Ae);
            h = fmaf(dA, h, (dj * xj) * Bn);
            float p = h * Cn;
            p = dppadd<0xB1>(p);   // quad_perm swap-1
            p = dppadd<0x4E>(p);   // quad_perm swap-2
            p = dppadd<0x141>(p);  // row_half_mirror
            p = dppadd<0x140>(p);  // row_mirror -> full row sums
            p = dppadd<0x142>(p);  // row_bcast15
            p = dppadd<0x143>(p);  // row_bcast31 -> lane 63 = total
            (&yv.x)[j] = (p + dp * xj) * (&zz.x)[j];
        }
        dbg += 640;
        if (n == 63) s4[g] = yv;
    }
}

extern "C" void kernel_launch(void* const* d_in, const int* in_sizes, int n_in,
                              void* d_out, int out_size, void* d_ws, size_t ws_size,
                              hipStream_t stream) {
    const float* x      = (const float*)d_in[0];
    const float* ln_g   = (const float*)d_in[1];
    const float* ln_b   = (const float*)d_in[2];
    const float* Win    = (const float*)d_in[3];
    const float* conv_w = (const float*)d_in[4];
    const float* conv_b = (const float*)d_in[5];
    const float* Wx     = (const float*)d_in[6];
    const float* Wdt    = (const float*)d_in[7];
    const float* bdt    = (const float*)d_in[8];
    const float* A_log  = (const float*)d_in[9];
    const float* Dp     = (const float*)d_in[10];
    const float* Wout   = (const float*)d_in[11];
    float* out = (float*)d_out;

    // Workspace: 30 MB, same footprint as the proven R4/R5/R7/R8 layouts.
    float* ws   = (float*)d_ws;
    float* bufA = ws;                            // 1,048,576 f: xn -> dbc + P
    float* bufB = bufA + (size_t)SEQ * DM;       // 2,097,152 f: xi_raw -> xi2T
    float* bufC = bufB + (size_t)SEQ * DI;       // 2,097,152 f: szT -> yT (in-place)
    float* bufD = bufC + (size_t)SEQ * DI;       // 2,097,152 f: xi2 -> deltaT -> y
    float* hend = bufD + (size_t)SEQ * DI;       //   524,288 f

    float* xn     = bufA;
    float* dbc    = bufA;                        // [SEQ][160], after xn dies
    float* Pbuf   = bufA + (size_t)SEQ * 160;    // bufA tail (327,680 + 524,288 < 1 M)
    float* xi_raw = bufB;
    float* xi2T   = bufB;                        // after xi_raw dies
    float* szT    = bufC;
    float* xi2    = bufD;
    float* deltaT = bufD;                        // after xi2 dies
    float* ybuf   = bufD;                        // after deltaT dies

    // 1. LayerNorm
    ln_kernel<<<SEQ, 256, 0, stream>>>(x, ln_g, ln_b, xn);

    // 2a. xi_raw = xn @ Win[0:DI]^T  (normal out [SEQ][DI])
    gemm_mfma<0, false><<<dim3(SEQ / 128, DI / 64), 256, 0, stream>>>(
        xn, DM, Win, DM, DI, DM, xi_raw, nullptr, DI);
    // 2b. szT = silu(xn @ Win[DI:2DI]^T)^T  (transposed out [DI][SEQ])
    gemm_mfma<1, true><<<dim3(SEQ / 128, DI / 64), 256, 0, stream>>>(
        xn, DM, Win + (size_t)DI * DM, DM, DI, DM, szT, nullptr, SEQ);

    // 3. conv + SiLU -> xi2 [SEQ][DI]
    conv_kernel<<<(SEQ * DI) / 256, 256, 0, stream>>>(xi_raw, conv_w, conv_b, xi2);

    // 4. xi2T = xi2^T  (bufB, xi_raw dead)
    transpose_kernel<<<dim3(SEQ / 64, DI / 64), 256, 0, stream>>>(xi2, xi2T, SEQ, DI);

    // 5. dbc = xi2 @ Wx^T  [SEQ][160]  (bufA, xn dead; coalesced for scan lanes)
    gemm_mfma<0, false><<<dim3(SEQ / 128, (160 + 63) / 64), 256, 0, stream>>>(
        xi2, DI, Wx, DI, 160, DI, dbc, nullptr, 160);

    // 6. deltaT = softplus(dbc[:,:32] @ Wdt^T + bdt)^T  [DI][SEQ]  (bufD, xi2 dead)
    gemm_dt_t<<<dim3(SEQ / 64, DI / 64), 256, 0, stream>>>(dbc, Wdt, bdt, deltaT);

    // 7. chunked scan: A (local) -> carry -> B (y^T in-place over szT)
    scan_passA<<<(DI * NCHUNK) / 4, 256, 0, stream>>>(deltaT, xi2T, dbc, A_log, Pbuf, hend);
    scan_carry<<<DI / 4, 256, 0, stream>>>(Pbuf, hend);
    scan_passB<<<(DI * NCHUNK) / 4, 256, 0, stream>>>(deltaT, xi2T, dbc, szT, A_log, Dp, Pbuf);

    // 8. y = yT^T  (bufD, deltaT dead)
    transpose_kernel<<<dim3(DI / 64, SEQ / 64), 256, 0, stream>>>(szT, ybuf, DI, SEQ);

    // 9. out = y @ Wout^T + x  (normal out, fused residual)
    gemm_mfma<2, false><<<dim3(SEQ / 128, DM / 64), 256, 0, stream>>>(
        ybuf, DI, Wout, DI, DM, DI, out, x, DM);
}

// Round 12
// 314.801 us; speedup vs baseline: 1.9745x; 1.5193x over previous
//
#include <hip/hip_runtime.h>
#include <hip/hip_bf16.h>
#include <cstddef>

#define SEQ 2048
#define DM  512
#define DI  1024   // d_inner
#define DR  32     // dt_rank
#define DS  64     // d_state
#define NCHUNK 8
#define CHUNK  256 // SEQ / NCHUNK
#define MB (1024 * 1024)

typedef __attribute__((ext_vector_type(4))) float f32x4;
typedef __attribute__((ext_vector_type(8))) short frag8;

// round-to-nearest-even f32 -> bf16 raw bits (finite inputs)
__device__ __forceinline__ unsigned short f2bf(float f) {
    unsigned u = __float_as_uint(f);
    unsigned r = (u + 0x7fffu + ((u >> 16) & 1u)) >> 16;
    return (unsigned short)r;
}
__device__ __forceinline__ float bf2f(unsigned short u) {
    return __int_as_float(((int)u) << 16);
}

// p + dpp_permute(p), compile-time DPP control
template <int CTRL>
__device__ __forceinline__ float dppadd(float p) {
    return p + __int_as_float(
        __builtin_amdgcn_update_dpp(0, __float_as_int(p), CTRL, 0xF, 0xF, true));
}

// ---------------- weight fp32 -> bf16 conversion (once per launch) --------
// Sizes: Win 2*DI*DM = 1,048,576; Wx 160*DI = 163,840; Wout DM*DI = 524,288.
__global__ void cvt_weights(const float* __restrict__ w1, unsigned short* __restrict__ o1, int n1,
                            const float* __restrict__ w2, unsigned short* __restrict__ o2, int n2,
                            const float* __restrict__ w3, unsigned short* __restrict__ o3, int n3) {
    int i = (blockIdx.x * 256 + threadIdx.x) * 4;
    const float* s; unsigned short* d; int off;
    if (i < n1) { s = w1; d = o1; off = i; }
    else if (i < n1 + n2) { s = w2; d = o2; off = i - n1; }
    else if (i < n1 + n2 + n3) { s = w3; d = o3; off = i - n1 - n2; }
    else return;
    float4 v = *(const float4*)(s + off);
    ushort4 o = { f2bf(v.x), f2bf(v.y), f2bf(v.z), f2bf(v.w) };
    *(ushort4*)(d + off) = o;
}

// ---------------- LayerNorm -> bf16 xn ------------------------------------
__global__ void ln_kernel(const float* __restrict__ x, const float* __restrict__ g,
                          const float* __restrict__ b, unsigned short* __restrict__ xn) {
    int l = blockIdx.x;
    int t = threadIdx.x;
    __shared__ float red[256];
    float v0 = x[l * DM + t];
    float v1 = x[l * DM + t + 256];
    red[t] = v0 + v1;
    __syncthreads();
    for (int o = 128; o > 0; o >>= 1) { if (t < o) red[t] += red[t + o]; __syncthreads(); }
    float mu = red[0] * (1.f / DM);
    __syncthreads();
    float c0 = v0 - mu, c1 = v1 - mu;
    red[t] = c0 * c0 + c1 * c1;
    __syncthreads();
    for (int o = 128; o > 0; o >>= 1) { if (t < o) red[t] += red[t + o]; __syncthreads(); }
    float rstd = rsqrtf(red[0] * (1.f / DM) + 1e-5f);
    xn[l * DM + t]       = f2bf(c0 * rstd * g[t]       + b[t]);
    xn[l * DM + t + 256] = f2bf(c1 * rstd * g[t + 256] + b[t + 256]);
}

// ---------------- bf16 MFMA GEMM: C[M,N] = A[M,K] * B[N,K]^T --------------
// A,B bf16 in memory. Tile 128x64, BK=32, 256 thr = 4 waves (64x32 each).
// EPI 1: in-proj split (N=2048): n<DI -> bf16 out1 [M][DI]; n>=DI -> silu,
//        bf16 transposed out2 [DI][SEQ]. EPI 2: fp32 + residual. EPI 3: fp32.
#define LDK 40
template <int EPI>
__global__ void gemm_bf(const unsigned short* __restrict__ A, int lda,
                        const unsigned short* __restrict__ B, int ldb,
                        int N, int K,
                        float* __restrict__ outF, const float* __restrict__ res, int ldo,
                        unsigned short* __restrict__ outB1, unsigned short* __restrict__ outB2) {
    __shared__ unsigned short As[128 * LDK];
    __shared__ unsigned short Bs[64 * LDK];
    int t = threadIdx.x;
    int lane = t & 63;
    int wv = t >> 6;
    int wm = (wv >> 1) * 64;
    int wn = (wv & 1) * 32;
    int m0 = blockIdx.x * 128, n0 = blockIdx.y * 64;

    f32x4 acc[4][2];
#pragma unroll
    for (int i = 0; i < 4; i++)
#pragma unroll
        for (int j = 0; j < 2; j++) acc[i][j] = (f32x4){0.f, 0.f, 0.f, 0.f};

    int lm = lane & 15;
    int kq = (lane >> 4) * 8;

    for (int k0 = 0; k0 < K; k0 += 32) {
        // A: 512 chunks of 8 bf16; 2 per thread
#pragma unroll
        for (int j = 0; j < 2; j++) {
            int c = t + j * 256;
            int m = c >> 2;
            int k = (c & 3) * 8;
            frag8 v = *(const frag8*)(A + (size_t)(m0 + m) * lda + k0 + k);
            *(frag8*)(&As[m * LDK + k]) = v;
        }
        // B: 256 chunks; 1 per thread; N-guarded
        {
            int m = t >> 2;
            int k = (t & 3) * 8;
            int gn = n0 + m;
            frag8 v = {0, 0, 0, 0, 0, 0, 0, 0};
            if (gn < N) v = *(const frag8*)(B + (size_t)gn * ldb + k0 + k);
            *(frag8*)(&Bs[m * LDK + k]) = v;
        }
        __syncthreads();

        frag8 af[4], bfr[2];
#pragma unroll
        for (int mt = 0; mt < 4; mt++)
            af[mt] = *(const frag8*)(&As[(wm + mt * 16 + lm) * LDK + kq]);
#pragma unroll
        for (int nt = 0; nt < 2; nt++)
            bfr[nt] = *(const frag8*)(&Bs[(wn + nt * 16 + lm) * LDK + kq]);
#pragma unroll
        for (int mt = 0; mt < 4; mt++)
#pragma unroll
            for (int nt = 0; nt < 2; nt++)
                acc[mt][nt] = __builtin_amdgcn_mfma_f32_16x16x32_bf16(
                    af[mt], bfr[nt], acc[mt][nt], 0, 0, 0);
        __syncthreads();
    }

    // epilogue: C/D layout col=lane&15, row=(lane>>4)*4+reg
    int rbase = (lane >> 4) * 4;
#pragma unroll
    for (int mt = 0; mt < 4; mt++) {
#pragma unroll
        for (int nt = 0; nt < 2; nt++) {
            int n = n0 + wn + nt * 16 + lm;
            int mb = m0 + wm + mt * 16 + rbase;
            if (EPI == 1) {
                if (n < DI) {
#pragma unroll
                    for (int r = 0; r < 4; r++)
                        outB1[(size_t)(mb + r) * DI + n] = f2bf(acc[mt][nt][r]);
                } else {
                    int nn = n - DI;
                    ushort4 o;
#pragma unroll
                    for (int r = 0; r < 4; r++) {
                        float v = acc[mt][nt][r];
                        v = v / (1.f + __expf(-v));
                        (&o.x)[r] = f2bf(v);
                    }
                    *(ushort4*)(outB2 + (size_t)nn * SEQ + mb) = o;
                }
            } else if (EPI == 2) {
                if (n < N) {
#pragma unroll
                    for (int r = 0; r < 4; r++)
                        outF[(size_t)(mb + r) * ldo + n] =
                            acc[mt][nt][r] + res[(size_t)(mb + r) * ldo + n];
                }
            } else {
                if (n < N) {
#pragma unroll
                    for (int r = 0; r < 4; r++)
                        outF[(size_t)(mb + r) * ldo + n] = acc[mt][nt][r];
                }
            }
        }
    }
}

// ---------------- dt-proj vector GEMM, transposed store (fp32) ------------
__global__ void gemm_dt_t(const float* __restrict__ A,   // dbc [SEQ][160]
                          const float* __restrict__ B,   // Wdt [DI][DR]
                          const float* __restrict__ bias,
                          float* __restrict__ outT) {    // deltaT [DI][SEQ]
    __shared__ float As[16][65];
    __shared__ float Bs[16][65];
    int tid = threadIdx.x;
    int tx = tid & 15, ty = tid >> 4;
    int bm = blockIdx.x * 64, bn = blockIdx.y * 64;   // bm: l, bn: e
    float acc[4][4] = {};
    int kk = tid & 15;
    int rr = tid >> 4;
    for (int k0 = 0; k0 < DR; k0 += 16) {
#pragma unroll
        for (int i = 0; i < 4; i++)
            As[kk][rr + 16 * i] = A[(size_t)(bm + rr + 16 * i) * 160 + k0 + kk];
#pragma unroll
        for (int i = 0; i < 4; i++)
            Bs[kk][rr + 16 * i] = B[(size_t)(bn + rr + 16 * i) * DR + k0 + kk];
        __syncthreads();
#pragma unroll
        for (int k = 0; k < 16; k++) {
            float a[4], bb[4];
#pragma unroll
            for (int i = 0; i < 4; i++) a[i] = As[k][ty * 4 + i];
#pragma unroll
            for (int j = 0; j < 4; j++) bb[j] = Bs[k][tx * 4 + j];
#pragma unroll
            for (int i = 0; i < 4; i++)
#pragma unroll
                for (int j = 0; j < 4; j++)
                    acc[i][j] = fmaf(a[i], bb[j], acc[i][j]);
        }
        __syncthreads();
    }
#pragma unroll
    for (int j = 0; j < 4; j++) {
        int e = bn + tx * 4 + j;
        float bv = bias[e];
        float4 o;
#pragma unroll
        for (int i = 0; i < 4; i++) {
            float v = acc[i][j] + bv;
            v = (v > 20.f) ? v : __logf(1.f + __expf(v));
            (&o.x)[i] = v;
        }
        *(float4*)(outT + (size_t)e * SEQ + bm + ty * 4) = o;
    }
}

// ---------------- Causal depthwise conv (w=4) + bias + SiLU, bf16 ---------
__global__ void conv_bf(const unsigned short* __restrict__ xi_raw,
                        const float* __restrict__ w, const float* __restrict__ cb,
                        unsigned short* __restrict__ xi2bf) {
    int idx = blockIdx.x * 256 + threadIdx.x;
    int e = idx & (DI - 1);
    int l = idx >> 10;
    float acc = cb[e];
#pragma unroll
    for (int j = 0; j < 4; j++) {
        int ls = l - 3 + j;
        if (ls >= 0) acc = fmaf(w[e * 4 + j], bf2f(xi_raw[(size_t)ls * DI + e]), acc);
    }
    float s = acc / (1.f + __expf(-acc));
    xi2bf[idx] = f2bf(s);
}

// ---------------- generic bf16 transpose: in[R][C] -> out[C][R] -----------
// R, C multiples of 64. grid (R/64, C/64).
__global__ void transpose_bf(const unsigned short* __restrict__ in,
                             unsigned short* __restrict__ outp, int R, int C) {
    __shared__ unsigned short tile[64][72];
    int r0 = blockIdx.x * 64, c0 = blockIdx.y * 64;
    int t = threadIdx.x;
    for (int c = t; c < 512; c += 256) {   // 64 rows x 8 chunks of 8
        int r = c >> 3, k = (c & 7) * 8;
        frag8 v = *(const frag8*)(in + (size_t)(r0 + r) * C + c0 + k);
        *(frag8*)(&tile[r][k]) = v;
    }
    __syncthreads();
    for (int c = t; c < 1024; c += 256) {  // 64 out-rows x 16 chunks of 4
        int cr = c >> 4, r4 = (c & 15) * 4;
        ushort4 o = { tile[r4][cr], tile[r4 + 1][cr], tile[r4 + 2][cr], tile[r4 + 3][cr] };
        *(ushort4*)(outp + (size_t)(c0 + cr) * R + r0 + r4) = o;
    }
}

// ---------------- Chunked selective scan (hybrid layout) ------------------
// deltaT fp32 [DI][SEQ]; xi2T/szT bf16 [DI][SEQ]; dbc fp32 [SEQ][160].
__global__ void scan_passA(const float* __restrict__ deltaT, const unsigned short* __restrict__ xi2T,
                           const float* __restrict__ dbc, const float* __restrict__ A_log,
                           float* __restrict__ P, float* __restrict__ hend) {
    int wid = blockIdx.x * 4 + (threadIdx.x >> 6);
    int e = wid & (DI - 1);
    int c = wid >> 10;
    int n = threadIdx.x & 63;
    float Ae = -__expf(A_log[e * DS + n]);
    float h = 0.f, sum_d = 0.f;
    int l0 = c * CHUNK;
    const float4* d4  = (const float4*)(deltaT + (size_t)e * SEQ + l0);
    const ushort4* x4 = (const ushort4*)(xi2T + (size_t)e * SEQ + l0);
    const float* dbg = dbc + (size_t)l0 * 160 + DR + n;
    for (int g = 0; g < CHUNK / 4; g++) {
        float4 dd = d4[g];
        ushort4 xx = x4[g];
#pragma unroll
        for (int j = 0; j < 4; j++) {
            float Bn = dbg[j * 160];
            float dj = (&dd.x)[j];
            float xj = bf2f((&xx.x)[j]);
            float dA = __expf(dj * Ae);
            h = fmaf(dA, h, (dj * xj) * Bn);
            sum_d += dj;
        }
        dbg += 640;
    }
    int idx = (c * DI + e) * DS + n;
    P[idx] = __expf(Ae * sum_d);
    hend[idx] = h;
}

__global__ void scan_carry(float* __restrict__ P, const float* __restrict__ hend) {
    int e = blockIdx.x * 4 + (threadIdx.x >> 6);
    int n = threadIdx.x & 63;
    float h = 0.f;
    for (int c = 0; c < NCHUNK; c++) {
        int idx = (c * DI + e) * DS + n;
        float p  = P[idx];
        float he = hend[idx];
        P[idx] = h;
        h = fmaf(p, h, he);
    }
}

// Pass B: 6-DPP wave64 reduce; lane 63 holds total, gates and stores bf16 yT
// in-place over szT (read-before-write within owning wave).
__global__ void scan_passB(const float* __restrict__ deltaT, const unsigned short* __restrict__ xi2T,
                           const float* __restrict__ dbc, unsigned short* __restrict__ szyT,
                           const float* __restrict__ A_log, const float* __restrict__ Dp,
                           const float* __restrict__ hin) {
    int wid = blockIdx.x * 4 + (threadIdx.x >> 6);
    int e = wid & (DI - 1);
    int c = wid >> 10;
    int n = threadIdx.x & 63;
    float Ae = -__expf(A_log[e * DS + n]);
    float dp = Dp[e];
    float h = hin[(c * DI + e) * DS + n];
    int l0 = c * CHUNK;
    const float4* d4  = (const float4*)(deltaT + (size_t)e * SEQ + l0);
    const ushort4* x4 = (const ushort4*)(xi2T + (size_t)e * SEQ + l0);
    ushort4* s4       = (ushort4*)(szyT + (size_t)e * SEQ + l0);
    const float* dbg = dbc + (size_t)l0 * 160 + DR + n;
    for (int g = 0; g < CHUNK / 4; g++) {
        float4 dd = d4[g];
        ushort4 xx = x4[g], zz = s4[g];
        ushort4 yv;
#pragma unroll
        for (int j = 0; j < 4; j++) {
            float Bn = dbg[j * 160];
            float Cn = dbg[j * 160 + DS];
            float dj = (&dd.x)[j];
            float xj = bf2f((&xx.x)[j]);
            float dA = __expf(dj * Ae);
            h = fmaf(dA, h, (dj * xj) * Bn);
            float p = h * Cn;
            p = dppadd<0xB1>(p);   // quad_perm swap-1
            p = dppadd<0x4E>(p);   // quad_perm swap-2
            p = dppadd<0x141>(p);  // row_half_mirror
            p = dppadd<0x140>(p);  // row_mirror -> 16-lane row sums
            p = dppadd<0x142>(p);  // row_bcast15
            p = dppadd<0x143>(p);  // row_bcast31 -> lane 63 = total
            (&yv.x)[j] = f2bf((p + dp * xj) * bf2f((&zz.x)[j]));
        }
        dbg += 640;
        if (n == 63) s4[g] = yv;
    }
}

extern "C" void kernel_launch(void* const* d_in, const int* in_sizes, int n_in,
                              void* d_out, int out_size, void* d_ws, size_t ws_size,
                              hipStream_t stream) {
    const float* x      = (const float*)d_in[0];
    const float* ln_g   = (const float*)d_in[1];
    const float* ln_b   = (const float*)d_in[2];
    const float* Win    = (const float*)d_in[3];
    const float* conv_w = (const float*)d_in[4];
    const float* conv_b = (const float*)d_in[5];
    const float* Wx     = (const float*)d_in[6];
    const float* Wdt    = (const float*)d_in[7];
    const float* bdt    = (const float*)d_in[8];
    const float* A_log  = (const float*)d_in[9];
    const float* Dp     = (const float*)d_in[10];
    const float* Wout   = (const float*)d_in[11];
    float* out = (float*)d_out;

    // Workspace map (27 MB total; 30 MB proven safe):
    char* W = (char*)d_ws;
    unsigned short* xi_raw  = (unsigned short*)W;              // 4 MB (early)
    float*          deltaT  = (float*)W;                       // 8 MB (late, xi_raw dead)
    unsigned short* Win_bf  = (unsigned short*)(W + 8 * MB);   // 2 MB used (-> xi2bf -> y_bf)
    unsigned short* xi2bf   = (unsigned short*)(W + 8 * MB);
    unsigned short* y_bf    = (unsigned short*)(W + 8 * MB);
    unsigned short* szT     = (unsigned short*)(W + 12 * MB);  // 4 MB (-> yT in-place)
    unsigned short* xi2T    = (unsigned short*)(W + 16 * MB);  // 4 MB
    unsigned short* xn_bf   = (unsigned short*)(W + 20 * MB);  // 2 MB (-> Pbuf)
    float*          Pbuf    = (float*)(W + 20 * MB);
    unsigned short* Wout_bf = (unsigned short*)(W + 22 * MB);  // 1 MB
    unsigned short* Wx_bf   = (unsigned short*)(W + 23 * MB);  // 0.32 MB
    float*          dbc     = (float*)(W + 23 * MB + 512 * 1024); // 1.31 MB
    float*          hend    = (float*)(W + 25 * MB);           // 2 MB

    // 1. weights -> bf16. Element counts: Win 2*DI*DM = 1,048,576 (NOT 2M —
    //    the R10/R11 crash was an OOB read from this constant), Wx 163,840,
    //    Wout 524,288. Total 1,736,704 -> 1696 blocks of 256 (x4 elems).
    cvt_weights<<<(1048576 + 163840 + 524288) / 1024, 256, 0, stream>>>(
        Win, Win_bf, 1048576, Wx, Wx_bf, 163840, Wout, Wout_bf, 524288);

    // 2. LayerNorm -> bf16 xn
    ln_kernel<<<SEQ, 256, 0, stream>>>(x, ln_g, ln_b, xn_bf);

    // 3. fused in-proj [2048 x 2048 x 512]: lower half -> xi_raw bf16,
    //    upper half -> silu -> szT bf16 (transposed)
    gemm_bf<1><<<dim3(SEQ / 128, 2048 / 64), 256, 0, stream>>>(
        xn_bf, DM, Win_bf, DM, 2048, DM, nullptr, nullptr, 0, xi_raw, szT);

    // 4. conv + SiLU -> xi2bf [SEQ][DI] bf16
    conv_bf<<<(SEQ * DI) / 256, 256, 0, stream>>>(xi_raw, conv_w, conv_b, xi2bf);

    // 5. xi2T = xi2^T [DI][SEQ] bf16
    transpose_bf<<<dim3(SEQ / 64, DI / 64), 256, 0, stream>>>(xi2bf, xi2T, SEQ, DI);

    // 6. dbc = xi2 @ Wx^T  [SEQ][160] fp32
    gemm_bf<3><<<dim3(SEQ / 128, 3), 256, 0, stream>>>(
        xi2bf, DI, Wx_bf, DI, 160, DI, dbc, nullptr, 160, nullptr, nullptr);

    // 7. deltaT = softplus(dbc[:,:32] @ Wdt^T + bdt)^T  [DI][SEQ] fp32
    gemm_dt_t<<<dim3(SEQ / 64, DI / 64), 256, 0, stream>>>(dbc, Wdt, bdt, deltaT);

    // 8. chunked scan: A (local) -> carry -> B (bf16 yT in-place over szT)
    scan_passA<<<(DI * NCHUNK) / 4, 256, 0, stream>>>(deltaT, xi2T, dbc, A_log, Pbuf, hend);
    scan_carry<<<DI / 4, 256, 0, stream>>>(Pbuf, hend);
    scan_passB<<<(DI * NCHUNK) / 4, 256, 0, stream>>>(deltaT, xi2T, dbc, szT, A_log, Dp, Pbuf);

    // 9. y_bf = yT^T  [SEQ][DI] bf16
    transpose_bf<<<dim3(DI / 64, SEQ / 64), 256, 0, stream>>>(szT, y_bf, DI, SEQ);

    // 10. out = y @ Wout^T + x  fp32
    gemm_bf<2><<<dim3(SEQ / 128, DM / 64), 256, 0, stream>>>(
        y_bf, DI, Wout_bf, DI, DM, DI, out, x, DM, nullptr, nullptr);
}

// Round 13
// 304.093 us; speedup vs baseline: 2.0441x; 1.0352x over previous
//
#include <hip/hip_runtime.h>
#include <hip/hip_bf16.h>
#include <cstddef>

#define SEQ 2048
#define DM  512
#define DI  1024   // d_inner
#define DR  32     // dt_rank
#define DS  64     // d_state
#define NCHUNK 8
#define CHUNK  256 // SEQ / NCHUNK
#define MB (1024 * 1024)

typedef __attribute__((ext_vector_type(4))) float f32x4;
typedef __attribute__((ext_vector_type(8))) short frag8;

// round-to-nearest-even f32 -> bf16 raw bits (finite inputs)
__device__ __forceinline__ unsigned short f2bf(float f) {
    unsigned u = __float_as_uint(f);
    unsigned r = (u + 0x7fffu + ((u >> 16) & 1u)) >> 16;
    return (unsigned short)r;
}
__device__ __forceinline__ float bf2f(unsigned short u) {
    return __int_as_float(((int)u) << 16);
}

// p + dpp_permute(p), compile-time DPP control
template <int CTRL>
__device__ __forceinline__ float dppadd(float p) {
    return p + __int_as_float(
        __builtin_amdgcn_update_dpp(0, __float_as_int(p), CTRL, 0xF, 0xF, true));
}

// ---------------- weight fp32 -> bf16 conversion (once per launch) --------
// Sizes: Win 2*DI*DM = 1,048,576; Wx 160*DI = 163,840; Wout DM*DI = 524,288.
__global__ void cvt_weights(const float* __restrict__ w1, unsigned short* __restrict__ o1, int n1,
                            const float* __restrict__ w2, unsigned short* __restrict__ o2, int n2,
                            const float* __restrict__ w3, unsigned short* __restrict__ o3, int n3) {
    int i = (blockIdx.x * 256 + threadIdx.x) * 4;
    const float* s; unsigned short* d; int off;
    if (i < n1) { s = w1; d = o1; off = i; }
    else if (i < n1 + n2) { s = w2; d = o2; off = i - n1; }
    else if (i < n1 + n2 + n3) { s = w3; d = o3; off = i - n1 - n2; }
    else return;
    float4 v = *(const float4*)(s + off);
    ushort4 o = { f2bf(v.x), f2bf(v.y), f2bf(v.z), f2bf(v.w) };
    *(ushort4*)(d + off) = o;
}

// ---------------- LayerNorm -> bf16 xn ------------------------------------
__global__ void ln_kernel(const float* __restrict__ x, const float* __restrict__ g,
                          const float* __restrict__ b, unsigned short* __restrict__ xn) {
    int l = blockIdx.x;
    int t = threadIdx.x;
    __shared__ float red[256];
    float v0 = x[l * DM + t];
    float v1 = x[l * DM + t + 256];
    red[t] = v0 + v1;
    __syncthreads();
    for (int o = 128; o > 0; o >>= 1) { if (t < o) red[t] += red[t + o]; __syncthreads(); }
    float mu = red[0] * (1.f / DM);
    __syncthreads();
    float c0 = v0 - mu, c1 = v1 - mu;
    red[t] = c0 * c0 + c1 * c1;
    __syncthreads();
    for (int o = 128; o > 0; o >>= 1) { if (t < o) red[t] += red[t + o]; __syncthreads(); }
    float rstd = rsqrtf(red[0] * (1.f / DM) + 1e-5f);
    xn[l * DM + t]       = f2bf(c0 * rstd * g[t]       + b[t]);
    xn[l * DM + t + 256] = f2bf(c1 * rstd * g[t + 256] + b[t + 256]);
}

#define LDK 40

// ---------------- 128x128 bf16 MFMA GEMM (in-proj only) -------------------
// C[M,N] = A[M,K]*B[N,K]^T. 256 thr = 4 waves, each 64x64 (4x4 16x16 tiles).
// Split epilogue: n < DI -> bf16 out1 [M][DI]; n >= DI -> silu -> bf16
// transposed out2 [DI][SEQ]. DI is a multiple of 128 so the branch is
// tile-uniform.
__global__ void gemm_bf128_inproj(const unsigned short* __restrict__ A, int lda,
                                  const unsigned short* __restrict__ B, int ldb,
                                  int K,
                                  unsigned short* __restrict__ outB1,
                                  unsigned short* __restrict__ outB2) {
    __shared__ unsigned short As[128 * LDK];
    __shared__ unsigned short Bs[128 * LDK];
    int t = threadIdx.x;
    int lane = t & 63;
    int wv = t >> 6;
    int wm = (wv >> 1) * 64;
    int wn = (wv & 1) * 64;
    int m0 = blockIdx.x * 128, n0 = blockIdx.y * 128;

    f32x4 acc[4][4];
#pragma unroll
    for (int i = 0; i < 4; i++)
#pragma unroll
        for (int j = 0; j < 4; j++) acc[i][j] = (f32x4){0.f, 0.f, 0.f, 0.f};

    int lm = lane & 15;
    int kq = (lane >> 4) * 8;

    for (int k0 = 0; k0 < K; k0 += 32) {
        // A and B: each 128 rows x 32 k = 512 frag8 chunks; 2/thread each.
#pragma unroll
        for (int j = 0; j < 2; j++) {
            int c = t + j * 256;
            int m = c >> 2;
            int k = (c & 3) * 8;
            frag8 va = *(const frag8*)(A + (size_t)(m0 + m) * lda + k0 + k);
            *(frag8*)(&As[m * LDK + k]) = va;
            frag8 vb = *(const frag8*)(B + (size_t)(n0 + m) * ldb + k0 + k);
            *(frag8*)(&Bs[m * LDK + k]) = vb;
        }
        __syncthreads();

        frag8 af[4], bfr[4];
#pragma unroll
        for (int mt = 0; mt < 4; mt++)
            af[mt] = *(const frag8*)(&As[(wm + mt * 16 + lm) * LDK + kq]);
#pragma unroll
        for (int nt = 0; nt < 4; nt++)
            bfr[nt] = *(const frag8*)(&Bs[(wn + nt * 16 + lm) * LDK + kq]);
#pragma unroll
        for (int mt = 0; mt < 4; mt++)
#pragma unroll
            for (int nt = 0; nt < 4; nt++)
                acc[mt][nt] = __builtin_amdgcn_mfma_f32_16x16x32_bf16(
                    af[mt], bfr[nt], acc[mt][nt], 0, 0, 0);
        __syncthreads();
    }

    int rbase = (lane >> 4) * 4;
    bool lower = (n0 < DI);   // tile-uniform split
#pragma unroll
    for (int mt = 0; mt < 4; mt++) {
#pragma unroll
        for (int nt = 0; nt < 4; nt++) {
            int n = n0 + wn + nt * 16 + lm;
            int mb = m0 + wm + mt * 16 + rbase;
            if (lower) {
#pragma unroll
                for (int r = 0; r < 4; r++)
                    outB1[(size_t)(mb + r) * DI + n] = f2bf(acc[mt][nt][r]);
            } else {
                int nn = n - DI;
                ushort4 o;
#pragma unroll
                for (int r = 0; r < 4; r++) {
                    float v = acc[mt][nt][r];
                    v = v / (1.f + __expf(-v));
                    (&o.x)[r] = f2bf(v);
                }
                *(ushort4*)(outB2 + (size_t)nn * SEQ + mb) = o;
            }
        }
    }
}

// ---------------- 128x64 bf16 MFMA GEMM (x-proj / out-proj) ---------------
// EPI 2: fp32 + residual. EPI 3: fp32 plain.
template <int EPI>
__global__ void gemm_bf(const unsigned short* __restrict__ A, int lda,
                        const unsigned short* __restrict__ B, int ldb,
                        int N, int K,
                        float* __restrict__ outF, const float* __restrict__ res, int ldo) {
    __shared__ unsigned short As[128 * LDK];
    __shared__ unsigned short Bs[64 * LDK];
    int t = threadIdx.x;
    int lane = t & 63;
    int wv = t >> 6;
    int wm = (wv >> 1) * 64;
    int wn = (wv & 1) * 32;
    int m0 = blockIdx.x * 128, n0 = blockIdx.y * 64;

    f32x4 acc[4][2];
#pragma unroll
    for (int i = 0; i < 4; i++)
#pragma unroll
        for (int j = 0; j < 2; j++) acc[i][j] = (f32x4){0.f, 0.f, 0.f, 0.f};

    int lm = lane & 15;
    int kq = (lane >> 4) * 8;

    for (int k0 = 0; k0 < K; k0 += 32) {
#pragma unroll
        for (int j = 0; j < 2; j++) {
            int c = t + j * 256;
            int m = c >> 2;
            int k = (c & 3) * 8;
            frag8 v = *(const frag8*)(A + (size_t)(m0 + m) * lda + k0 + k);
            *(frag8*)(&As[m * LDK + k]) = v;
        }
        {
            int m = t >> 2;
            int k = (t & 3) * 8;
            int gn = n0 + m;
            frag8 v = {0, 0, 0, 0, 0, 0, 0, 0};
            if (gn < N) v = *(const frag8*)(B + (size_t)gn * ldb + k0 + k);
            *(frag8*)(&Bs[m * LDK + k]) = v;
        }
        __syncthreads();

        frag8 af[4], bfr[2];
#pragma unroll
        for (int mt = 0; mt < 4; mt++)
            af[mt] = *(const frag8*)(&As[(wm + mt * 16 + lm) * LDK + kq]);
#pragma unroll
        for (int nt = 0; nt < 2; nt++)
            bfr[nt] = *(const frag8*)(&Bs[(wn + nt * 16 + lm) * LDK + kq]);
#pragma unroll
        for (int mt = 0; mt < 4; mt++)
#pragma unroll
            for (int nt = 0; nt < 2; nt++)
                acc[mt][nt] = __builtin_amdgcn_mfma_f32_16x16x32_bf16(
                    af[mt], bfr[nt], acc[mt][nt], 0, 0, 0);
        __syncthreads();
    }

    int rbase = (lane >> 4) * 4;
#pragma unroll
    for (int mt = 0; mt < 4; mt++) {
#pragma unroll
        for (int nt = 0; nt < 2; nt++) {
            int n = n0 + wn + nt * 16 + lm;
            int mb = m0 + wm + mt * 16 + rbase;
            if (n < N) {
#pragma unroll
                for (int r = 0; r < 4; r++) {
                    float v = acc[mt][nt][r];
                    if (EPI == 2) v += res[(size_t)(mb + r) * ldo + n];
                    outF[(size_t)(mb + r) * ldo + n] = v;
                }
            }
        }
    }
}

// ---------------- dt-proj vector GEMM, transposed store (fp32) ------------
__global__ void gemm_dt_t(const float* __restrict__ A,   // dbc [SEQ][160]
                          const float* __restrict__ B,   // Wdt [DI][DR]
                          const float* __restrict__ bias,
                          float* __restrict__ outT) {    // deltaT [DI][SEQ]
    __shared__ float As[16][65];
    __shared__ float Bs[16][65];
    int tid = threadIdx.x;
    int tx = tid & 15, ty = tid >> 4;
    int bm = blockIdx.x * 64, bn = blockIdx.y * 64;   // bm: l, bn: e
    float acc[4][4] = {};
    int kk = tid & 15;
    int rr = tid >> 4;
    for (int k0 = 0; k0 < DR; k0 += 16) {
#pragma unroll
        for (int i = 0; i < 4; i++)
            As[kk][rr + 16 * i] = A[(size_t)(bm + rr + 16 * i) * 160 + k0 + kk];
#pragma unroll
        for (int i = 0; i < 4; i++)
            Bs[kk][rr + 16 * i] = B[(size_t)(bn + rr + 16 * i) * DR + k0 + kk];
        __syncthreads();
#pragma unroll
        for (int k = 0; k < 16; k++) {
            float a[4], bb[4];
#pragma unroll
            for (int i = 0; i < 4; i++) a[i] = As[k][ty * 4 + i];
#pragma unroll
            for (int j = 0; j < 4; j++) bb[j] = Bs[k][tx * 4 + j];
#pragma unroll
            for (int i = 0; i < 4; i++)
#pragma unroll
                for (int j = 0; j < 4; j++)
                    acc[i][j] = fmaf(a[i], bb[j], acc[i][j]);
        }
        __syncthreads();
    }
#pragma unroll
    for (int j = 0; j < 4; j++) {
        int e = bn + tx * 4 + j;
        float bv = bias[e];
        float4 o;
#pragma unroll
        for (int i = 0; i < 4; i++) {
            float v = acc[i][j] + bv;
            v = (v > 20.f) ? v : __logf(1.f + __expf(v));
            (&o.x)[i] = v;
        }
        *(float4*)(outT + (size_t)e * SEQ + bm + ty * 4) = o;
    }
}

// ---------------- fused conv(w=4, causal) + bias + SiLU + transpose -------
// in: xi_raw bf16 [SEQ][DI]; out: xi2bf bf16 [SEQ][DI] + xi2T bf16 [DI][SEQ].
// Tile: 64 l x 64 e per block, 256 threads.
__global__ void conv_t(const unsigned short* __restrict__ xi_raw,
                       const float* __restrict__ w, const float* __restrict__ cb,
                       unsigned short* __restrict__ xi2bf, unsigned short* __restrict__ xi2T) {
    __shared__ float tin[67][72];
    __shared__ float tout[64][65];
    int l0 = blockIdx.x * 64, e0 = blockIdx.y * 64;
    int t = threadIdx.x;
    for (int c = t; c < 536; c += 256) {      // 67 rows x 8 chunks of 8
        int r = c >> 3, ke = (c & 7) * 8;
        int l = l0 - 3 + r;
        frag8 v = {0, 0, 0, 0, 0, 0, 0, 0};
        if (l >= 0) v = *(const frag8*)(xi_raw + (size_t)l * DI + e0 + ke);
#pragma unroll
        for (int i = 0; i < 8; i++) tin[r][ke + i] = bf2f((unsigned short)v[i]);
    }
    __syncthreads();
    int e_loc = t & 63;
    int e = e0 + e_loc;
    float4 wv = *(const float4*)(w + e * 4);
    float bias = cb[e];
#pragma unroll 4
    for (int i = 0; i < 16; i++) {
        int l_loc = (t >> 6) + i * 4;
        float acc = bias;
        acc = fmaf(wv.x, tin[l_loc][e_loc], acc);
        acc = fmaf(wv.y, tin[l_loc + 1][e_loc], acc);
        acc = fmaf(wv.z, tin[l_loc + 2][e_loc], acc);
        acc = fmaf(wv.w, tin[l_loc + 3][e_loc], acc);
        float s = acc / (1.f + __expf(-acc));
        tout[l_loc][e_loc] = s;
        xi2bf[(size_t)(l0 + l_loc) * DI + e] = f2bf(s);
    }
    __syncthreads();
    for (int c = t; c < 1024; c += 256) {     // 64 e-rows x 16 l-chunks of 4
        int er = c >> 4, l4 = (c & 15) * 4;
        ushort4 o = { f2bf(tout[l4][er]), f2bf(tout[l4 + 1][er]),
                      f2bf(tout[l4 + 2][er]), f2bf(tout[l4 + 3][er]) };
        *(ushort4*)(xi2T + (size_t)(e0 + er) * SEQ + l0 + l4) = o;
    }
}

// ---------------- generic bf16 transpose: in[R][C] -> out[C][R] -----------
__global__ void transpose_bf(const unsigned short* __restrict__ in,
                             unsigned short* __restrict__ outp, int R, int C) {
    __shared__ unsigned short tile[64][72];
    int r0 = blockIdx.x * 64, c0 = blockIdx.y * 64;
    int t = threadIdx.x;
    for (int c = t; c < 512; c += 256) {   // 64 rows x 8 chunks of 8
        int r = c >> 3, k = (c & 7) * 8;
        frag8 v = *(const frag8*)(in + (size_t)(r0 + r) * C + c0 + k);
        *(frag8*)(&tile[r][k]) = v;
    }
    __syncthreads();
    for (int c = t; c < 1024; c += 256) {  // 64 out-rows x 16 chunks of 4
        int cr = c >> 4, r4 = (c & 15) * 4;
        ushort4 o = { tile[r4][cr], tile[r4 + 1][cr], tile[r4 + 2][cr], tile[r4 + 3][cr] };
        *(ushort4*)(outp + (size_t)(c0 + cr) * R + r0 + r4) = o;
    }
}

// ---------------- Chunked selective scan (hybrid layout) ------------------
// deltaT fp32 [DI][SEQ]; xi2T/szT bf16 [DI][SEQ]; dbc fp32 [SEQ][160].
// passA runs chunks 0..NCHUNK-2 only: P[7]/hend[7] are never consumed.
__global__ void scan_passA(const float* __restrict__ deltaT, const unsigned short* __restrict__ xi2T,
                           const float* __restrict__ dbc, const float* __restrict__ A_log,
                           float* __restrict__ P, float* __restrict__ hend) {
    int wid = blockIdx.x * 4 + (threadIdx.x >> 6);
    int e = wid & (DI - 1);
    int c = wid >> 10;     // 0..NCHUNK-2
    int n = threadIdx.x & 63;
    float Ae = -__expf(A_log[e * DS + n]);
    float h = 0.f, sum_d = 0.f;
    int l0 = c * CHUNK;
    const float4* d4  = (const float4*)(deltaT + (size_t)e * SEQ + l0);
    const ushort4* x4 = (const ushort4*)(xi2T + (size_t)e * SEQ + l0);
    const float* dbg = dbc + (size_t)l0 * 160 + DR + n;
    for (int g = 0; g < CHUNK / 4; g++) {
        float4 dd = d4[g];
        ushort4 xx = x4[g];
#pragma unroll
        for (int j = 0; j < 4; j++) {
            float Bn = dbg[j * 160];
            float dj = (&dd.x)[j];
            float xj = bf2f((&xx.x)[j]);
            float dA = __expf(dj * Ae);
            h = fmaf(dA, h, (dj * xj) * Bn);
            sum_d += dj;
        }
        dbg += 640;
    }
    int idx = (c * DI + e) * DS + n;
    P[idx] = __expf(Ae * sum_d);
    hend[idx] = h;
}

// Carry: h_in[c] written into P[c] in-place. P/hend valid for c<NCHUNK-1;
// the last slot is write-only (passA never produced it).
__global__ void scan_carry(float* __restrict__ P, const float* __restrict__ hend) {
    int e = blockIdx.x * 4 + (threadIdx.x >> 6);
    int n = threadIdx.x & 63;
    float h = 0.f;
    for (int c = 0; c < NCHUNK; c++) {
        int idx = (c * DI + e) * DS + n;
        if (c < NCHUNK - 1) {
            float p  = P[idx];
            float he = hend[idx];
            P[idx] = h;
            h = fmaf(p, h, he);
        } else {
            P[idx] = h;
        }
    }
}

// Pass B: 6-DPP wave64 reduce; lane 63 holds total, gates and stores bf16 yT
// in-place over szT (read-before-write within owning wave).
__global__ void scan_passB(const float* __restrict__ deltaT, const unsigned short* __restrict__ xi2T,
                           const float* __restrict__ dbc, unsigned short* __restrict__ szyT,
                           const float* __restrict__ A_log, const float* __restrict__ Dp,
                           const float* __restrict__ hin) {
    int wid = blockIdx.x * 4 + (threadIdx.x >> 6);
    int e = wid & (DI - 1);
    int c = wid >> 10;
    int n = threadIdx.x & 63;
    float Ae = -__expf(A_log[e * DS + n]);
    float dp = Dp[e];
    float h = hin[(c * DI + e) * DS + n];
    int l0 = c * CHUNK;
    const float4* d4  = (const float4*)(deltaT + (size_t)e * SEQ + l0);
    const ushort4* x4 = (const ushort4*)(xi2T + (size_t)e * SEQ + l0);
    ushort4* s4       = (ushort4*)(szyT + (size_t)e * SEQ + l0);
    const float* dbg = dbc + (size_t)l0 * 160 + DR + n;
    for (int g = 0; g < CHUNK / 4; g++) {
        float4 dd = d4[g];
        ushort4 xx = x4[g], zz = s4[g];
        ushort4 yv;
#pragma unroll
        for (int j = 0; j < 4; j++) {
            float Bn = dbg[j * 160];
            float Cn = dbg[j * 160 + DS];
            float dj = (&dd.x)[j];
            float xj = bf2f((&xx.x)[j]);
            float dA = __expf(dj * Ae);
            h = fmaf(dA, h, (dj * xj) * Bn);
            float p = h * Cn;
            p = dppadd<0xB1>(p);   // quad_perm swap-1
            p = dppadd<0x4E>(p);   // quad_perm swap-2
            p = dppadd<0x141>(p);  // row_half_mirror
            p = dppadd<0x140>(p);  // row_mirror -> 16-lane row sums
            p = dppadd<0x142>(p);  // row_bcast15
            p = dppadd<0x143>(p);  // row_bcast31 -> lane 63 = total
            (&yv.x)[j] = f2bf((p + dp * xj) * bf2f((&zz.x)[j]));
        }
        dbg += 640;
        if (n == 63) s4[g] = yv;
    }
}

extern "C" void kernel_launch(void* const* d_in, const int* in_sizes, int n_in,
                              void* d_out, int out_size, void* d_ws, size_t ws_size,
                              hipStream_t stream) {
    const float* x      = (const float*)d_in[0];
    const float* ln_g   = (const float*)d_in[1];
    const float* ln_b   = (const float*)d_in[2];
    const float* Win    = (const float*)d_in[3];
    const float* conv_w = (const float*)d_in[4];
    const float* conv_b = (const float*)d_in[5];
    const float* Wx     = (const float*)d_in[6];
    const float* Wdt    = (const float*)d_in[7];
    const float* bdt    = (const float*)d_in[8];
    const float* A_log  = (const float*)d_in[9];
    const float* Dp     = (const float*)d_in[10];
    const float* Wout   = (const float*)d_in[11];
    float* out = (float*)d_out;

    // Workspace map (27 MB total; 30 MB proven safe):
    char* W = (char*)d_ws;
    unsigned short* xi_raw  = (unsigned short*)W;              // 4 MB (early)
    float*          deltaT  = (float*)W;                       // 8 MB (late, xi_raw dead)
    unsigned short* Win_bf  = (unsigned short*)(W + 8 * MB);   // 2 MB used (-> xi2bf -> y_bf)
    unsigned short* xi2bf   = (unsigned short*)(W + 8 * MB);
    unsigned short* y_bf    = (unsigned short*)(W + 8 * MB);
    unsigned short* szT     = (unsigned short*)(W + 12 * MB);  // 4 MB (-> yT in-place)
    unsigned short* xi2T    = (unsigned short*)(W + 16 * MB);  // 4 MB
    unsigned short* xn_bf   = (unsigned short*)(W + 20 * MB);  // 2 MB (-> Pbuf)
    float*          Pbuf    = (float*)(W + 20 * MB);
    unsigned short* Wout_bf = (unsigned short*)(W + 22 * MB);  // 1 MB
    unsigned short* Wx_bf   = (unsigned short*)(W + 23 * MB);  // 0.32 MB
    float*          dbc     = (float*)(W + 23 * MB + 512 * 1024); // 1.31 MB
    float*          hend    = (float*)(W + 25 * MB);           // 2 MB

    // 1. weights -> bf16. Element counts: Win 1,048,576 (R10/R11 crash was an
    //    OOB read from a wrong 2M constant here), Wx 163,840, Wout 524,288.
    cvt_weights<<<(1048576 + 163840 + 524288) / 1024, 256, 0, stream>>>(
        Win, Win_bf, 1048576, Wx, Wx_bf, 163840, Wout, Wout_bf, 524288);

    // 2. LayerNorm -> bf16 xn
    ln_kernel<<<SEQ, 256, 0, stream>>>(x, ln_g, ln_b, xn_bf);

    // 3. fused in-proj [2048 x 2048 x 512], 128x128 tile (256 blocks = 1/CU):
    //    lower half -> xi_raw bf16, upper half -> silu -> szT bf16 transposed
    gemm_bf128_inproj<<<dim3(SEQ / 128, 2048 / 128), 256, 0, stream>>>(
        xn_bf, DM, Win_bf, DM, DM, xi_raw, szT);

    // 4. fused conv + SiLU + transpose -> xi2bf [SEQ][DI] + xi2T [DI][SEQ]
    conv_t<<<dim3(SEQ / 64, DI / 64), 256, 0, stream>>>(xi_raw, conv_w, conv_b, xi2bf, xi2T);

    // 5. dbc = xi2 @ Wx^T  [SEQ][160] fp32
    gemm_bf<3><<<dim3(SEQ / 128, 3), 256, 0, stream>>>(
        xi2bf, DI, Wx_bf, DI, 160, DI, dbc, nullptr, 160);

    // 6. deltaT = softplus(dbc[:,:32] @ Wdt^T + bdt)^T  [DI][SEQ] fp32
    gemm_dt_t<<<dim3(SEQ / 64, DI / 64), 256, 0, stream>>>(dbc, Wdt, bdt, deltaT);

    // 7. chunked scan: A (chunks 0..6) -> carry -> B (bf16 yT in-place)
    scan_passA<<<(DI * (NCHUNK - 1)) / 4, 256, 0, stream>>>(deltaT, xi2T, dbc, A_log, Pbuf, hend);
    scan_carry<<<DI / 4, 256, 0, stream>>>(Pbuf, hend);
    scan_passB<<<(DI * NCHUNK) / 4, 256, 0, stream>>>(deltaT, xi2T, dbc, szT, A_log, Dp, Pbuf);

    // 8. y_bf = yT^T  [SEQ][DI] bf16
    transpose_bf<<<dim3(DI / 64, SEQ / 64), 256, 0, stream>>>(szT, y_bf, DI, SEQ);

    // 9. out = y @ Wout^T + x  fp32
    gemm_bf<2><<<dim3(SEQ / 128, DM / 64), 256, 0, stream>>>(
        y_bf, DI, Wout_bf, DI, DM, DI, out, x, DM);
}

// Round 14
// 297.715 us; speedup vs baseline: 2.0879x; 1.0214x over previous
//
#include <hip/hip_runtime.h>
#include <hip/hip_bf16.h>
#include <cstddef>

#define SEQ 2048
#define DM  512
#define DI  1024   // d_inner
#define DR  32     // dt_rank
#define DS  64     // d_state
#define NCHUNK 8
#define CHUNK  256 // SEQ / NCHUNK
#define MB (1024 * 1024)
#define NCVT 1696  // blocks for weight conversion part of cvt_ln

typedef __attribute__((ext_vector_type(4))) float f32x4;
typedef __attribute__((ext_vector_type(8))) short frag8;

// round-to-nearest-even f32 -> bf16 raw bits (finite inputs)
__device__ __forceinline__ unsigned short f2bf(float f) {
    unsigned u = __float_as_uint(f);
    unsigned r = (u + 0x7fffu + ((u >> 16) & 1u)) >> 16;
    return (unsigned short)r;
}
__device__ __forceinline__ float bf2f(unsigned short u) {
    return __int_as_float(((int)u) << 16);
}

// hardware exp2 (v_exp_f32)
__device__ __forceinline__ float fexp2(float x) {
#if __has_builtin(__builtin_amdgcn_exp2f)
    return __builtin_amdgcn_exp2f(x);
#else
    return exp2f(x);
#endif
}
#define LOG2E 1.44269504088896f

// p + dpp_permute(p), compile-time DPP control
template <int CTRL>
__device__ __forceinline__ float dppadd(float p) {
    return p + __int_as_float(
        __builtin_amdgcn_update_dpp(0, __float_as_int(p), CTRL, 0xF, 0xF, true));
}

// ---------------- fused: weights->bf16 (blocks < NCVT) + LayerNorm --------
// Sizes: Win 1,048,576; Wx 163,840; Wout 524,288 -> total 1,736,704 = NCVT*1024.
__global__ void cvt_ln(const float* __restrict__ w1, unsigned short* __restrict__ o1,
                       const float* __restrict__ w2, unsigned short* __restrict__ o2,
                       const float* __restrict__ w3, unsigned short* __restrict__ o3,
                       const float* __restrict__ x, const float* __restrict__ g,
                       const float* __restrict__ b, unsigned short* __restrict__ xn) {
    if (blockIdx.x < NCVT) {
        const int n1 = 1048576, n2 = 163840, n3 = 524288;
        int i = (blockIdx.x * 256 + threadIdx.x) * 4;
        const float* s; unsigned short* d; int off;
        if (i < n1) { s = w1; d = o1; off = i; }
        else if (i < n1 + n2) { s = w2; d = o2; off = i - n1; }
        else if (i < n1 + n2 + n3) { s = w3; d = o3; off = i - n1 - n2; }
        else return;
        float4 v = *(const float4*)(s + off);
        ushort4 o = { f2bf(v.x), f2bf(v.y), f2bf(v.z), f2bf(v.w) };
        *(ushort4*)(d + off) = o;
        return;
    }
    int l = blockIdx.x - NCVT;
    int t = threadIdx.x;
    __shared__ float red[256];
    float v0 = x[l * DM + t];
    float v1 = x[l * DM + t + 256];
    red[t] = v0 + v1;
    __syncthreads();
    for (int o = 128; o > 0; o >>= 1) { if (t < o) red[t] += red[t + o]; __syncthreads(); }
    float mu = red[0] * (1.f / DM);
    __syncthreads();
    float c0 = v0 - mu, c1 = v1 - mu;
    red[t] = c0 * c0 + c1 * c1;
    __syncthreads();
    for (int o = 128; o > 0; o >>= 1) { if (t < o) red[t] += red[t + o]; __syncthreads(); }
    float rstd = rsqrtf(red[0] * (1.f / DM) + 1e-5f);
    xn[l * DM + t]       = f2bf(c0 * rstd * g[t]       + b[t]);
    xn[l * DM + t + 256] = f2bf(c1 * rstd * g[t + 256] + b[t + 256]);
}

#define LDK 40

// ---------------- 128x128 bf16 MFMA GEMM (in-proj only) -------------------
// Split epilogue: n < DI -> bf16 out1 [M][DI]; n >= DI -> silu -> bf16
// transposed out2 [DI][SEQ]. Tile-uniform branch (DI multiple of 128).
__global__ void gemm_bf128_inproj(const unsigned short* __restrict__ A, int lda,
                                  const unsigned short* __restrict__ B, int ldb,
                                  int K,
                                  unsigned short* __restrict__ outB1,
                                  unsigned short* __restrict__ outB2) {
    __shared__ unsigned short As[128 * LDK];
    __shared__ unsigned short Bs[128 * LDK];
    int t = threadIdx.x;
    int lane = t & 63;
    int wv = t >> 6;
    int wm = (wv >> 1) * 64;
    int wn = (wv & 1) * 64;
    int m0 = blockIdx.x * 128, n0 = blockIdx.y * 128;

    f32x4 acc[4][4];
#pragma unroll
    for (int i = 0; i < 4; i++)
#pragma unroll
        for (int j = 0; j < 4; j++) acc[i][j] = (f32x4){0.f, 0.f, 0.f, 0.f};

    int lm = lane & 15;
    int kq = (lane >> 4) * 8;

    for (int k0 = 0; k0 < K; k0 += 32) {
#pragma unroll
        for (int j = 0; j < 2; j++) {
            int c = t + j * 256;
            int m = c >> 2;
            int k = (c & 3) * 8;
            frag8 va = *(const frag8*)(A + (size_t)(m0 + m) * lda + k0 + k);
            *(frag8*)(&As[m * LDK + k]) = va;
            frag8 vb = *(const frag8*)(B + (size_t)(n0 + m) * ldb + k0 + k);
            *(frag8*)(&Bs[m * LDK + k]) = vb;
        }
        __syncthreads();

        frag8 af[4], bfr[4];
#pragma unroll
        for (int mt = 0; mt < 4; mt++)
            af[mt] = *(const frag8*)(&As[(wm + mt * 16 + lm) * LDK + kq]);
#pragma unroll
        for (int nt = 0; nt < 4; nt++)
            bfr[nt] = *(const frag8*)(&Bs[(wn + nt * 16 + lm) * LDK + kq]);
#pragma unroll
        for (int mt = 0; mt < 4; mt++)
#pragma unroll
            for (int nt = 0; nt < 4; nt++)
                acc[mt][nt] = __builtin_amdgcn_mfma_f32_16x16x32_bf16(
                    af[mt], bfr[nt], acc[mt][nt], 0, 0, 0);
        __syncthreads();
    }

    int rbase = (lane >> 4) * 4;
    bool lower = (n0 < DI);
#pragma unroll
    for (int mt = 0; mt < 4; mt++) {
#pragma unroll
        for (int nt = 0; nt < 4; nt++) {
            int n = n0 + wn + nt * 16 + lm;
            int mb = m0 + wm + mt * 16 + rbase;
            if (lower) {
#pragma unroll
                for (int r = 0; r < 4; r++)
                    outB1[(size_t)(mb + r) * DI + n] = f2bf(acc[mt][nt][r]);
            } else {
                int nn = n - DI;
                ushort4 o;
#pragma unroll
                for (int r = 0; r < 4; r++) {
                    float v = acc[mt][nt][r];
                    v = v / (1.f + __expf(-v));
                    (&o.x)[r] = f2bf(v);
                }
                *(ushort4*)(outB2 + (size_t)nn * SEQ + mb) = o;
            }
        }
    }
}

// ---------------- 128x64 bf16 MFMA GEMM (x-proj / out-proj) ---------------
// EPI 2: fp32 + residual -> outF.
// EPI 4: x-proj split: n<32 -> fp32 dtc [SEQ][32]; 32<=n<96 -> bf16 B at
//        bci[m][2(n-32)]; 96<=n<160 -> bf16 C at bci[m][2(n-96)+1].
template <int EPI>
__global__ void gemm_bf(const unsigned short* __restrict__ A, int lda,
                        const unsigned short* __restrict__ B, int ldb,
                        int N, int K,
                        float* __restrict__ outF, const float* __restrict__ res, int ldo,
                        float* __restrict__ dtc, unsigned short* __restrict__ bci) {
    __shared__ unsigned short As[128 * LDK];
    __shared__ unsigned short Bs[64 * LDK];
    int t = threadIdx.x;
    int lane = t & 63;
    int wv = t >> 6;
    int wm = (wv >> 1) * 64;
    int wn = (wv & 1) * 32;
    int m0 = blockIdx.x * 128, n0 = blockIdx.y * 64;

    f32x4 acc[4][2];
#pragma unroll
    for (int i = 0; i < 4; i++)
#pragma unroll
        for (int j = 0; j < 2; j++) acc[i][j] = (f32x4){0.f, 0.f, 0.f, 0.f};

    int lm = lane & 15;
    int kq = (lane >> 4) * 8;

    for (int k0 = 0; k0 < K; k0 += 32) {
#pragma unroll
        for (int j = 0; j < 2; j++) {
            int c = t + j * 256;
            int m = c >> 2;
            int k = (c & 3) * 8;
            frag8 v = *(const frag8*)(A + (size_t)(m0 + m) * lda + k0 + k);
            *(frag8*)(&As[m * LDK + k]) = v;
        }
        {
            int m = t >> 2;
            int k = (t & 3) * 8;
            int gn = n0 + m;
            frag8 v = {0, 0, 0, 0, 0, 0, 0, 0};
            if (gn < N) v = *(const frag8*)(B + (size_t)gn * ldb + k0 + k);
            *(frag8*)(&Bs[m * LDK + k]) = v;
        }
        __syncthreads();

        frag8 af[4], bfr[2];
#pragma unroll
        for (int mt = 0; mt < 4; mt++)
            af[mt] = *(const frag8*)(&As[(wm + mt * 16 + lm) * LDK + kq]);
#pragma unroll
        for (int nt = 0; nt < 2; nt++)
            bfr[nt] = *(const frag8*)(&Bs[(wn + nt * 16 + lm) * LDK + kq]);
#pragma unroll
        for (int mt = 0; mt < 4; mt++)
#pragma unroll
            for (int nt = 0; nt < 2; nt++)
                acc[mt][nt] = __builtin_amdgcn_mfma_f32_16x16x32_bf16(
                    af[mt], bfr[nt], acc[mt][nt], 0, 0, 0);
        __syncthreads();
    }

    int rbase = (lane >> 4) * 4;
#pragma unroll
    for (int mt = 0; mt < 4; mt++) {
#pragma unroll
        for (int nt = 0; nt < 2; nt++) {
            int n = n0 + wn + nt * 16 + lm;
            int mb = m0 + wm + mt * 16 + rbase;
            if (EPI == 2) {
                if (n < N) {
#pragma unroll
                    for (int r = 0; r < 4; r++)
                        outF[(size_t)(mb + r) * ldo + n] =
                            acc[mt][nt][r] + res[(size_t)(mb + r) * ldo + n];
                }
            } else { // EPI == 4
                if (n < 32) {
#pragma unroll
                    for (int r = 0; r < 4; r++)
                        dtc[(size_t)(mb + r) * 32 + n] = acc[mt][nt][r];
                } else if (n < 96) {
                    int col = 2 * (n - 32);
#pragma unroll
                    for (int r = 0; r < 4; r++)
                        bci[(size_t)(mb + r) * 128 + col] = f2bf(acc[mt][nt][r]);
                } else if (n < 160) {
                    int col = 2 * (n - 96) + 1;
#pragma unroll
                    for (int r = 0; r < 4; r++)
                        bci[(size_t)(mb + r) * 128 + col] = f2bf(acc[mt][nt][r]);
                }
            }
        }
    }
}

// ---------------- dt-proj vector GEMM, transposed store (fp32) ------------
__global__ void gemm_dt_t(const float* __restrict__ A,   // dtc [SEQ][32]
                          const float* __restrict__ B,   // Wdt [DI][DR]
                          const float* __restrict__ bias,
                          float* __restrict__ outT) {    // deltaT [DI][SEQ]
    __shared__ float As[16][65];
    __shared__ float Bs[16][65];
    int tid = threadIdx.x;
    int tx = tid & 15, ty = tid >> 4;
    int bm = blockIdx.x * 64, bn = blockIdx.y * 64;   // bm: l, bn: e
    float acc[4][4] = {};
    int kk = tid & 15;
    int rr = tid >> 4;
    for (int k0 = 0; k0 < DR; k0 += 16) {
#pragma unroll
        for (int i = 0; i < 4; i++)
            As[kk][rr + 16 * i] = A[(size_t)(bm + rr + 16 * i) * 32 + k0 + kk];
#pragma unroll
        for (int i = 0; i < 4; i++)
            Bs[kk][rr + 16 * i] = B[(size_t)(bn + rr + 16 * i) * DR + k0 + kk];
        __syncthreads();
#pragma unroll
        for (int k = 0; k < 16; k++) {
            float a[4], bb[4];
#pragma unroll
            for (int i = 0; i < 4; i++) a[i] = As[k][ty * 4 + i];
#pragma unroll
            for (int j = 0; j < 4; j++) bb[j] = Bs[k][tx * 4 + j];
#pragma unroll
            for (int i = 0; i < 4; i++)
#pragma unroll
                for (int j = 0; j < 4; j++)
                    acc[i][j] = fmaf(a[i], bb[j], acc[i][j]);
        }
        __syncthreads();
    }
#pragma unroll
    for (int j = 0; j < 4; j++) {
        int e = bn + tx * 4 + j;
        float bv = bias[e];
        float4 o;
#pragma unroll
        for (int i = 0; i < 4; i++) {
            float v = acc[i][j] + bv;
            v = (v > 20.f) ? v : __logf(1.f + __expf(v));
            (&o.x)[i] = v;
        }
        *(float4*)(outT + (size_t)e * SEQ + bm + ty * 4) = o;
    }
}

// ---------------- fused conv(w=4, causal) + bias + SiLU + transpose -------
__global__ void conv_t(const unsigned short* __restrict__ xi_raw,
                       const float* __restrict__ w, const float* __restrict__ cb,
                       unsigned short* __restrict__ xi2bf, unsigned short* __restrict__ xi2T) {
    __shared__ float tin[67][72];
    __shared__ float tout[64][65];
    int l0 = blockIdx.x * 64, e0 = blockIdx.y * 64;
    int t = threadIdx.x;
    for (int c = t; c < 536; c += 256) {      // 67 rows x 8 chunks of 8
        int r = c >> 3, ke = (c & 7) * 8;
        int l = l0 - 3 + r;
        frag8 v = {0, 0, 0, 0, 0, 0, 0, 0};
        if (l >= 0) v = *(const frag8*)(xi_raw + (size_t)l * DI + e0 + ke);
#pragma unroll
        for (int i = 0; i < 8; i++) tin[r][ke + i] = bf2f((unsigned short)v[i]);
    }
    __syncthreads();
    int e_loc = t & 63;
    int e = e0 + e_loc;
    float4 wv = *(const float4*)(w + e * 4);
    float bias = cb[e];
#pragma unroll 4
    for (int i = 0; i < 16; i++) {
        int l_loc = (t >> 6) + i * 4;
        float acc = bias;
        acc = fmaf(wv.x, tin[l_loc][e_loc], acc);
        acc = fmaf(wv.y, tin[l_loc + 1][e_loc], acc);
        acc = fmaf(wv.z, tin[l_loc + 2][e_loc], acc);
        acc = fmaf(wv.w, tin[l_loc + 3][e_loc], acc);
        float s = acc / (1.f + __expf(-acc));
        tout[l_loc][e_loc] = s;
        xi2bf[(size_t)(l0 + l_loc) * DI + e] = f2bf(s);
    }
    __syncthreads();
    for (int c = t; c < 1024; c += 256) {     // 64 e-rows x 16 l-chunks of 4
        int er = c >> 4, l4 = (c & 15) * 4;
        ushort4 o = { f2bf(tout[l4][er]), f2bf(tout[l4 + 1][er]),
                      f2bf(tout[l4 + 2][er]), f2bf(tout[l4 + 3][er]) };
        *(ushort4*)(xi2T + (size_t)(e0 + er) * SEQ + l0 + l4) = o;
    }
}

// ---------------- generic bf16 transpose: in[R][C] -> out[C][R] -----------
__global__ void transpose_bf(const unsigned short* __restrict__ in,
                             unsigned short* __restrict__ outp, int R, int C) {
    __shared__ unsigned short tile[64][72];
    int r0 = blockIdx.x * 64, c0 = blockIdx.y * 64;
    int t = threadIdx.x;
    for (int c = t; c < 512; c += 256) {
        int r = c >> 3, k = (c & 7) * 8;
        frag8 v = *(const frag8*)(in + (size_t)(r0 + r) * C + c0 + k);
        *(frag8*)(&tile[r][k]) = v;
    }
    __syncthreads();
    for (int c = t; c < 1024; c += 256) {
        int cr = c >> 4, r4 = (c & 15) * 4;
        ushort4 o = { tile[r4][cr], tile[r4 + 1][cr], tile[r4 + 2][cr], tile[r4 + 3][cr] };
        *(ushort4*)(outp + (size_t)(c0 + cr) * R + r0 + r4) = o;
    }
}

// ---------------- Chunked selective scan ----------------------------------
// deltaT fp32 [DI][SEQ]; xi2T/szT bf16 [DI][SEQ]; bci bf16 interleaved
// [SEQ][128] (lane n: one dword = {B_n, C_n}). passA: chunks 0..NCHUNK-2.
__global__ void scan_passA(const float* __restrict__ deltaT, const unsigned short* __restrict__ xi2T,
                           const unsigned short* __restrict__ bci, const float* __restrict__ A_log,
                           float* __restrict__ P, float* __restrict__ hend) {
    int wid = blockIdx.x * 4 + (threadIdx.x >> 6);
    int e = wid & (DI - 1);
    int c = wid >> 10;
    int n = threadIdx.x & 63;
    float Ae2 = -__expf(A_log[e * DS + n]) * LOG2E;   // exp(d*Ae) = exp2(d*Ae2)
    float h = 0.f, sum_d = 0.f;
    int l0 = c * CHUNK;
    const float4* d4  = (const float4*)(deltaT + (size_t)e * SEQ + l0);
    const ushort4* x4 = (const ushort4*)(xi2T + (size_t)e * SEQ + l0);
    const unsigned* bc = (const unsigned*)bci + (size_t)l0 * 64 + n;
    for (int g = 0; g < CHUNK / 4; g++) {
        float4 dd = d4[g];
        ushort4 xx = x4[g];
#pragma unroll
        for (int j = 0; j < 4; j++) {
            unsigned bcv = bc[j * 64];
            float Bn = __int_as_float(bcv << 16);
            float dj = (&dd.x)[j];
            float xj = bf2f((&xx.x)[j]);
            float dA = fexp2(dj * Ae2);
            h = fmaf(dA, h, (dj * xj) * Bn);
            sum_d += dj;
        }
        bc += 256;
    }
    int idx = (c * DI + e) * DS + n;
    P[idx] = fexp2(Ae2 * sum_d);
    hend[idx] = h;
}

// Carry: h_in[c] written into P[c] in-place; last slot write-only.
__global__ void scan_carry(float* __restrict__ P, const float* __restrict__ hend) {
    int e = blockIdx.x * 4 + (threadIdx.x >> 6);
    int n = threadIdx.x & 63;
    float h = 0.f;
    for (int c = 0; c < NCHUNK; c++) {
        int idx = (c * DI + e) * DS + n;
        if (c < NCHUNK - 1) {
            float p  = P[idx];
            float he = hend[idx];
            P[idx] = h;
            h = fmaf(p, h, he);
        } else {
            P[idx] = h;
        }
    }
}

// Pass B: 6-DPP wave64 reduce; lane 63 gates and stores bf16 yT in-place.
__global__ void scan_passB(const float* __restrict__ deltaT, const unsigned short* __restrict__ xi2T,
                           const unsigned short* __restrict__ bci, unsigned short* __restrict__ szyT,
                           const float* __restrict__ A_log, const float* __restrict__ Dp,
                           const float* __restrict__ hin) {
    int wid = blockIdx.x * 4 + (threadIdx.x >> 6);
    int e = wid & (DI - 1);
    int c = wid >> 10;
    int n = threadIdx.x & 63;
    float Ae2 = -__expf(A_log[e * DS + n]) * LOG2E;
    float dp = Dp[e];
    float h = hin[(c * DI + e) * DS + n];
    int l0 = c * CHUNK;
    const float4* d4  = (const float4*)(deltaT + (size_t)e * SEQ + l0);
    const ushort4* x4 = (const ushort4*)(xi2T + (size_t)e * SEQ + l0);
    ushort4* s4       = (ushort4*)(szyT + (size_t)e * SEQ + l0);
    const unsigned* bc = (const unsigned*)bci + (size_t)l0 * 64 + n;
    for (int g = 0; g < CHUNK / 4; g++) {
        float4 dd = d4[g];
        ushort4 xx = x4[g], zz = s4[g];
        ushort4 yv;
#pragma unroll
        for (int j = 0; j < 4; j++) {
            unsigned bcv = bc[j * 64];
            float Bn = __int_as_float(bcv << 16);
            float Cn = __int_as_float(bcv & 0xffff0000u);
            float dj = (&dd.x)[j];
            float xj = bf2f((&xx.x)[j]);
            float dA = fexp2(dj * Ae2);
            h = fmaf(dA, h, (dj * xj) * Bn);
            float p = h * Cn;
            p = dppadd<0xB1>(p);   // quad_perm swap-1
            p = dppadd<0x4E>(p);   // quad_perm swap-2
            p = dppadd<0x141>(p);  // row_half_mirror
            p = dppadd<0x140>(p);  // row_mirror -> 16-lane row sums
            p = dppadd<0x142>(p);  // row_bcast15
            p = dppadd<0x143>(p);  // row_bcast31 -> lane 63 = total
            (&yv.x)[j] = f2bf((p + dp * xj) * bf2f((&zz.x)[j]));
        }
        bc += 256;
        if (n == 63) s4[g] = yv;
    }
}

extern "C" void kernel_launch(void* const* d_in, const int* in_sizes, int n_in,
                              void* d_out, int out_size, void* d_ws, size_t ws_size,
                              hipStream_t stream) {
    const float* x      = (const float*)d_in[0];
    const float* ln_g   = (const float*)d_in[1];
    const float* ln_b   = (const float*)d_in[2];
    const float* Win    = (const float*)d_in[3];
    const float* conv_w = (const float*)d_in[4];
    const float* conv_b = (const float*)d_in[5];
    const float* Wx     = (const float*)d_in[6];
    const float* Wdt    = (const float*)d_in[7];
    const float* bdt    = (const float*)d_in[8];
    const float* A_log  = (const float*)d_in[9];
    const float* Dp     = (const float*)d_in[10];
    const float* Wout   = (const float*)d_in[11];
    float* out = (float*)d_out;

    // Workspace map (<= 27 MB; 30 MB proven safe):
    char* W = (char*)d_ws;
    unsigned short* xi_raw  = (unsigned short*)W;              // 4 MB (early)
    float*          deltaT  = (float*)W;                       // 8 MB (late, xi_raw dead)
    unsigned short* Win_bf  = (unsigned short*)(W + 8 * MB);   // 2 MB (-> xi2bf -> y_bf)
    unsigned short* xi2bf   = (unsigned short*)(W + 8 * MB);
    unsigned short* y_bf    = (unsigned short*)(W + 8 * MB);
    unsigned short* szT     = (unsigned short*)(W + 12 * MB);  // 4 MB (-> yT in-place)
    unsigned short* xi2T    = (unsigned short*)(W + 16 * MB);  // 4 MB
    unsigned short* xn_bf   = (unsigned short*)(W + 20 * MB);  // 2 MB (-> Pbuf)
    float*          Pbuf    = (float*)(W + 20 * MB);
    unsigned short* Wout_bf = (unsigned short*)(W + 22 * MB);  // 1 MB
    unsigned short* Wx_bf   = (unsigned short*)(W + 23 * MB);  // 0.32 MB
    float*          dtc     = (float*)(W + 23 * MB + 512 * 1024);       // 256 KB
    unsigned short* bci     = (unsigned short*)(W + 23 * MB + 768 * 1024); // 512 KB
    float*          hend    = (float*)(W + 25 * MB);           // 2 MB

    // 1. fused: weights -> bf16 (Win 1,048,576 / Wx 163,840 / Wout 524,288;
    //    the R10/R11 crash was an OOB from a wrong 2M Win constant) + LayerNorm.
    cvt_ln<<<NCVT + SEQ, 256, 0, stream>>>(Win, Win_bf, Wx, Wx_bf, Wout, Wout_bf,
                                           x, ln_g, ln_b, xn_bf);

    // 2. fused in-proj [2048 x 2048 x 512], 128x128 tile: lower half ->
    //    xi_raw bf16, upper half -> silu -> szT bf16 transposed
    gemm_bf128_inproj<<<dim3(SEQ / 128, 2048 / 128), 256, 0, stream>>>(
        xn_bf, DM, Win_bf, DM, DM, xi_raw, szT);

    // 3. fused conv + SiLU + transpose -> xi2bf [SEQ][DI] + xi2T [DI][SEQ]
    conv_t<<<dim3(SEQ / 64, DI / 64), 256, 0, stream>>>(xi_raw, conv_w, conv_b, xi2bf, xi2T);

    // 4. x-proj split epilogue: dtc fp32 [SEQ][32] + bci bf16 interleaved [SEQ][128]
    gemm_bf<4><<<dim3(SEQ / 128, 3), 256, 0, stream>>>(
        xi2bf, DI, Wx_bf, DI, 160, DI, nullptr, nullptr, 0, dtc, bci);

    // 5. deltaT = softplus(dtc @ Wdt^T + bdt)^T  [DI][SEQ] fp32
    gemm_dt_t<<<dim3(SEQ / 64, DI / 64), 256, 0, stream>>>(dtc, Wdt, bdt, deltaT);

    // 6. chunked scan: A (chunks 0..6) -> carry -> B (bf16 yT in-place)
    scan_passA<<<(DI * (NCHUNK - 1)) / 4, 256, 0, stream>>>(deltaT, xi2T, bci, A_log, Pbuf, hend);
    scan_carry<<<DI / 4, 256, 0, stream>>>(Pbuf, hend);
    scan_passB<<<(DI * NCHUNK) / 4, 256, 0, stream>>>(deltaT, xi2T, bci, szT, A_log, Dp, Pbuf);

    // 7. y_bf = yT^T  [SEQ][DI] bf16
    transpose_bf<<<dim3(DI / 64, SEQ / 64), 256, 0, stream>>>(szT, y_bf, DI, SEQ);

    // 8. out = y @ Wout^T + x  fp32
    gemm_bf<2><<<dim3(SEQ / 128, DM / 64), 256, 0, stream>>>(
        y_bf, DI, Wout_bf, DI, DM, DI, out, x, DM, nullptr, nullptr);
}

// Round 15
// 292.956 us; speedup vs baseline: 2.1218x; 1.0162x over previous
//
#include <hip/hip_runtime.h>
#include <hip/hip_bf16.h>
#include <cstddef>

#define SEQ 2048
#define DM  512
#define DI  1024   // d_inner
#define DR  32     // dt_rank
#define DS  64     // d_state
#define NCHUNK 8
#define CHUNK  256 // SEQ / NCHUNK
#define MB (1024 * 1024)
#define NCVT 1696  // blocks for weight conversion part of cvt_ln

typedef __attribute__((ext_vector_type(4))) float f32x4;
typedef __attribute__((ext_vector_type(8))) short frag8;

// round-to-nearest-even f32 -> bf16 raw bits (finite inputs)
__device__ __forceinline__ unsigned short f2bf(float f) {
    unsigned u = __float_as_uint(f);
    unsigned r = (u + 0x7fffu + ((u >> 16) & 1u)) >> 16;
    return (unsigned short)r;
}
__device__ __forceinline__ float bf2f(unsigned short u) {
    return __int_as_float(((int)u) << 16);
}

// hardware exp2 (v_exp_f32)
__device__ __forceinline__ float fexp2(float x) {
#if __has_builtin(__builtin_amdgcn_exp2f)
    return __builtin_amdgcn_exp2f(x);
#else
    return exp2f(x);
#endif
}
#define LOG2E 1.44269504088896f

// p + dpp_permute(p), compile-time DPP control
template <int CTRL>
__device__ __forceinline__ float dppadd(float p) {
    return p + __int_as_float(
        __builtin_amdgcn_update_dpp(0, __float_as_int(p), CTRL, 0xF, 0xF, true));
}

// ---------------- fused: weights->bf16 (blocks < NCVT) + LayerNorm --------
// Sizes: Win 1,048,576; Wx 163,840; Wout 524,288 -> total 1,736,704 = NCVT*1024.
__global__ void cvt_ln(const float* __restrict__ w1, unsigned short* __restrict__ o1,
                       const float* __restrict__ w2, unsigned short* __restrict__ o2,
                       const float* __restrict__ w3, unsigned short* __restrict__ o3,
                       const float* __restrict__ x, const float* __restrict__ g,
                       const float* __restrict__ b, unsigned short* __restrict__ xn) {
    if (blockIdx.x < NCVT) {
        const int n1 = 1048576, n2 = 163840, n3 = 524288;
        int i = (blockIdx.x * 256 + threadIdx.x) * 4;
        const float* s; unsigned short* d; int off;
        if (i < n1) { s = w1; d = o1; off = i; }
        else if (i < n1 + n2) { s = w2; d = o2; off = i - n1; }
        else if (i < n1 + n2 + n3) { s = w3; d = o3; off = i - n1 - n2; }
        else return;
        float4 v = *(const float4*)(s + off);
        ushort4 o = { f2bf(v.x), f2bf(v.y), f2bf(v.z), f2bf(v.w) };
        *(ushort4*)(d + off) = o;
        return;
    }
    int l = blockIdx.x - NCVT;
    int t = threadIdx.x;
    __shared__ float red[256];
    float v0 = x[l * DM + t];
    float v1 = x[l * DM + t + 256];
    red[t] = v0 + v1;
    __syncthreads();
    for (int o = 128; o > 0; o >>= 1) { if (t < o) red[t] += red[t + o]; __syncthreads(); }
    float mu = red[0] * (1.f / DM);
    __syncthreads();
    float c0 = v0 - mu, c1 = v1 - mu;
    red[t] = c0 * c0 + c1 * c1;
    __syncthreads();
    for (int o = 128; o > 0; o >>= 1) { if (t < o) red[t] += red[t + o]; __syncthreads(); }
    float rstd = rsqrtf(red[0] * (1.f / DM) + 1e-5f);
    xn[l * DM + t]       = f2bf(c0 * rstd * g[t]       + b[t]);
    xn[l * DM + t + 256] = f2bf(c1 * rstd * g[t + 256] + b[t + 256]);
}

#define LDK 40

// ---------------- 128x64 bf16 MFMA GEMM ------------------------------------
// EPI 1: in-proj split (N=2048): n<DI -> bf16 outB1 [M][DI]; n>=DI -> silu ->
//        bf16 transposed outB2 [DI][SEQ].
// EPI 2: fp32 + residual -> outF.
// EPI 4: x-proj split: n<32 -> fp32 dtc [SEQ][32]; 32<=n<96 -> bf16 B at
//        bci[m][2(n-32)]; 96<=n<160 -> bf16 C at bci[m][2(n-96)+1].
// __launch_bounds__(256,2): 2 waves/EU min -> 2 blocks/CU schedulable.
template <int EPI>
__global__ __launch_bounds__(256, 2)
void gemm_bf(const unsigned short* __restrict__ A, int lda,
             const unsigned short* __restrict__ B, int ldb,
             int N, int K,
             float* __restrict__ outF, const float* __restrict__ res, int ldo,
             float* __restrict__ dtc, unsigned short* __restrict__ bci,
             unsigned short* __restrict__ outB1, unsigned short* __restrict__ outB2) {
    __shared__ unsigned short As[128 * LDK];
    __shared__ unsigned short Bs[64 * LDK];
    int t = threadIdx.x;
    int lane = t & 63;
    int wv = t >> 6;
    int wm = (wv >> 1) * 64;
    int wn = (wv & 1) * 32;
    int m0 = blockIdx.x * 128, n0 = blockIdx.y * 64;

    f32x4 acc[4][2];
#pragma unroll
    for (int i = 0; i < 4; i++)
#pragma unroll
        for (int j = 0; j < 2; j++) acc[i][j] = (f32x4){0.f, 0.f, 0.f, 0.f};

    int lm = lane & 15;
    int kq = (lane >> 4) * 8;

    for (int k0 = 0; k0 < K; k0 += 32) {
#pragma unroll
        for (int j = 0; j < 2; j++) {
            int c = t + j * 256;
            int m = c >> 2;
            int k = (c & 3) * 8;
            frag8 v = *(const frag8*)(A + (size_t)(m0 + m) * lda + k0 + k);
            *(frag8*)(&As[m * LDK + k]) = v;
        }
        {
            int m = t >> 2;
            int k = (t & 3) * 8;
            int gn = n0 + m;
            frag8 v = {0, 0, 0, 0, 0, 0, 0, 0};
            if (gn < N) v = *(const frag8*)(B + (size_t)gn * ldb + k0 + k);
            *(frag8*)(&Bs[m * LDK + k]) = v;
        }
        __syncthreads();

        frag8 af[4], bfr[2];
#pragma unroll
        for (int mt = 0; mt < 4; mt++)
            af[mt] = *(const frag8*)(&As[(wm + mt * 16 + lm) * LDK + kq]);
#pragma unroll
        for (int nt = 0; nt < 2; nt++)
            bfr[nt] = *(const frag8*)(&Bs[(wn + nt * 16 + lm) * LDK + kq]);
#pragma unroll
        for (int mt = 0; mt < 4; mt++)
#pragma unroll
            for (int nt = 0; nt < 2; nt++)
                acc[mt][nt] = __builtin_amdgcn_mfma_f32_16x16x32_bf16(
                    af[mt], bfr[nt], acc[mt][nt], 0, 0, 0);
        __syncthreads();
    }

    int rbase = (lane >> 4) * 4;
#pragma unroll
    for (int mt = 0; mt < 4; mt++) {
#pragma unroll
        for (int nt = 0; nt < 2; nt++) {
            int n = n0 + wn + nt * 16 + lm;
            int mb = m0 + wm + mt * 16 + rbase;
            if (EPI == 1) {
                if (n < DI) {
#pragma unroll
                    for (int r = 0; r < 4; r++)
                        outB1[(size_t)(mb + r) * DI + n] = f2bf(acc[mt][nt][r]);
                } else {
                    int nn = n - DI;
                    ushort4 o;
#pragma unroll
                    for (int r = 0; r < 4; r++) {
                        float v = acc[mt][nt][r];
                        v = v / (1.f + __expf(-v));
                        (&o.x)[r] = f2bf(v);
                    }
                    *(ushort4*)(outB2 + (size_t)nn * SEQ + mb) = o;
                }
            } else if (EPI == 2) {
                if (n < N) {
#pragma unroll
                    for (int r = 0; r < 4; r++)
                        outF[(size_t)(mb + r) * ldo + n] =
                            acc[mt][nt][r] + res[(size_t)(mb + r) * ldo + n];
                }
            } else { // EPI == 4
                if (n < 32) {
#pragma unroll
                    for (int r = 0; r < 4; r++)
                        dtc[(size_t)(mb + r) * 32 + n] = acc[mt][nt][r];
                } else if (n < 96) {
                    int col = 2 * (n - 32);
#pragma unroll
                    for (int r = 0; r < 4; r++)
                        bci[(size_t)(mb + r) * 128 + col] = f2bf(acc[mt][nt][r]);
                } else if (n < 160) {
                    int col = 2 * (n - 96) + 1;
#pragma unroll
                    for (int r = 0; r < 4; r++)
                        bci[(size_t)(mb + r) * 128 + col] = f2bf(acc[mt][nt][r]);
                }
            }
        }
    }
}

// ---------------- dt-proj vector GEMM, transposed store (fp32) ------------
__global__ void gemm_dt_t(const float* __restrict__ A,   // dtc [SEQ][32]
                          const float* __restrict__ B,   // Wdt [DI][DR]
                          const float* __restrict__ bias,
                          float* __restrict__ outT) {    // deltaT [DI][SEQ]
    __shared__ float As[16][65];
    __shared__ float Bs[16][65];
    int tid = threadIdx.x;
    int tx = tid & 15, ty = tid >> 4;
    int bm = blockIdx.x * 64, bn = blockIdx.y * 64;   // bm: l, bn: e
    float acc[4][4] = {};
    int kk = tid & 15;
    int rr = tid >> 4;
    for (int k0 = 0; k0 < DR; k0 += 16) {
#pragma unroll
        for (int i = 0; i < 4; i++)
            As[kk][rr + 16 * i] = A[(size_t)(bm + rr + 16 * i) * 32 + k0 + kk];
#pragma unroll
        for (int i = 0; i < 4; i++)
            Bs[kk][rr + 16 * i] = B[(size_t)(bn + rr + 16 * i) * DR + k0 + kk];
        __syncthreads();
#pragma unroll
        for (int k = 0; k < 16; k++) {
            float a[4], bb[4];
#pragma unroll
            for (int i = 0; i < 4; i++) a[i] = As[k][ty * 4 + i];
#pragma unroll
            for (int j = 0; j < 4; j++) bb[j] = Bs[k][tx * 4 + j];
#pragma unroll
            for (int i = 0; i < 4; i++)
#pragma unroll
                for (int j = 0; j < 4; j++)
                    acc[i][j] = fmaf(a[i], bb[j], acc[i][j]);
        }
        __syncthreads();
    }
#pragma unroll
    for (int j = 0; j < 4; j++) {
        int e = bn + tx * 4 + j;
        float bv = bias[e];
        float4 o;
#pragma unroll
        for (int i = 0; i < 4; i++) {
            float v = acc[i][j] + bv;
            v = (v > 20.f) ? v : __logf(1.f + __expf(v));
            (&o.x)[i] = v;
        }
        *(float4*)(outT + (size_t)e * SEQ + bm + ty * 4) = o;
    }
}

// ---------------- fused conv(w=4, causal) + bias + SiLU + transpose -------
__global__ void conv_t(const unsigned short* __restrict__ xi_raw,
                       const float* __restrict__ w, const float* __restrict__ cb,
                       unsigned short* __restrict__ xi2bf, unsigned short* __restrict__ xi2T) {
    __shared__ float tin[67][72];
    __shared__ float tout[64][65];
    int l0 = blockIdx.x * 64, e0 = blockIdx.y * 64;
    int t = threadIdx.x;
    for (int c = t; c < 536; c += 256) {      // 67 rows x 8 chunks of 8
        int r = c >> 3, ke = (c & 7) * 8;
        int l = l0 - 3 + r;
        frag8 v = {0, 0, 0, 0, 0, 0, 0, 0};
        if (l >= 0) v = *(const frag8*)(xi_raw + (size_t)l * DI + e0 + ke);
#pragma unroll
        for (int i = 0; i < 8; i++) tin[r][ke + i] = bf2f((unsigned short)v[i]);
    }
    __syncthreads();
    int e_loc = t & 63;
    int e = e0 + e_loc;
    float4 wv = *(const float4*)(w + e * 4);
    float bias = cb[e];
#pragma unroll 4
    for (int i = 0; i < 16; i++) {
        int l_loc = (t >> 6) + i * 4;
        float acc = bias;
        acc = fmaf(wv.x, tin[l_loc][e_loc], acc);
        acc = fmaf(wv.y, tin[l_loc + 1][e_loc], acc);
        acc = fmaf(wv.z, tin[l_loc + 2][e_loc], acc);
        acc = fmaf(wv.w, tin[l_loc + 3][e_loc], acc);
        float s = acc / (1.f + __expf(-acc));
        tout[l_loc][e_loc] = s;
        xi2bf[(size_t)(l0 + l_loc) * DI + e] = f2bf(s);
    }
    __syncthreads();
    for (int c = t; c < 1024; c += 256) {     // 64 e-rows x 16 l-chunks of 4
        int er = c >> 4, l4 = (c & 15) * 4;
        ushort4 o = { f2bf(tout[l4][er]), f2bf(tout[l4 + 1][er]),
                      f2bf(tout[l4 + 2][er]), f2bf(tout[l4 + 3][er]) };
        *(ushort4*)(xi2T + (size_t)(e0 + er) * SEQ + l0 + l4) = o;
    }
}

// ---------------- generic bf16 transpose: in[R][C] -> out[C][R] -----------
__global__ void transpose_bf(const unsigned short* __restrict__ in,
                             unsigned short* __restrict__ outp, int R, int C) {
    __shared__ unsigned short tile[64][72];
    int r0 = blockIdx.x * 64, c0 = blockIdx.y * 64;
    int t = threadIdx.x;
    for (int c = t; c < 512; c += 256) {
        int r = c >> 3, k = (c & 7) * 8;
        frag8 v = *(const frag8*)(in + (size_t)(r0 + r) * C + c0 + k);
        *(frag8*)(&tile[r][k]) = v;
    }
    __syncthreads();
    for (int c = t; c < 1024; c += 256) {
        int cr = c >> 4, r4 = (c & 15) * 4;
        ushort4 o = { tile[r4][cr], tile[r4 + 1][cr], tile[r4 + 2][cr], tile[r4 + 3][cr] };
        *(ushort4*)(outp + (size_t)(c0 + cr) * R + r0 + r4) = o;
    }
}

// ---------------- Chunked selective scan ----------------------------------
// deltaT fp32 [DI][SEQ]; xi2T/szT bf16 [DI][SEQ]; bci bf16 interleaved
// [SEQ][128] (lane n: one dword = {B_n, C_n}). passA: chunks 0..NCHUNK-2.
__global__ void scan_passA(const float* __restrict__ deltaT, const unsigned short* __restrict__ xi2T,
                           const unsigned short* __restrict__ bci, const float* __restrict__ A_log,
                           float* __restrict__ P, float* __restrict__ hend) {
    int wid = blockIdx.x * 4 + (threadIdx.x >> 6);
    int e = wid & (DI - 1);
    int c = wid >> 10;
    int n = threadIdx.x & 63;
    float Ae2 = -__expf(A_log[e * DS + n]) * LOG2E;   // exp(d*Ae) = exp2(d*Ae2)
    float h = 0.f, sum_d = 0.f;
    int l0 = c * CHUNK;
    const float4* d4  = (const float4*)(deltaT + (size_t)e * SEQ + l0);
    const ushort4* x4 = (const ushort4*)(xi2T + (size_t)e * SEQ + l0);
    const unsigned* bc = (const unsigned*)bci + (size_t)l0 * 64 + n;
#pragma unroll 2
    for (int g = 0; g < CHUNK / 4; g++) {
        float4 dd = d4[g];
        ushort4 xx = x4[g];
#pragma unroll
        for (int j = 0; j < 4; j++) {
            unsigned bcv = bc[g * 256 + j * 64];
            float Bn = __int_as_float(bcv << 16);
            float dj = (&dd.x)[j];
            float xj = bf2f((&xx.x)[j]);
            float dA = fexp2(dj * Ae2);
            h = fmaf(dA, h, (dj * xj) * Bn);
            sum_d += dj;
        }
    }
    int idx = (c * DI + e) * DS + n;
    P[idx] = fexp2(Ae2 * sum_d);
    hend[idx] = h;
}

// Carry: h_in[c] written into P[c] in-place; last slot write-only.
__global__ void scan_carry(float* __restrict__ P, const float* __restrict__ hend) {
    int e = blockIdx.x * 4 + (threadIdx.x >> 6);
    int n = threadIdx.x & 63;
    float h = 0.f;
    for (int c = 0; c < NCHUNK; c++) {
        int idx = (c * DI + e) * DS + n;
        if (c < NCHUNK - 1) {
            float p  = P[idx];
            float he = hend[idx];
            P[idx] = h;
            h = fmaf(p, h, he);
        } else {
            P[idx] = h;
        }
    }
}

// Pass B: 6-DPP wave64 reduce; lane 63 gates and stores bf16 yT in-place.
__global__ void scan_passB(const float* __restrict__ deltaT, const unsigned short* __restrict__ xi2T,
                           const unsigned short* __restrict__ bci, unsigned short* __restrict__ szyT,
                           const float* __restrict__ A_log, const float* __restrict__ Dp,
                           const float* __restrict__ hin) {
    int wid = blockIdx.x * 4 + (threadIdx.x >> 6);
    int e = wid & (DI - 1);
    int c = wid >> 10;
    int n = threadIdx.x & 63;
    float Ae2 = -__expf(A_log[e * DS + n]) * LOG2E;
    float dp = Dp[e];
    float h = hin[(c * DI + e) * DS + n];
    int l0 = c * CHUNK;
    const float4* d4  = (const float4*)(deltaT + (size_t)e * SEQ + l0);
    const ushort4* x4 = (const ushort4*)(xi2T + (size_t)e * SEQ + l0);
    ushort4* s4       = (ushort4*)(szyT + (size_t)e * SEQ + l0);
    const unsigned* bc = (const unsigned*)bci + (size_t)l0 * 64 + n;
#pragma unroll 2
    for (int g = 0; g < CHUNK / 4; g++) {
        float4 dd = d4[g];
        ushort4 xx = x4[g], zz = s4[g];
        ushort4 yv;
#pragma unroll
        for (int j = 0; j < 4; j++) {
            unsigned bcv = bc[g * 256 + j * 64];
            float Bn = __int_as_float(bcv << 16);
            float Cn = __int_as_float(bcv & 0xffff0000u);
            float dj = (&dd.x)[j];
            float xj = bf2f((&xx.x)[j]);
            float dA = fexp2(dj * Ae2);
            h = fmaf(dA, h, (dj * xj) * Bn);
            float p = h * Cn;
            p = dppadd<0xB1>(p);   // quad_perm swap-1
            p = dppadd<0x4E>(p);   // quad_perm swap-2
            p = dppadd<0x141>(p);  // row_half_mirror
            p = dppadd<0x140>(p);  // row_mirror -> 16-lane row sums
            p = dppadd<0x142>(p);  // row_bcast15
            p = dppadd<0x143>(p);  // row_bcast31 -> lane 63 = total
            (&yv.x)[j] = f2bf((p + dp * xj) * bf2f((&zz.x)[j]));
        }
        if (n == 63) s4[g] = yv;
    }
}

extern "C" void kernel_launch(void* const* d_in, const int* in_sizes, int n_in,
                              void* d_out, int out_size, void* d_ws, size_t ws_size,
                              hipStream_t stream) {
    const float* x      = (const float*)d_in[0];
    const float* ln_g   = (const float*)d_in[1];
    const float* ln_b   = (const float*)d_in[2];
    const float* Win    = (const float*)d_in[3];
    const float* conv_w = (const float*)d_in[4];
    const float* conv_b = (const float*)d_in[5];
    const float* Wx     = (const float*)d_in[6];
    const float* Wdt    = (const float*)d_in[7];
    const float* bdt    = (const float*)d_in[8];
    const float* A_log  = (const float*)d_in[9];
    const float* Dp     = (const float*)d_in[10];
    const float* Wout   = (const float*)d_in[11];
    float* out = (float*)d_out;

    // Workspace map (<= 27 MB; 30 MB proven safe):
    char* W = (char*)d_ws;
    unsigned short* xi_raw  = (unsigned short*)W;              // 4 MB (early)
    float*          deltaT  = (float*)W;                       // 8 MB (late, xi_raw dead)
    unsigned short* Win_bf  = (unsigned short*)(W + 8 * MB);   // 2 MB (-> xi2bf -> y_bf)
    unsigned short* xi2bf   = (unsigned short*)(W + 8 * MB);
    unsigned short* y_bf    = (unsigned short*)(W + 8 * MB);
    unsigned short* szT     = (unsigned short*)(W + 12 * MB);  // 4 MB (-> yT in-place)
    unsigned short* xi2T    = (unsigned short*)(W + 16 * MB);  // 4 MB
    unsigned short* xn_bf   = (unsigned short*)(W + 20 * MB);  // 2 MB (-> Pbuf)
    float*          Pbuf    = (float*)(W + 20 * MB);
    unsigned short* Wout_bf = (unsigned short*)(W + 22 * MB);  // 1 MB
    unsigned short* Wx_bf   = (unsigned short*)(W + 23 * MB);  // 0.32 MB
    float*          dtc     = (float*)(W + 23 * MB + 512 * 1024);       // 256 KB
    unsigned short* bci     = (unsigned short*)(W + 23 * MB + 768 * 1024); // 512 KB
    float*          hend    = (float*)(W + 25 * MB);           // 2 MB

    // 1. fused: weights -> bf16 (Win 1,048,576 / Wx 163,840 / Wout 524,288) + LN
    cvt_ln<<<NCVT + SEQ, 256, 0, stream>>>(Win, Win_bf, Wx, Wx_bf, Wout, Wout_bf,
                                           x, ln_g, ln_b, xn_bf);

    // 2. fused in-proj [2048 x 2048 x 512], 128x64 tile (512 blocks = 2/CU):
    //    lower half -> xi_raw bf16, upper half -> silu -> szT bf16 transposed
    gemm_bf<1><<<dim3(SEQ / 128, 2048 / 64), 256, 0, stream>>>(
        xn_bf, DM, Win_bf, DM, 2048, DM, nullptr, nullptr, 0, nullptr, nullptr,
        xi_raw, szT);

    // 3. fused conv + SiLU + transpose -> xi2bf [SEQ][DI] + xi2T [DI][SEQ]
    conv_t<<<dim3(SEQ / 64, DI / 64), 256, 0, stream>>>(xi_raw, conv_w, conv_b, xi2bf, xi2T);

    // 4. x-proj split epilogue: dtc fp32 [SEQ][32] + bci bf16 interleaved [SEQ][128]
    gemm_bf<4><<<dim3(SEQ / 128, 3), 256, 0, stream>>>(
        xi2bf, DI, Wx_bf, DI, 160, DI, nullptr, nullptr, 0, dtc, bci, nullptr, nullptr);

    // 5. deltaT = softplus(dtc @ Wdt^T + bdt)^T  [DI][SEQ] fp32
    gemm_dt_t<<<dim3(SEQ / 64, DI / 64), 256, 0, stream>>>(dtc, Wdt, bdt, deltaT);

    // 6. chunked scan: A (chunks 0..6) -> carry -> B (bf16 yT in-place)
    scan_passA<<<(DI * (NCHUNK - 1)) / 4, 256, 0, stream>>>(deltaT, xi2T, bci, A_log, Pbuf, hend);
    scan_carry<<<DI / 4, 256, 0, stream>>>(Pbuf, hend);
    scan_passB<<<(DI * NCHUNK) / 4, 256, 0, stream>>>(deltaT, xi2T, bci, szT, A_log, Dp, Pbuf);

    // 7. y_bf = yT^T  [SEQ][DI] bf16
    transpose_bf<<<dim3(DI / 64, SEQ / 64), 256, 0, stream>>>(szT, y_bf, DI, SEQ);

    // 8. out = y @ Wout^T + x  fp32
    gemm_bf<2><<<dim3(SEQ / 128, DM / 64), 256, 0, stream>>>(
        y_bf, DI, Wout_bf, DI, DM, DI, out, x, DM, nullptr, nullptr, nullptr, nullptr);
}

// Round 16
// 255.194 us; speedup vs baseline: 2.4357x; 1.1480x over previous
//
#include <hip/hip_runtime.h>
#include <hip/hip_bf16.h>
#include <cstddef>

#define SEQ 2048
#define DM  512
#define DI  1024   // d_inner
#define DR  32     // dt_rank
#define DS  64     // d_state
#define NCHUNK 8
#define CHUNK  256 // SEQ / NCHUNK
#define MB (1024 * 1024)
#define NCVT 1696  // blocks for weight conversion part of cvt_ln

typedef __attribute__((ext_vector_type(4))) float f32x4;
typedef __attribute__((ext_vector_type(8))) short frag8;

// round-to-nearest-even f32 -> bf16 raw bits (finite inputs)
__device__ __forceinline__ unsigned short f2bf(float f) {
    unsigned u = __float_as_uint(f);
    unsigned r = (u + 0x7fffu + ((u >> 16) & 1u)) >> 16;
    return (unsigned short)r;
}
__device__ __forceinline__ float bf2f(unsigned short u) {
    return __int_as_float(((int)u) << 16);
}

// hardware exp2 (v_exp_f32)
__device__ __forceinline__ float fexp2(float x) {
#if __has_builtin(__builtin_amdgcn_exp2f)
    return __builtin_amdgcn_exp2f(x);
#else
    return exp2f(x);
#endif
}
#define LOG2E 1.44269504088896f

// p + dpp_permute(p), compile-time DPP control
template <int CTRL>
__device__ __forceinline__ float dppadd(float p) {
    return p + __int_as_float(
        __builtin_amdgcn_update_dpp(0, __float_as_int(p), CTRL, 0xF, 0xF, true));
}

// ---------------- fused: weights->bf16 (blocks < NCVT) + LayerNorm --------
// Sizes: Win 1,048,576; Wx 163,840; Wout 524,288 -> total 1,736,704 = NCVT*1024.
__global__ void cvt_ln(const float* __restrict__ w1, unsigned short* __restrict__ o1,
                       const float* __restrict__ w2, unsigned short* __restrict__ o2,
                       const float* __restrict__ w3, unsigned short* __restrict__ o3,
                       const float* __restrict__ x, const float* __restrict__ g,
                       const float* __restrict__ b, unsigned short* __restrict__ xn) {
    if (blockIdx.x < NCVT) {
        const int n1 = 1048576, n2 = 163840, n3 = 524288;
        int i = (blockIdx.x * 256 + threadIdx.x) * 4;
        const float* s; unsigned short* d; int off;
        if (i < n1) { s = w1; d = o1; off = i; }
        else if (i < n1 + n2) { s = w2; d = o2; off = i - n1; }
        else if (i < n1 + n2 + n3) { s = w3; d = o3; off = i - n1 - n2; }
        else return;
        float4 v = *(const float4*)(s + off);
        ushort4 o = { f2bf(v.x), f2bf(v.y), f2bf(v.z), f2bf(v.w) };
        *(ushort4*)(d + off) = o;
        return;
    }
    int l = blockIdx.x - NCVT;
    int t = threadIdx.x;
    __shared__ float red[256];
    float v0 = x[l * DM + t];
    float v1 = x[l * DM + t + 256];
    red[t] = v0 + v1;
    __syncthreads();
    for (int o = 128; o > 0; o >>= 1) { if (t < o) red[t] += red[t + o]; __syncthreads(); }
    float mu = red[0] * (1.f / DM);
    __syncthreads();
    float c0 = v0 - mu, c1 = v1 - mu;
    red[t] = c0 * c0 + c1 * c1;
    __syncthreads();
    for (int o = 128; o > 0; o >>= 1) { if (t < o) red[t] += red[t + o]; __syncthreads(); }
    float rstd = rsqrtf(red[0] * (1.f / DM) + 1e-5f);
    xn[l * DM + t]       = f2bf(c0 * rstd * g[t]       + b[t]);
    xn[l * DM + t + 256] = f2bf(c1 * rstd * g[t + 256] + b[t + 256]);
}

#define LDK 40

// ---------------- 128x64 bf16 MFMA GEMM ------------------------------------
// EPI 1: in-proj split (N=2048): n<DI -> bf16 outB1 [M][DI]; n>=DI -> silu ->
//        bf16 transposed outB2 [DI][SEQ].
// EPI 2: fp32 + residual -> outF.
// EPI 4: x-proj split: n<32 -> fp32 dtc [SEQ][32]; 32<=n<96 -> bf16 B at
//        bci[m][2(n-32)]; 96<=n<160 -> bf16 C at bci[m][2(n-96)+1].
template <int EPI>
__global__ __launch_bounds__(256, 2)
void gemm_bf(const unsigned short* __restrict__ A, int lda,
             const unsigned short* __restrict__ B, int ldb,
             int N, int K,
             float* __restrict__ outF, const float* __restrict__ res, int ldo,
             float* __restrict__ dtc, unsigned short* __restrict__ bci,
             unsigned short* __restrict__ outB1, unsigned short* __restrict__ outB2) {
    __shared__ unsigned short As[128 * LDK];
    __shared__ unsigned short Bs[64 * LDK];
    int t = threadIdx.x;
    int lane = t & 63;
    int wv = t >> 6;
    int wm = (wv >> 1) * 64;
    int wn = (wv & 1) * 32;
    int m0 = blockIdx.x * 128, n0 = blockIdx.y * 64;

    f32x4 acc[4][2];
#pragma unroll
    for (int i = 0; i < 4; i++)
#pragma unroll
        for (int j = 0; j < 2; j++) acc[i][j] = (f32x4){0.f, 0.f, 0.f, 0.f};

    int lm = lane & 15;
    int kq = (lane >> 4) * 8;

    for (int k0 = 0; k0 < K; k0 += 32) {
#pragma unroll
        for (int j = 0; j < 2; j++) {
            int c = t + j * 256;
            int m = c >> 2;
            int k = (c & 3) * 8;
            frag8 v = *(const frag8*)(A + (size_t)(m0 + m) * lda + k0 + k);
            *(frag8*)(&As[m * LDK + k]) = v;
        }
        {
            int m = t >> 2;
            int k = (t & 3) * 8;
            int gn = n0 + m;
            frag8 v = {0, 0, 0, 0, 0, 0, 0, 0};
            if (gn < N) v = *(const frag8*)(B + (size_t)gn * ldb + k0 + k);
            *(frag8*)(&Bs[m * LDK + k]) = v;
        }
        __syncthreads();

        frag8 af[4], bfr[2];
#pragma unroll
        for (int mt = 0; mt < 4; mt++)
            af[mt] = *(const frag8*)(&As[(wm + mt * 16 + lm) * LDK + kq]);
#pragma unroll
        for (int nt = 0; nt < 2; nt++)
            bfr[nt] = *(const frag8*)(&Bs[(wn + nt * 16 + lm) * LDK + kq]);
#pragma unroll
        for (int mt = 0; mt < 4; mt++)
#pragma unroll
            for (int nt = 0; nt < 2; nt++)
                acc[mt][nt] = __builtin_amdgcn_mfma_f32_16x16x32_bf16(
                    af[mt], bfr[nt], acc[mt][nt], 0, 0, 0);
        __syncthreads();
    }

    int rbase = (lane >> 4) * 4;
#pragma unroll
    for (int mt = 0; mt < 4; mt++) {
#pragma unroll
        for (int nt = 0; nt < 2; nt++) {
            int n = n0 + wn + nt * 16 + lm;
            int mb = m0 + wm + mt * 16 + rbase;
            if (EPI == 1) {
                if (n < DI) {
#pragma unroll
                    for (int r = 0; r < 4; r++)
                        outB1[(size_t)(mb + r) * DI + n] = f2bf(acc[mt][nt][r]);
                } else {
                    int nn = n - DI;
                    ushort4 o;
#pragma unroll
                    for (int r = 0; r < 4; r++) {
                        float v = acc[mt][nt][r];
                        v = v / (1.f + __expf(-v));
                        (&o.x)[r] = f2bf(v);
                    }
                    *(ushort4*)(outB2 + (size_t)nn * SEQ + mb) = o;
                }
            } else if (EPI == 2) {
                if (n < N) {
#pragma unroll
                    for (int r = 0; r < 4; r++)
                        outF[(size_t)(mb + r) * ldo + n] =
                            acc[mt][nt][r] + res[(size_t)(mb + r) * ldo + n];
                }
            } else { // EPI == 4
                if (n < 32) {
#pragma unroll
                    for (int r = 0; r < 4; r++)
                        dtc[(size_t)(mb + r) * 32 + n] = acc[mt][nt][r];
                } else if (n < 96) {
                    int col = 2 * (n - 32);
#pragma unroll
                    for (int r = 0; r < 4; r++)
                        bci[(size_t)(mb + r) * 128 + col] = f2bf(acc[mt][nt][r]);
                } else if (n < 160) {
                    int col = 2 * (n - 96) + 1;
#pragma unroll
                    for (int r = 0; r < 4; r++)
                        bci[(size_t)(mb + r) * 128 + col] = f2bf(acc[mt][nt][r]);
                }
            }
        }
    }
}

// ---------------- dt-proj vector GEMM, transposed store (fp32) ------------
__global__ void gemm_dt_t(const float* __restrict__ A,   // dtc [SEQ][32]
                          const float* __restrict__ B,   // Wdt [DI][DR]
                          const float* __restrict__ bias,
                          float* __restrict__ outT) {    // deltaT [DI][SEQ]
    __shared__ float As[16][65];
    __shared__ float Bs[16][65];
    int tid = threadIdx.x;
    int tx = tid & 15, ty = tid >> 4;
    int bm = blockIdx.x * 64, bn = blockIdx.y * 64;   // bm: l, bn: e
    float acc[4][4] = {};
    int kk = tid & 15;
    int rr = tid >> 4;
    for (int k0 = 0; k0 < DR; k0 += 16) {
#pragma unroll
        for (int i = 0; i < 4; i++)
            As[kk][rr + 16 * i] = A[(size_t)(bm + rr + 16 * i) * 32 + k0 + kk];
#pragma unroll
        for (int i = 0; i < 4; i++)
            Bs[kk][rr + 16 * i] = B[(size_t)(bn + rr + 16 * i) * DR + k0 + kk];
        __syncthreads();
#pragma unroll
        for (int k = 0; k < 16; k++) {
            float a[4], bb[4];
#pragma unroll
            for (int i = 0; i < 4; i++) a[i] = As[k][ty * 4 + i];
#pragma unroll
            for (int j = 0; j < 4; j++) bb[j] = Bs[k][tx * 4 + j];
#pragma unroll
            for (int i = 0; i < 4; i++)
#pragma unroll
                for (int j = 0; j < 4; j++)
                    acc[i][j] = fmaf(a[i], bb[j], acc[i][j]);
        }
        __syncthreads();
    }
#pragma unroll
    for (int j = 0; j < 4; j++) {
        int e = bn + tx * 4 + j;
        float bv = bias[e];
        float4 o;
#pragma unroll
        for (int i = 0; i < 4; i++) {
            float v = acc[i][j] + bv;
            v = (v > 20.f) ? v : __logf(1.f + __expf(v));
            (&o.x)[i] = v;
        }
        *(float4*)(outT + (size_t)e * SEQ + bm + ty * 4) = o;
    }
}

// ---------------- fused conv(w=4, causal) + bias + SiLU + transpose -------
__global__ void conv_t(const unsigned short* __restrict__ xi_raw,
                       const float* __restrict__ w, const float* __restrict__ cb,
                       unsigned short* __restrict__ xi2bf, unsigned short* __restrict__ xi2T) {
    __shared__ float tin[67][72];
    __shared__ float tout[64][65];
    int l0 = blockIdx.x * 64, e0 = blockIdx.y * 64;
    int t = threadIdx.x;
    for (int c = t; c < 536; c += 256) {      // 67 rows x 8 chunks of 8
        int r = c >> 3, ke = (c & 7) * 8;
        int l = l0 - 3 + r;
        frag8 v = {0, 0, 0, 0, 0, 0, 0, 0};
        if (l >= 0) v = *(const frag8*)(xi_raw + (size_t)l * DI + e0 + ke);
#pragma unroll
        for (int i = 0; i < 8; i++) tin[r][ke + i] = bf2f((unsigned short)v[i]);
    }
    __syncthreads();
    int e_loc = t & 63;
    int e = e0 + e_loc;
    float4 wv = *(const float4*)(w + e * 4);
    float bias = cb[e];
#pragma unroll 4
    for (int i = 0; i < 16; i++) {
        int l_loc = (t >> 6) + i * 4;
        float acc = bias;
        acc = fmaf(wv.x, tin[l_loc][e_loc], acc);
        acc = fmaf(wv.y, tin[l_loc + 1][e_loc], acc);
        acc = fmaf(wv.z, tin[l_loc + 2][e_loc], acc);
        acc = fmaf(wv.w, tin[l_loc + 3][e_loc], acc);
        float s = acc / (1.f + __expf(-acc));
        tout[l_loc][e_loc] = s;
        xi2bf[(size_t)(l0 + l_loc) * DI + e] = f2bf(s);
    }
    __syncthreads();
    for (int c = t; c < 1024; c += 256) {     // 64 e-rows x 16 l-chunks of 4
        int er = c >> 4, l4 = (c & 15) * 4;
        ushort4 o = { f2bf(tout[l4][er]), f2bf(tout[l4 + 1][er]),
                      f2bf(tout[l4 + 2][er]), f2bf(tout[l4 + 3][er]) };
        *(ushort4*)(xi2T + (size_t)(e0 + er) * SEQ + l0 + l4) = o;
    }
}

// ---------------- generic bf16 transpose: in[R][C] -> out[C][R] -----------
__global__ void transpose_bf(const unsigned short* __restrict__ in,
                             unsigned short* __restrict__ outp, int R, int C) {
    __shared__ unsigned short tile[64][72];
    int r0 = blockIdx.x * 64, c0 = blockIdx.y * 64;
    int t = threadIdx.x;
    for (int c = t; c < 512; c += 256) {
        int r = c >> 3, k = (c & 7) * 8;
        frag8 v = *(const frag8*)(in + (size_t)(r0 + r) * C + c0 + k);
        *(frag8*)(&tile[r][k]) = v;
    }
    __syncthreads();
    for (int c = t; c < 1024; c += 256) {
        int cr = c >> 4, r4 = (c & 15) * 4;
        ushort4 o = { tile[r4][cr], tile[r4 + 1][cr], tile[r4 + 2][cr], tile[r4 + 3][cr] };
        *(ushort4*)(outp + (size_t)(c0 + cr) * R + r0 + r4) = o;
    }
}

// ---------------- Chunked selective scan: 4 states/lane x 4 channels/wave --
// Lane (g=lane>>4, i=lane&15) holds states 4i..4i+3 of channel e0+g.
// B/C (bci) are channel-independent: one uint4 load serves all 4 rows.
// deltaT fp32 [DI][SEQ]; xi2T/szT bf16 [DI][SEQ]; bci interleaved [SEQ][64] dw.
// P/hend/hin layout (c*DI+e)*DS+n unchanged (float4 at 4i) -> carry untouched.
__global__ void scan_passA(const float* __restrict__ deltaT, const unsigned short* __restrict__ xi2T,
                           const unsigned short* __restrict__ bci, const float* __restrict__ A_log,
                           float* __restrict__ P, float* __restrict__ hend) {
    int wid = blockIdx.x * 4 + (threadIdx.x >> 6);  // 0..256*(NCHUNK-1)-1
    int eg = wid & 255;        // channel group (DI/4)
    int c  = wid >> 8;         // chunk 0..NCHUNK-2
    int lane = threadIdx.x & 63;
    int g = lane >> 4;         // channel within group
    int i = lane & 15;         // state quad
    int e = eg * 4 + g;
    int l0 = c * CHUNK;
    float4 al = *(const float4*)(A_log + e * DS + 4 * i);
    float Ae2[4];
#pragma unroll
    for (int k = 0; k < 4; k++) Ae2[k] = -__expf((&al.x)[k]) * LOG2E;
    float h[4] = {0.f, 0.f, 0.f, 0.f};
    float sum_d = 0.f;
    const float4* d4  = (const float4*)(deltaT + (size_t)e * SEQ + l0);
    const ushort4* x4 = (const ushort4*)(xi2T + (size_t)e * SEQ + l0);
    const uint4* bc4  = (const uint4*)((const unsigned*)bci + (size_t)l0 * 64) + i;
    for (int gq = 0; gq < CHUNK / 4; gq++) {
        float4 dd = d4[gq];
        ushort4 xx = x4[gq];
#pragma unroll
        for (int j = 0; j < 4; j++) {
            uint4 bcv = bc4[(4 * gq + j) * 16];
            float dj = (&dd.x)[j];
            float dx = dj * bf2f((&xx.x)[j]);
            sum_d += dj;
#pragma unroll
            for (int k = 0; k < 4; k++) {
                float dA = fexp2(dj * Ae2[k]);
                float Bk = __int_as_float((&bcv.x)[k] << 16);
                h[k] = fmaf(dA, h[k], dx * Bk);
            }
        }
    }
    size_t idx = ((size_t)c * DI + e) * DS + 4 * i;
    float4 Pv, hv;
#pragma unroll
    for (int k = 0; k < 4; k++) {
        (&Pv.x)[k] = fexp2(Ae2[k] * sum_d);
        (&hv.x)[k] = h[k];
    }
    *(float4*)(P + idx) = Pv;
    *(float4*)(hend + idx) = hv;
}

// Carry: h_in[c] written into P[c] in-place; last slot write-only.
__global__ void scan_carry(float* __restrict__ P, const float* __restrict__ hend) {
    int e = blockIdx.x * 4 + (threadIdx.x >> 6);
    int n = threadIdx.x & 63;
    float h = 0.f;
    for (int c = 0; c < NCHUNK; c++) {
        int idx = (c * DI + e) * DS + n;
        if (c < NCHUNK - 1) {
            float p  = P[idx];
            float he = hend[idx];
            P[idx] = h;
            h = fmaf(p, h, he);
        } else {
            P[idx] = h;
        }
    }
}

// Pass B: local 4-state fma chain + 4-DPP 16-lane row reduce; lane i==0 of
// each row gates and stores bf16 yT in-place over szT.
__global__ void scan_passB(const float* __restrict__ deltaT, const unsigned short* __restrict__ xi2T,
                           const unsigned short* __restrict__ bci, unsigned short* __restrict__ szyT,
                           const float* __restrict__ A_log, const float* __restrict__ Dp,
                           const float* __restrict__ hin) {
    int wid = blockIdx.x * 4 + (threadIdx.x >> 6);  // 0..256*NCHUNK-1
    int eg = wid & 255;
    int c  = wid >> 8;
    int lane = threadIdx.x & 63;
    int g = lane >> 4;
    int i = lane & 15;
    int e = eg * 4 + g;
    int l0 = c * CHUNK;
    float4 al = *(const float4*)(A_log + e * DS + 4 * i);
    float Ae2[4];
#pragma unroll
    for (int k = 0; k < 4; k++) Ae2[k] = -__expf((&al.x)[k]) * LOG2E;
    float dp = Dp[e];
    float4 hv = *(const float4*)(hin + ((size_t)c * DI + e) * DS + 4 * i);
    float h[4] = {hv.x, hv.y, hv.z, hv.w};
    const float4* d4  = (const float4*)(deltaT + (size_t)e * SEQ + l0);
    const ushort4* x4 = (const ushort4*)(xi2T + (size_t)e * SEQ + l0);
    ushort4* s4       = (ushort4*)(szyT + (size_t)e * SEQ + l0);
    const uint4* bc4  = (const uint4*)((const unsigned*)bci + (size_t)l0 * 64) + i;
    for (int gq = 0; gq < CHUNK / 4; gq++) {
        float4 dd = d4[gq];
        ushort4 xx = x4[gq], zz = s4[gq];
        ushort4 yv;
#pragma unroll
        for (int j = 0; j < 4; j++) {
            uint4 bcv = bc4[(4 * gq + j) * 16];
            float dj = (&dd.x)[j];
            float xj = bf2f((&xx.x)[j]);
            float dx = dj * xj;
            float Ck[4];
#pragma unroll
            for (int k = 0; k < 4; k++) {
                unsigned w = (&bcv.x)[k];
                float Bk = __int_as_float(w << 16);
                Ck[k] = __int_as_float(w & 0xffff0000u);
                float dA = fexp2(dj * Ae2[k]);
                h[k] = fmaf(dA, h[k], dx * Bk);
            }
            float p = h[0] * Ck[0];
            p = fmaf(h[1], Ck[1], p);
            p = fmaf(h[2], Ck[2], p);
            p = fmaf(h[3], Ck[3], p);
            p = dppadd<0xB1>(p);   // quad_perm swap-1
            p = dppadd<0x4E>(p);   // quad_perm swap-2
            p = dppadd<0x141>(p);  // row_half_mirror
            p = dppadd<0x140>(p);  // row_mirror -> 16-lane row sum (all lanes)
            (&yv.x)[j] = f2bf((p + dp * xj) * bf2f((&zz.x)[j]));
        }
        if (i == 0) s4[gq] = yv;
    }
}

extern "C" void kernel_launch(void* const* d_in, const int* in_sizes, int n_in,
                              void* d_out, int out_size, void* d_ws, size_t ws_size,
                              hipStream_t stream) {
    const float* x      = (const float*)d_in[0];
    const float* ln_g   = (const float*)d_in[1];
    const float* ln_b   = (const float*)d_in[2];
    const float* Win    = (const float*)d_in[3];
    const float* conv_w = (const float*)d_in[4];
    const float* conv_b = (const float*)d_in[5];
    const float* Wx     = (const float*)d_in[6];
    const float* Wdt    = (const float*)d_in[7];
    const float* bdt    = (const float*)d_in[8];
    const float* A_log  = (const float*)d_in[9];
    const float* Dp     = (const float*)d_in[10];
    const float* Wout   = (const float*)d_in[11];
    float* out = (float*)d_out;

    // Workspace map (<= 27 MB; 30 MB proven safe):
    char* W = (char*)d_ws;
    unsigned short* xi_raw  = (unsigned short*)W;              // 4 MB (early)
    float*          deltaT  = (float*)W;                       // 8 MB (late, xi_raw dead)
    unsigned short* Win_bf  = (unsigned short*)(W + 8 * MB);   // 2 MB (-> xi2bf -> y_bf)
    unsigned short* xi2bf   = (unsigned short*)(W + 8 * MB);
    unsigned short* y_bf    = (unsigned short*)(W + 8 * MB);
    unsigned short* szT     = (unsigned short*)(W + 12 * MB);  // 4 MB (-> yT in-place)
    unsigned short* xi2T    = (unsigned short*)(W + 16 * MB);  // 4 MB
    unsigned short* xn_bf   = (unsigned short*)(W + 20 * MB);  // 2 MB (-> Pbuf)
    float*          Pbuf    = (float*)(W + 20 * MB);
    unsigned short* Wout_bf = (unsigned short*)(W + 22 * MB);  // 1 MB
    unsigned short* Wx_bf   = (unsigned short*)(W + 23 * MB);  // 0.32 MB
    float*          dtc     = (float*)(W + 23 * MB + 512 * 1024);       // 256 KB
    unsigned short* bci     = (unsigned short*)(W + 23 * MB + 768 * 1024); // 512 KB
    float*          hend    = (float*)(W + 25 * MB);           // 2 MB

    // 1. fused: weights -> bf16 (Win 1,048,576 / Wx 163,840 / Wout 524,288) + LN
    cvt_ln<<<NCVT + SEQ, 256, 0, stream>>>(Win, Win_bf, Wx, Wx_bf, Wout, Wout_bf,
                                           x, ln_g, ln_b, xn_bf);

    // 2. fused in-proj [2048 x 2048 x 512], 128x64 tile (512 blocks = 2/CU):
    //    lower half -> xi_raw bf16, upper half -> silu -> szT bf16 transposed
    gemm_bf<1><<<dim3(SEQ / 128, 2048 / 64), 256, 0, stream>>>(
        xn_bf, DM, Win_bf, DM, 2048, DM, nullptr, nullptr, 0, nullptr, nullptr,
        xi_raw, szT);

    // 3. fused conv + SiLU + transpose -> xi2bf [SEQ][DI] + xi2T [DI][SEQ]
    conv_t<<<dim3(SEQ / 64, DI / 64), 256, 0, stream>>>(xi_raw, conv_w, conv_b, xi2bf, xi2T);

    // 4. x-proj split epilogue: dtc fp32 [SEQ][32] + bci bf16 interleaved [SEQ][128]
    gemm_bf<4><<<dim3(SEQ / 128, 3), 256, 0, stream>>>(
        xi2bf, DI, Wx_bf, DI, 160, DI, nullptr, nullptr, 0, dtc, bci, nullptr, nullptr);

    // 5. deltaT = softplus(dtc @ Wdt^T + bdt)^T  [DI][SEQ] fp32
    gemm_dt_t<<<dim3(SEQ / 64, DI / 64), 256, 0, stream>>>(dtc, Wdt, bdt, deltaT);

    // 6. chunked scan (4 ch/wave): A (chunks 0..6) -> carry -> B (yT in-place)
    scan_passA<<<(DI / 4) * (NCHUNK - 1) / 4, 256, 0, stream>>>(deltaT, xi2T, bci, A_log, Pbuf, hend);
    scan_carry<<<DI / 4, 256, 0, stream>>>(Pbuf, hend);
    scan_passB<<<(DI / 4) * NCHUNK / 4, 256, 0, stream>>>(deltaT, xi2T, bci, szT, A_log, Dp, Pbuf);

    // 7. y_bf = yT^T  [SEQ][DI] bf16
    transpose_bf<<<dim3(DI / 64, SEQ / 64), 256, 0, stream>>>(szT, y_bf, DI, SEQ);

    // 8. out = y @ Wout^T + x  fp32
    gemm_bf<2><<<dim3(SEQ / 128, DM / 64), 256, 0, stream>>>(
        y_bf, DI, Wout_bf, DI, DM, DI, out, x, DM, nullptr, nullptr, nullptr, nullptr);
}

// Round 17
// 244.228 us; speedup vs baseline: 2.5451x; 1.0449x over previous
//
#include <hip/hip_runtime.h>
#include <hip/hip_bf16.h>
#include <cstddef>

#define SEQ 2048
#define DM  512
#define DI  1024   // d_inner
#define DR  32     // dt_rank
#define DS  64     // d_state
#define NCHUNK 16
#define CHUNK  128 // SEQ / NCHUNK
#define MB (1024 * 1024)
#define NCVT 1696  // blocks for weight conversion part of cvt_ln

typedef __attribute__((ext_vector_type(4))) float f32x4;
typedef __attribute__((ext_vector_type(8))) short frag8;

// round-to-nearest-even f32 -> bf16 raw bits (finite inputs)
__device__ __forceinline__ unsigned short f2bf(float f) {
    unsigned u = __float_as_uint(f);
    unsigned r = (u + 0x7fffu + ((u >> 16) & 1u)) >> 16;
    return (unsigned short)r;
}
__device__ __forceinline__ float bf2f(unsigned short u) {
    return __int_as_float(((int)u) << 16);
}

// hardware exp2 (v_exp_f32)
__device__ __forceinline__ float fexp2(float x) {
#if __has_builtin(__builtin_amdgcn_exp2f)
    return __builtin_amdgcn_exp2f(x);
#else
    return exp2f(x);
#endif
}
#define LOG2E 1.44269504088896f

// p + dpp_permute(p), compile-time DPP control
template <int CTRL>
__device__ __forceinline__ float dppadd(float p) {
    return p + __int_as_float(
        __builtin_amdgcn_update_dpp(0, __float_as_int(p), CTRL, 0xF, 0xF, true));
}

// ---------------- fused: weights->bf16 (blocks < NCVT) + LayerNorm --------
// Sizes: Win 1,048,576; Wx 163,840; Wout 524,288 -> total 1,736,704 = NCVT*1024.
__global__ void cvt_ln(const float* __restrict__ w1, unsigned short* __restrict__ o1,
                       const float* __restrict__ w2, unsigned short* __restrict__ o2,
                       const float* __restrict__ w3, unsigned short* __restrict__ o3,
                       const float* __restrict__ x, const float* __restrict__ g,
                       const float* __restrict__ b, unsigned short* __restrict__ xn) {
    if (blockIdx.x < NCVT) {
        const int n1 = 1048576, n2 = 163840, n3 = 524288;
        int i = (blockIdx.x * 256 + threadIdx.x) * 4;
        const float* s; unsigned short* d; int off;
        if (i < n1) { s = w1; d = o1; off = i; }
        else if (i < n1 + n2) { s = w2; d = o2; off = i - n1; }
        else if (i < n1 + n2 + n3) { s = w3; d = o3; off = i - n1 - n2; }
        else return;
        float4 v = *(const float4*)(s + off);
        ushort4 o = { f2bf(v.x), f2bf(v.y), f2bf(v.z), f2bf(v.w) };
        *(ushort4*)(d + off) = o;
        return;
    }
    int l = blockIdx.x - NCVT;
    int t = threadIdx.x;
    __shared__ float red[256];
    float v0 = x[l * DM + t];
    float v1 = x[l * DM + t + 256];
    red[t] = v0 + v1;
    __syncthreads();
    for (int o = 128; o > 0; o >>= 1) { if (t < o) red[t] += red[t + o]; __syncthreads(); }
    float mu = red[0] * (1.f / DM);
    __syncthreads();
    float c0 = v0 - mu, c1 = v1 - mu;
    red[t] = c0 * c0 + c1 * c1;
    __syncthreads();
    for (int o = 128; o > 0; o >>= 1) { if (t < o) red[t] += red[t + o]; __syncthreads(); }
    float rstd = rsqrtf(red[0] * (1.f / DM) + 1e-5f);
    xn[l * DM + t]       = f2bf(c0 * rstd * g[t]       + b[t]);
    xn[l * DM + t + 256] = f2bf(c1 * rstd * g[t + 256] + b[t + 256]);
}

#define LDK 40

// ---------------- 128x64 bf16 MFMA GEMM ------------------------------------
// EPI 1: in-proj split (N=2048): n<DI -> bf16 outB1 [M][DI]; n>=DI -> silu ->
//        bf16 transposed outB2 [DI][SEQ].
// EPI 2: fp32 + residual -> outF.
// EPI 4: x-proj split: n<32 -> fp32 dtc [SEQ][32]; 32<=n<96 -> bf16 B at
//        bci[m][2(n-32)]; 96<=n<160 -> bf16 C at bci[m][2(n-96)+1].
template <int EPI>
__global__ __launch_bounds__(256, 2)
void gemm_bf(const unsigned short* __restrict__ A, int lda,
             const unsigned short* __restrict__ B, int ldb,
             int N, int K,
             float* __restrict__ outF, const float* __restrict__ res, int ldo,
             float* __restrict__ dtc, unsigned short* __restrict__ bci,
             unsigned short* __restrict__ outB1, unsigned short* __restrict__ outB2) {
    __shared__ unsigned short As[128 * LDK];
    __shared__ unsigned short Bs[64 * LDK];
    int t = threadIdx.x;
    int lane = t & 63;
    int wv = t >> 6;
    int wm = (wv >> 1) * 64;
    int wn = (wv & 1) * 32;
    int m0 = blockIdx.x * 128, n0 = blockIdx.y * 64;

    f32x4 acc[4][2];
#pragma unroll
    for (int i = 0; i < 4; i++)
#pragma unroll
        for (int j = 0; j < 2; j++) acc[i][j] = (f32x4){0.f, 0.f, 0.f, 0.f};

    int lm = lane & 15;
    int kq = (lane >> 4) * 8;

    for (int k0 = 0; k0 < K; k0 += 32) {
#pragma unroll
        for (int j = 0; j < 2; j++) {
            int c = t + j * 256;
            int m = c >> 2;
            int k = (c & 3) * 8;
            frag8 v = *(const frag8*)(A + (size_t)(m0 + m) * lda + k0 + k);
            *(frag8*)(&As[m * LDK + k]) = v;
        }
        {
            int m = t >> 2;
            int k = (t & 3) * 8;
            int gn = n0 + m;
            frag8 v = {0, 0, 0, 0, 0, 0, 0, 0};
            if (gn < N) v = *(const frag8*)(B + (size_t)gn * ldb + k0 + k);
            *(frag8*)(&Bs[m * LDK + k]) = v;
        }
        __syncthreads();

        frag8 af[4], bfr[2];
#pragma unroll
        for (int mt = 0; mt < 4; mt++)
            af[mt] = *(const frag8*)(&As[(wm + mt * 16 + lm) * LDK + kq]);
#pragma unroll
        for (int nt = 0; nt < 2; nt++)
            bfr[nt] = *(const frag8*)(&Bs[(wn + nt * 16 + lm) * LDK + kq]);
#pragma unroll
        for (int mt = 0; mt < 4; mt++)
#pragma unroll
            for (int nt = 0; nt < 2; nt++)
                acc[mt][nt] = __builtin_amdgcn_mfma_f32_16x16x32_bf16(
                    af[mt], bfr[nt], acc[mt][nt], 0, 0, 0);
        __syncthreads();
    }

    int rbase = (lane >> 4) * 4;
#pragma unroll
    for (int mt = 0; mt < 4; mt++) {
#pragma unroll
        for (int nt = 0; nt < 2; nt++) {
            int n = n0 + wn + nt * 16 + lm;
            int mb = m0 + wm + mt * 16 + rbase;
            if (EPI == 1) {
                if (n < DI) {
#pragma unroll
                    for (int r = 0; r < 4; r++)
                        outB1[(size_t)(mb + r) * DI + n] = f2bf(acc[mt][nt][r]);
                } else {
                    int nn = n - DI;
                    ushort4 o;
#pragma unroll
                    for (int r = 0; r < 4; r++) {
                        float v = acc[mt][nt][r];
                        v = v / (1.f + __expf(-v));
                        (&o.x)[r] = f2bf(v);
                    }
                    *(ushort4*)(outB2 + (size_t)nn * SEQ + mb) = o;
                }
            } else if (EPI == 2) {
                if (n < N) {
#pragma unroll
                    for (int r = 0; r < 4; r++)
                        outF[(size_t)(mb + r) * ldo + n] =
                            acc[mt][nt][r] + res[(size_t)(mb + r) * ldo + n];
                }
            } else { // EPI == 4
                if (n < 32) {
#pragma unroll
                    for (int r = 0; r < 4; r++)
                        dtc[(size_t)(mb + r) * 32 + n] = acc[mt][nt][r];
                } else if (n < 96) {
                    int col = 2 * (n - 32);
#pragma unroll
                    for (int r = 0; r < 4; r++)
                        bci[(size_t)(mb + r) * 128 + col] = f2bf(acc[mt][nt][r]);
                } else if (n < 160) {
                    int col = 2 * (n - 96) + 1;
#pragma unroll
                    for (int r = 0; r < 4; r++)
                        bci[(size_t)(mb + r) * 128 + col] = f2bf(acc[mt][nt][r]);
                }
            }
        }
    }
}

// ---------------- dt-proj vector GEMM, transposed store (fp32) ------------
__global__ void gemm_dt_t(const float* __restrict__ A,   // dtc [SEQ][32]
                          const float* __restrict__ B,   // Wdt [DI][DR]
                          const float* __restrict__ bias,
                          float* __restrict__ outT) {    // deltaT [DI][SEQ]
    __shared__ float As[16][65];
    __shared__ float Bs[16][65];
    int tid = threadIdx.x;
    int tx = tid & 15, ty = tid >> 4;
    int bm = blockIdx.x * 64, bn = blockIdx.y * 64;   // bm: l, bn: e
    float acc[4][4] = {};
    int kk = tid & 15;
    int rr = tid >> 4;
    for (int k0 = 0; k0 < DR; k0 += 16) {
#pragma unroll
        for (int i = 0; i < 4; i++)
            As[kk][rr + 16 * i] = A[(size_t)(bm + rr + 16 * i) * 32 + k0 + kk];
#pragma unroll
        for (int i = 0; i < 4; i++)
            Bs[kk][rr + 16 * i] = B[(size_t)(bn + rr + 16 * i) * DR + k0 + kk];
        __syncthreads();
#pragma unroll
        for (int k = 0; k < 16; k++) {
            float a[4], bb[4];
#pragma unroll
            for (int i = 0; i < 4; i++) a[i] = As[k][ty * 4 + i];
#pragma unroll
            for (int j = 0; j < 4; j++) bb[j] = Bs[k][tx * 4 + j];
#pragma unroll
            for (int i = 0; i < 4; i++)
#pragma unroll
                for (int j = 0; j < 4; j++)
                    acc[i][j] = fmaf(a[i], bb[j], acc[i][j]);
        }
        __syncthreads();
    }
#pragma unroll
    for (int j = 0; j < 4; j++) {
        int e = bn + tx * 4 + j;
        float bv = bias[e];
        float4 o;
#pragma unroll
        for (int i = 0; i < 4; i++) {
            float v = acc[i][j] + bv;
            v = (v > 20.f) ? v : __logf(1.f + __expf(v));
            (&o.x)[i] = v;
        }
        *(float4*)(outT + (size_t)e * SEQ + bm + ty * 4) = o;
    }
}

// ---------------- fused conv(w=4, causal) + bias + SiLU + transpose -------
__global__ void conv_t(const unsigned short* __restrict__ xi_raw,
                       const float* __restrict__ w, const float* __restrict__ cb,
                       unsigned short* __restrict__ xi2bf, unsigned short* __restrict__ xi2T) {
    __shared__ float tin[67][72];
    __shared__ float tout[64][65];
    int l0 = blockIdx.x * 64, e0 = blockIdx.y * 64;
    int t = threadIdx.x;
    for (int c = t; c < 536; c += 256) {      // 67 rows x 8 chunks of 8
        int r = c >> 3, ke = (c & 7) * 8;
        int l = l0 - 3 + r;
        frag8 v = {0, 0, 0, 0, 0, 0, 0, 0};
        if (l >= 0) v = *(const frag8*)(xi_raw + (size_t)l * DI + e0 + ke);
#pragma unroll
        for (int i = 0; i < 8; i++) tin[r][ke + i] = bf2f((unsigned short)v[i]);
    }
    __syncthreads();
    int e_loc = t & 63;
    int e = e0 + e_loc;
    float4 wv = *(const float4*)(w + e * 4);
    float bias = cb[e];
#pragma unroll 4
    for (int i = 0; i < 16; i++) {
        int l_loc = (t >> 6) + i * 4;
        float acc = bias;
        acc = fmaf(wv.x, tin[l_loc][e_loc], acc);
        acc = fmaf(wv.y, tin[l_loc + 1][e_loc], acc);
        acc = fmaf(wv.z, tin[l_loc + 2][e_loc], acc);
        acc = fmaf(wv.w, tin[l_loc + 3][e_loc], acc);
        float s = acc / (1.f + __expf(-acc));
        tout[l_loc][e_loc] = s;
        xi2bf[(size_t)(l0 + l_loc) * DI + e] = f2bf(s);
    }
    __syncthreads();
    for (int c = t; c < 1024; c += 256) {     // 64 e-rows x 16 l-chunks of 4
        int er = c >> 4, l4 = (c & 15) * 4;
        ushort4 o = { f2bf(tout[l4][er]), f2bf(tout[l4 + 1][er]),
                      f2bf(tout[l4 + 2][er]), f2bf(tout[l4 + 3][er]) };
        *(ushort4*)(xi2T + (size_t)(e0 + er) * SEQ + l0 + l4) = o;
    }
}

// ---------------- generic bf16 transpose: in[R][C] -> out[C][R] -----------
__global__ void transpose_bf(const unsigned short* __restrict__ in,
                             unsigned short* __restrict__ outp, int R, int C) {
    __shared__ unsigned short tile[64][72];
    int r0 = blockIdx.x * 64, c0 = blockIdx.y * 64;
    int t = threadIdx.x;
    for (int c = t; c < 512; c += 256) {
        int r = c >> 3, k = (c & 7) * 8;
        frag8 v = *(const frag8*)(in + (size_t)(r0 + r) * C + c0 + k);
        *(frag8*)(&tile[r][k]) = v;
    }
    __syncthreads();
    for (int c = t; c < 1024; c += 256) {
        int cr = c >> 4, r4 = (c & 15) * 4;
        ushort4 o = { tile[r4][cr], tile[r4 + 1][cr], tile[r4 + 2][cr], tile[r4 + 3][cr] };
        *(ushort4*)(outp + (size_t)(c0 + cr) * R + r0 + r4) = o;
    }
}

// ---------------- Chunked selective scan: 4 states/lane x 4 channels/wave --
// Lane (g=lane>>4, i=lane&15) holds states 4i..4i+3 of channel e0+g.
// B/C (bci) are channel-independent: one uint4 load serves all 4 rows.
// deltaT fp32 [DI][SEQ]; xi2T/szT bf16 [DI][SEQ]; bci interleaved [SEQ][64] dw.
// NCHUNK=16 for occupancy (R16 @8 chunks: 2 waves/SIMD, VALUBusy 55% ->
// latency-bound). passA runs chunks 0..NCHUNK-2.
__global__ void scan_passA(const float* __restrict__ deltaT, const unsigned short* __restrict__ xi2T,
                           const unsigned short* __restrict__ bci, const float* __restrict__ A_log,
                           float* __restrict__ P, float* __restrict__ hend) {
    int wid = blockIdx.x * 4 + (threadIdx.x >> 6);  // 0..256*(NCHUNK-1)-1
    int eg = wid & 255;        // channel group (DI/4)
    int c  = wid >> 8;         // chunk 0..NCHUNK-2
    int lane = threadIdx.x & 63;
    int g = lane >> 4;         // channel within group
    int i = lane & 15;         // state quad
    int e = eg * 4 + g;
    int l0 = c * CHUNK;
    float4 al = *(const float4*)(A_log + e * DS + 4 * i);
    float Ae2[4];
#pragma unroll
    for (int k = 0; k < 4; k++) Ae2[k] = -__expf((&al.x)[k]) * LOG2E;
    float h[4] = {0.f, 0.f, 0.f, 0.f};
    float sum_d = 0.f;
    const float4* d4  = (const float4*)(deltaT + (size_t)e * SEQ + l0);
    const ushort4* x4 = (const ushort4*)(xi2T + (size_t)e * SEQ + l0);
    const uint4* bc4  = (const uint4*)((const unsigned*)bci + (size_t)l0 * 64) + i;
    for (int gq = 0; gq < CHUNK / 4; gq++) {
        float4 dd = d4[gq];
        ushort4 xx = x4[gq];
#pragma unroll
        for (int j = 0; j < 4; j++) {
            uint4 bcv = bc4[(4 * gq + j) * 16];
            float dj = (&dd.x)[j];
            float dx = dj * bf2f((&xx.x)[j]);
            sum_d += dj;
#pragma unroll
            for (int k = 0; k < 4; k++) {
                float dA = fexp2(dj * Ae2[k]);
                float Bk = __int_as_float((&bcv.x)[k] << 16);
                h[k] = fmaf(dA, h[k], dx * Bk);
            }
        }
    }
    size_t idx = ((size_t)c * DI + e) * DS + 4 * i;
    float4 Pv, hv;
#pragma unroll
    for (int k = 0; k < 4; k++) {
        (&Pv.x)[k] = fexp2(Ae2[k] * sum_d);
        (&hv.x)[k] = h[k];
    }
    *(float4*)(P + idx) = Pv;
    *(float4*)(hend + idx) = hv;
}

// Carry: h_in[c] written into P[c] in-place; last slot write-only.
__global__ void scan_carry(float* __restrict__ P, const float* __restrict__ hend) {
    int e = blockIdx.x * 4 + (threadIdx.x >> 6);
    int n = threadIdx.x & 63;
    float h = 0.f;
    for (int c = 0; c < NCHUNK; c++) {
        int idx = (c * DI + e) * DS + n;
        if (c < NCHUNK - 1) {
            float p  = P[idx];
            float he = hend[idx];
            P[idx] = h;
            h = fmaf(p, h, he);
        } else {
            P[idx] = h;
        }
    }
}

// Pass B: local 4-state fma chain + 4-DPP 16-lane row reduce; lane i==0 of
// each row gates and stores bf16 yT in-place over szT.
__global__ void scan_passB(const float* __restrict__ deltaT, const unsigned short* __restrict__ xi2T,
                           const unsigned short* __restrict__ bci, unsigned short* __restrict__ szyT,
                           const float* __restrict__ A_log, const float* __restrict__ Dp,
                           const float* __restrict__ hin) {
    int wid = blockIdx.x * 4 + (threadIdx.x >> 6);  // 0..256*NCHUNK-1
    int eg = wid & 255;
    int c  = wid >> 8;
    int lane = threadIdx.x & 63;
    int g = lane >> 4;
    int i = lane & 15;
    int e = eg * 4 + g;
    int l0 = c * CHUNK;
    float4 al = *(const float4*)(A_log + e * DS + 4 * i);
    float Ae2[4];
#pragma unroll
    for (int k = 0; k < 4; k++) Ae2[k] = -__expf((&al.x)[k]) * LOG2E;
    float dp = Dp[e];
    float4 hv = *(const float4*)(hin + ((size_t)c * DI + e) * DS + 4 * i);
    float h[4] = {hv.x, hv.y, hv.z, hv.w};
    const float4* d4  = (const float4*)(deltaT + (size_t)e * SEQ + l0);
    const ushort4* x4 = (const ushort4*)(xi2T + (size_t)e * SEQ + l0);
    ushort4* s4       = (ushort4*)(szyT + (size_t)e * SEQ + l0);
    const uint4* bc4  = (const uint4*)((const unsigned*)bci + (size_t)l0 * 64) + i;
    for (int gq = 0; gq < CHUNK / 4; gq++) {
        float4 dd = d4[gq];
        ushort4 xx = x4[gq], zz = s4[gq];
        ushort4 yv;
#pragma unroll
        for (int j = 0; j < 4; j++) {
            uint4 bcv = bc4[(4 * gq + j) * 16];
            float dj = (&dd.x)[j];
            float xj = bf2f((&xx.x)[j]);
            float dx = dj * xj;
            float Ck[4];
#pragma unroll
            for (int k = 0; k < 4; k++) {
                unsigned w = (&bcv.x)[k];
                float Bk = __int_as_float(w << 16);
                Ck[k] = __int_as_float(w & 0xffff0000u);
                float dA = fexp2(dj * Ae2[k]);
                h[k] = fmaf(dA, h[k], dx * Bk);
            }
            float p = h[0] * Ck[0];
            p = fmaf(h[1], Ck[1], p);
            p = fmaf(h[2], Ck[2], p);
            p = fmaf(h[3], Ck[3], p);
            p = dppadd<0xB1>(p);   // quad_perm swap-1
            p = dppadd<0x4E>(p);   // quad_perm swap-2
            p = dppadd<0x141>(p);  // row_half_mirror
            p = dppadd<0x140>(p);  // row_mirror -> 16-lane row sum (all lanes)
            (&yv.x)[j] = f2bf((p + dp * xj) * bf2f((&zz.x)[j]));
        }
        if (i == 0) s4[gq] = yv;
    }
}

extern "C" void kernel_launch(void* const* d_in, const int* in_sizes, int n_in,
                              void* d_out, int out_size, void* d_ws, size_t ws_size,
                              hipStream_t stream) {
    const float* x      = (const float*)d_in[0];
    const float* ln_g   = (const float*)d_in[1];
    const float* ln_b   = (const float*)d_in[2];
    const float* Win    = (const float*)d_in[3];
    const float* conv_w = (const float*)d_in[4];
    const float* conv_b = (const float*)d_in[5];
    const float* Wx     = (const float*)d_in[6];
    const float* Wdt    = (const float*)d_in[7];
    const float* bdt    = (const float*)d_in[8];
    const float* A_log  = (const float*)d_in[9];
    const float* Dp     = (const float*)d_in[10];
    const float* Wout   = (const float*)d_in[11];
    float* out = (float*)d_out;

    // Workspace map (28.5 MB total; 30 MB proven safe). NCHUNK=16 doubles
    // P/hend to 4 MB each; Pbuf reuses 8-12 MB (Win_bf/xi2bf dead before the
    // scan, y_bf written only after passB -> strictly stream-ordered).
    char* W = (char*)d_ws;
    unsigned short* xi_raw  = (unsigned short*)W;              // 4 MB (early)
    float*          deltaT  = (float*)W;                       // 8 MB (late, xi_raw dead)
    unsigned short* Win_bf  = (unsigned short*)(W + 8 * MB);   // 2 MB (steps 1-2)
    unsigned short* xi2bf   = (unsigned short*)(W + 8 * MB);   // 4 MB (steps 3-4)
    float*          Pbuf    = (float*)(W + 8 * MB);            // 4 MB (step 6)
    unsigned short* y_bf    = (unsigned short*)(W + 8 * MB);   // 4 MB (steps 7-8)
    unsigned short* szT     = (unsigned short*)(W + 12 * MB);  // 4 MB (-> yT in-place)
    unsigned short* xi2T    = (unsigned short*)(W + 16 * MB);  // 4 MB
    unsigned short* xn_bf   = (unsigned short*)(W + 20 * MB);  // 2 MB (dead after step 2)
    unsigned short* Wout_bf = (unsigned short*)(W + 22 * MB);  // 1 MB
    unsigned short* Wx_bf   = (unsigned short*)(W + 23 * MB);  // 0.32 MB
    float*          dtc     = (float*)(W + 23 * MB + 512 * 1024);       // 256 KB
    unsigned short* bci     = (unsigned short*)(W + 23 * MB + 768 * 1024); // 512 KB
    float*          hend    = (float*)(W + 24 * MB + 512 * 1024);       // 4 MB (24.5-28.5)

    // 1. fused: weights -> bf16 (Win 1,048,576 / Wx 163,840 / Wout 524,288) + LN
    cvt_ln<<<NCVT + SEQ, 256, 0, stream>>>(Win, Win_bf, Wx, Wx_bf, Wout, Wout_bf,
                                           x, ln_g, ln_b, xn_bf);

    // 2. fused in-proj [2048 x 2048 x 512], 128x64 tile (512 blocks = 2/CU):
    //    lower half -> xi_raw bf16, upper half -> silu -> szT bf16 transposed
    gemm_bf<1><<<dim3(SEQ / 128, 2048 / 64), 256, 0, stream>>>(
        xn_bf, DM, Win_bf, DM, 2048, DM, nullptr, nullptr, 0, nullptr, nullptr,
        xi_raw, szT);

    // 3. fused conv + SiLU + transpose -> xi2bf [SEQ][DI] + xi2T [DI][SEQ]
    conv_t<<<dim3(SEQ / 64, DI / 64), 256, 0, stream>>>(xi_raw, conv_w, conv_b, xi2bf, xi2T);

    // 4. x-proj split epilogue: dtc fp32 [SEQ][32] + bci bf16 interleaved [SEQ][128]
    gemm_bf<4><<<dim3(SEQ / 128, 3), 256, 0, stream>>>(
        xi2bf, DI, Wx_bf, DI, 160, DI, nullptr, nullptr, 0, dtc, bci, nullptr, nullptr);

    // 5. deltaT = softplus(dtc @ Wdt^T + bdt)^T  [DI][SEQ] fp32
    gemm_dt_t<<<dim3(SEQ / 64, DI / 64), 256, 0, stream>>>(dtc, Wdt, bdt, deltaT);

    // 6. chunked scan (4 ch/wave, 16 chunks): A (0..14) -> carry -> B (yT in-place)
    scan_passA<<<(DI / 4) * (NCHUNK - 1) / 4, 256, 0, stream>>>(deltaT, xi2T, bci, A_log, Pbuf, hend);
    scan_carry<<<DI / 4, 256, 0, stream>>>(Pbuf, hend);
    scan_passB<<<(DI / 4) * NCHUNK / 4, 256, 0, stream>>>(deltaT, xi2T, bci, szT, A_log, Dp, Pbuf);

    // 7. y_bf = yT^T  [SEQ][DI] bf16
    transpose_bf<<<dim3(DI / 64, SEQ / 64), 256, 0, stream>>>(szT, y_bf, DI, SEQ);

    // 8. out = y @ Wout^T + x  fp32
    gemm_bf<2><<<dim3(SEQ / 128, DM / 64), 256, 0, stream>>>(
        y_bf, DI, Wout_bf, DI, DM, DI, out, x, DM, nullptr, nullptr, nullptr, nullptr);
}

// Round 18
// 235.434 us; speedup vs baseline: 2.6402x; 1.0374x over previous
//
#include <hip/hip_runtime.h>
#include <hip/hip_bf16.h>
#include <cstddef>

#define SEQ 2048
#define DM  512
#define DI  1024   // d_inner
#define DR  32     // dt_rank
#define DS  64     // d_state
#define NCHUNK 32
#define CHUNK  64  // SEQ / NCHUNK
#define MB (1024 * 1024)
#define NCVT 1696  // blocks for weight conversion part of cvt_ln

typedef __attribute__((ext_vector_type(4))) float f32x4;
typedef __attribute__((ext_vector_type(8))) short frag8;

// round-to-nearest-even f32 -> bf16 raw bits (finite inputs)
__device__ __forceinline__ unsigned short f2bf(float f) {
    unsigned u = __float_as_uint(f);
    unsigned r = (u + 0x7fffu + ((u >> 16) & 1u)) >> 16;
    return (unsigned short)r;
}
__device__ __forceinline__ float bf2f(unsigned short u) {
    return __int_as_float(((int)u) << 16);
}

// hardware exp2 (v_exp_f32)
__device__ __forceinline__ float fexp2(float x) {
#if __has_builtin(__builtin_amdgcn_exp2f)
    return __builtin_amdgcn_exp2f(x);
#else
    return exp2f(x);
#endif
}
#define LOG2E 1.44269504088896f

// p + dpp_permute(p), compile-time DPP control
template <int CTRL>
__device__ __forceinline__ float dppadd(float p) {
    return p + __int_as_float(
        __builtin_amdgcn_update_dpp(0, __float_as_int(p), CTRL, 0xF, 0xF, true));
}

// ---------------- fused: weights->bf16 (blocks < NCVT) + LayerNorm --------
// Sizes: Win 1,048,576; Wx 163,840; Wout 524,288 -> total 1,736,704 = NCVT*1024.
__global__ void cvt_ln(const float* __restrict__ w1, unsigned short* __restrict__ o1,
                       const float* __restrict__ w2, unsigned short* __restrict__ o2,
                       const float* __restrict__ w3, unsigned short* __restrict__ o3,
                       const float* __restrict__ x, const float* __restrict__ g,
                       const float* __restrict__ b, unsigned short* __restrict__ xn) {
    if (blockIdx.x < NCVT) {
        const int n1 = 1048576, n2 = 163840, n3 = 524288;
        int i = (blockIdx.x * 256 + threadIdx.x) * 4;
        const float* s; unsigned short* d; int off;
        if (i < n1) { s = w1; d = o1; off = i; }
        else if (i < n1 + n2) { s = w2; d = o2; off = i - n1; }
        else if (i < n1 + n2 + n3) { s = w3; d = o3; off = i - n1 - n2; }
        else return;
        float4 v = *(const float4*)(s + off);
        ushort4 o = { f2bf(v.x), f2bf(v.y), f2bf(v.z), f2bf(v.w) };
        *(ushort4*)(d + off) = o;
        return;
    }
    int l = blockIdx.x - NCVT;
    int t = threadIdx.x;
    __shared__ float red[256];
    float v0 = x[l * DM + t];
    float v1 = x[l * DM + t + 256];
    red[t] = v0 + v1;
    __syncthreads();
    for (int o = 128; o > 0; o >>= 1) { if (t < o) red[t] += red[t + o]; __syncthreads(); }
    float mu = red[0] * (1.f / DM);
    __syncthreads();
    float c0 = v0 - mu, c1 = v1 - mu;
    red[t] = c0 * c0 + c1 * c1;
    __syncthreads();
    for (int o = 128; o > 0; o >>= 1) { if (t < o) red[t] += red[t + o]; __syncthreads(); }
    float rstd = rsqrtf(red[0] * (1.f / DM) + 1e-5f);
    xn[l * DM + t]       = f2bf(c0 * rstd * g[t]       + b[t]);
    xn[l * DM + t + 256] = f2bf(c1 * rstd * g[t + 256] + b[t + 256]);
}

#define LDK 40

// ---------------- 128x64 bf16 MFMA GEMM ------------------------------------
// EPI 1: in-proj split (N=2048): n<DI -> bf16 outB1 [M][DI]; n>=DI -> silu ->
//        bf16 transposed outB2 [DI][SEQ].
// EPI 2: fp32 + residual -> outF.
// EPI 4: x-proj split: n<32 -> fp32 dtc [SEQ][32]; 32<=n<96 -> bf16 B at
//        bci[m][2(n-32)]; 96<=n<160 -> bf16 C at bci[m][2(n-96)+1].
template <int EPI>
__global__ __launch_bounds__(256, 2)
void gemm_bf(const unsigned short* __restrict__ A, int lda,
             const unsigned short* __restrict__ B, int ldb,
             int N, int K,
             float* __restrict__ outF, const float* __restrict__ res, int ldo,
             float* __restrict__ dtc, unsigned short* __restrict__ bci,
             unsigned short* __restrict__ outB1, unsigned short* __restrict__ outB2) {
    __shared__ unsigned short As[128 * LDK];
    __shared__ unsigned short Bs[64 * LDK];
    int t = threadIdx.x;
    int lane = t & 63;
    int wv = t >> 6;
    int wm = (wv >> 1) * 64;
    int wn = (wv & 1) * 32;
    int m0 = blockIdx.x * 128, n0 = blockIdx.y * 64;

    f32x4 acc[4][2];
#pragma unroll
    for (int i = 0; i < 4; i++)
#pragma unroll
        for (int j = 0; j < 2; j++) acc[i][j] = (f32x4){0.f, 0.f, 0.f, 0.f};

    int lm = lane & 15;
    int kq = (lane >> 4) * 8;

    for (int k0 = 0; k0 < K; k0 += 32) {
#pragma unroll
        for (int j = 0; j < 2; j++) {
            int c = t + j * 256;
            int m = c >> 2;
            int k = (c & 3) * 8;
            frag8 v = *(const frag8*)(A + (size_t)(m0 + m) * lda + k0 + k);
            *(frag8*)(&As[m * LDK + k]) = v;
        }
        {
            int m = t >> 2;
            int k = (t & 3) * 8;
            int gn = n0 + m;
            frag8 v = {0, 0, 0, 0, 0, 0, 0, 0};
            if (gn < N) v = *(const frag8*)(B + (size_t)gn * ldb + k0 + k);
            *(frag8*)(&Bs[m * LDK + k]) = v;
        }
        __syncthreads();

        frag8 af[4], bfr[2];
#pragma unroll
        for (int mt = 0; mt < 4; mt++)
            af[mt] = *(const frag8*)(&As[(wm + mt * 16 + lm) * LDK + kq]);
#pragma unroll
        for (int nt = 0; nt < 2; nt++)
            bfr[nt] = *(const frag8*)(&Bs[(wn + nt * 16 + lm) * LDK + kq]);
#pragma unroll
        for (int mt = 0; mt < 4; mt++)
#pragma unroll
            for (int nt = 0; nt < 2; nt++)
                acc[mt][nt] = __builtin_amdgcn_mfma_f32_16x16x32_bf16(
                    af[mt], bfr[nt], acc[mt][nt], 0, 0, 0);
        __syncthreads();
    }

    int rbase = (lane >> 4) * 4;
#pragma unroll
    for (int mt = 0; mt < 4; mt++) {
#pragma unroll
        for (int nt = 0; nt < 2; nt++) {
            int n = n0 + wn + nt * 16 + lm;
            int mb = m0 + wm + mt * 16 + rbase;
            if (EPI == 1) {
                if (n < DI) {
#pragma unroll
                    for (int r = 0; r < 4; r++)
                        outB1[(size_t)(mb + r) * DI + n] = f2bf(acc[mt][nt][r]);
                } else {
                    int nn = n - DI;
                    ushort4 o;
#pragma unroll
                    for (int r = 0; r < 4; r++) {
                        float v = acc[mt][nt][r];
                        v = v / (1.f + __expf(-v));
                        (&o.x)[r] = f2bf(v);
                    }
                    *(ushort4*)(outB2 + (size_t)nn * SEQ + mb) = o;
                }
            } else if (EPI == 2) {
                if (n < N) {
#pragma unroll
                    for (int r = 0; r < 4; r++)
                        outF[(size_t)(mb + r) * ldo + n] =
                            acc[mt][nt][r] + res[(size_t)(mb + r) * ldo + n];
                }
            } else { // EPI == 4
                if (n < 32) {
#pragma unroll
                    for (int r = 0; r < 4; r++)
                        dtc[(size_t)(mb + r) * 32 + n] = acc[mt][nt][r];
                } else if (n < 96) {
                    int col = 2 * (n - 32);
#pragma unroll
                    for (int r = 0; r < 4; r++)
                        bci[(size_t)(mb + r) * 128 + col] = f2bf(acc[mt][nt][r]);
                } else if (n < 160) {
                    int col = 2 * (n - 96) + 1;
#pragma unroll
                    for (int r = 0; r < 4; r++)
                        bci[(size_t)(mb + r) * 128 + col] = f2bf(acc[mt][nt][r]);
                }
            }
        }
    }
}

// ---------------- dt-proj vector GEMM, transposed store (fp32) ------------
__global__ void gemm_dt_t(const float* __restrict__ A,   // dtc [SEQ][32]
                          const float* __restrict__ B,   // Wdt [DI][DR]
                          const float* __restrict__ bias,
                          float* __restrict__ outT) {    // deltaT [DI][SEQ]
    __shared__ float As[16][65];
    __shared__ float Bs[16][65];
    int tid = threadIdx.x;
    int tx = tid & 15, ty = tid >> 4;
    int bm = blockIdx.x * 64, bn = blockIdx.y * 64;   // bm: l, bn: e
    float acc[4][4] = {};
    int kk = tid & 15;
    int rr = tid >> 4;
    for (int k0 = 0; k0 < DR; k0 += 16) {
#pragma unroll
        for (int i = 0; i < 4; i++)
            As[kk][rr + 16 * i] = A[(size_t)(bm + rr + 16 * i) * 32 + k0 + kk];
#pragma unroll
        for (int i = 0; i < 4; i++)
            Bs[kk][rr + 16 * i] = B[(size_t)(bn + rr + 16 * i) * DR + k0 + kk];
        __syncthreads();
#pragma unroll
        for (int k = 0; k < 16; k++) {
            float a[4], bb[4];
#pragma unroll
            for (int i = 0; i < 4; i++) a[i] = As[k][ty * 4 + i];
#pragma unroll
            for (int j = 0; j < 4; j++) bb[j] = Bs[k][tx * 4 + j];
#pragma unroll
            for (int i = 0; i < 4; i++)
#pragma unroll
                for (int j = 0; j < 4; j++)
                    acc[i][j] = fmaf(a[i], bb[j], acc[i][j]);
        }
        __syncthreads();
    }
#pragma unroll
    for (int j = 0; j < 4; j++) {
        int e = bn + tx * 4 + j;
        float bv = bias[e];
        float4 o;
#pragma unroll
        for (int i = 0; i < 4; i++) {
            float v = acc[i][j] + bv;
            v = (v > 20.f) ? v : __logf(1.f + __expf(v));
            (&o.x)[i] = v;
        }
        *(float4*)(outT + (size_t)e * SEQ + bm + ty * 4) = o;
    }
}

// ---------------- fused conv(w=4, causal) + bias + SiLU + transpose -------
__global__ void conv_t(const unsigned short* __restrict__ xi_raw,
                       const float* __restrict__ w, const float* __restrict__ cb,
                       unsigned short* __restrict__ xi2bf, unsigned short* __restrict__ xi2T) {
    __shared__ float tin[67][72];
    __shared__ float tout[64][65];
    int l0 = blockIdx.x * 64, e0 = blockIdx.y * 64;
    int t = threadIdx.x;
    for (int c = t; c < 536; c += 256) {      // 67 rows x 8 chunks of 8
        int r = c >> 3, ke = (c & 7) * 8;
        int l = l0 - 3 + r;
        frag8 v = {0, 0, 0, 0, 0, 0, 0, 0};
        if (l >= 0) v = *(const frag8*)(xi_raw + (size_t)l * DI + e0 + ke);
#pragma unroll
        for (int i = 0; i < 8; i++) tin[r][ke + i] = bf2f((unsigned short)v[i]);
    }
    __syncthreads();
    int e_loc = t & 63;
    int e = e0 + e_loc;
    float4 wv = *(const float4*)(w + e * 4);
    float bias = cb[e];
#pragma unroll 4
    for (int i = 0; i < 16; i++) {
        int l_loc = (t >> 6) + i * 4;
        float acc = bias;
        acc = fmaf(wv.x, tin[l_loc][e_loc], acc);
        acc = fmaf(wv.y, tin[l_loc + 1][e_loc], acc);
        acc = fmaf(wv.z, tin[l_loc + 2][e_loc], acc);
        acc = fmaf(wv.w, tin[l_loc + 3][e_loc], acc);
        float s = acc / (1.f + __expf(-acc));
        tout[l_loc][e_loc] = s;
        xi2bf[(size_t)(l0 + l_loc) * DI + e] = f2bf(s);
    }
    __syncthreads();
    for (int c = t; c < 1024; c += 256) {     // 64 e-rows x 16 l-chunks of 4
        int er = c >> 4, l4 = (c & 15) * 4;
        ushort4 o = { f2bf(tout[l4][er]), f2bf(tout[l4 + 1][er]),
                      f2bf(tout[l4 + 2][er]), f2bf(tout[l4 + 3][er]) };
        *(ushort4*)(xi2T + (size_t)(e0 + er) * SEQ + l0 + l4) = o;
    }
}

// ---------------- Chunked selective scan: 4 states/lane x 4 channels/wave --
// Lane (g=lane>>4, i=lane&15) holds states 4i..4i+3 of channel e0+g.
// NCHUNK=32 (8 waves/SIMD). P is never stored: passA emits per-channel sum_d
// (128 KB) + fp32 hend; carry recomputes P=exp2(Ae2*sum_d) on the fly and
// writes h_in in-place over hend. passA runs chunks 0..NCHUNK-2.
__global__ void scan_passA(const float* __restrict__ deltaT, const unsigned short* __restrict__ xi2T,
                           const unsigned short* __restrict__ bci, const float* __restrict__ A_log,
                           float* __restrict__ sumd, float* __restrict__ hend) {
    int wid = blockIdx.x * 4 + (threadIdx.x >> 6);
    int eg = wid & 255;        // channel group (DI/4)
    int c  = wid >> 8;         // chunk 0..NCHUNK-2
    int lane = threadIdx.x & 63;
    int g = lane >> 4;         // channel within group
    int i = lane & 15;         // state quad
    int e = eg * 4 + g;
    int l0 = c * CHUNK;
    float4 al = *(const float4*)(A_log + e * DS + 4 * i);
    float Ae2[4];
#pragma unroll
    for (int k = 0; k < 4; k++) Ae2[k] = -__expf((&al.x)[k]) * LOG2E;
    float h[4] = {0.f, 0.f, 0.f, 0.f};
    float sum_d = 0.f;
    const float4* d4  = (const float4*)(deltaT + (size_t)e * SEQ + l0);
    const ushort4* x4 = (const ushort4*)(xi2T + (size_t)e * SEQ + l0);
    const uint4* bc4  = (const uint4*)((const unsigned*)bci + (size_t)l0 * 64) + i;
    for (int gq = 0; gq < CHUNK / 4; gq++) {
        float4 dd = d4[gq];
        ushort4 xx = x4[gq];
#pragma unroll
        for (int j = 0; j < 4; j++) {
            uint4 bcv = bc4[(4 * gq + j) * 16];
            float dj = (&dd.x)[j];
            float dx = dj * bf2f((&xx.x)[j]);
            sum_d += dj;
#pragma unroll
            for (int k = 0; k < 4; k++) {
                float dA = fexp2(dj * Ae2[k]);
                float Bk = __int_as_float((&bcv.x)[k] << 16);
                h[k] = fmaf(dA, h[k], dx * Bk);
            }
        }
    }
    size_t idx = ((size_t)c * DI + e) * DS + 4 * i;
    float4 hv = {h[0], h[1], h[2], h[3]};
    *(float4*)(hend + idx) = hv;
    if (i == 0) sumd[c * DI + e] = sum_d;
}

// Carry: recompute P = exp2(Ae2*sum_d); h_in written over hend in-place.
// Last slot write-only (passA never produced chunk NCHUNK-1).
__global__ void scan_carry(float* __restrict__ hend, const float* __restrict__ sumd,
                           const float* __restrict__ A_log) {
    int e = blockIdx.x * 4 + (threadIdx.x >> 6);
    int n = threadIdx.x & 63;
    float Ae2 = -__expf(A_log[e * DS + n]) * LOG2E;
    float h = 0.f;
    for (int c = 0; c < NCHUNK; c++) {
        size_t idx = ((size_t)c * DI + e) * DS + n;
        if (c < NCHUNK - 1) {
            float he = hend[idx];
            float P = fexp2(Ae2 * sumd[c * DI + e]);
            hend[idx] = h;
            h = fmaf(P, h, he);
        } else {
            hend[idx] = h;
        }
    }
}

// Pass B: local 4-state fma chain + 4-DPP 16-lane row reduce; lane i==0 of
// each row gates with silu(z) (szT read-only) and stores y DIRECTLY to
// y_bf [SEQ][DI] (4 adjacent-e b16 stores per row) — no transpose kernel.
__global__ void scan_passB(const float* __restrict__ deltaT, const unsigned short* __restrict__ xi2T,
                           const unsigned short* __restrict__ bci, const unsigned short* __restrict__ szT,
                           const float* __restrict__ A_log, const float* __restrict__ Dp,
                           const float* __restrict__ hin, unsigned short* __restrict__ y_bf) {
    int wid = blockIdx.x * 4 + (threadIdx.x >> 6);
    int eg = wid & 255;
    int c  = wid >> 8;
    int lane = threadIdx.x & 63;
    int g = lane >> 4;
    int i = lane & 15;
    int e = eg * 4 + g;
    int l0 = c * CHUNK;
    float4 al = *(const float4*)(A_log + e * DS + 4 * i);
    float Ae2[4];
#pragma unroll
    for (int k = 0; k < 4; k++) Ae2[k] = -__expf((&al.x)[k]) * LOG2E;
    float dp = Dp[e];
    float4 hv = *(const float4*)(hin + ((size_t)c * DI + e) * DS + 4 * i);
    float h[4] = {hv.x, hv.y, hv.z, hv.w};
    const float4* d4  = (const float4*)(deltaT + (size_t)e * SEQ + l0);
    const ushort4* x4 = (const ushort4*)(xi2T + (size_t)e * SEQ + l0);
    const ushort4* s4 = (const ushort4*)(szT + (size_t)e * SEQ + l0);
    const uint4* bc4  = (const uint4*)((const unsigned*)bci + (size_t)l0 * 64) + i;
    for (int gq = 0; gq < CHUNK / 4; gq++) {
        float4 dd = d4[gq];
        ushort4 xx = x4[gq], zz = s4[gq];
        ushort4 yv;
#pragma unroll
        for (int j = 0; j < 4; j++) {
            uint4 bcv = bc4[(4 * gq + j) * 16];
            float dj = (&dd.x)[j];
            float xj = bf2f((&xx.x)[j]);
            float dx = dj * xj;
            float Ck[4];
#pragma unroll
            for (int k = 0; k < 4; k++) {
                unsigned w = (&bcv.x)[k];
                float Bk = __int_as_float(w << 16);
                Ck[k] = __int_as_float(w & 0xffff0000u);
                float dA = fexp2(dj * Ae2[k]);
                h[k] = fmaf(dA, h[k], dx * Bk);
            }
            float p = h[0] * Ck[0];
            p = fmaf(h[1], Ck[1], p);
            p = fmaf(h[2], Ck[2], p);
            p = fmaf(h[3], Ck[3], p);
            p = dppadd<0xB1>(p);   // quad_perm swap-1
            p = dppadd<0x4E>(p);   // quad_perm swap-2
            p = dppadd<0x141>(p);  // row_half_mirror
            p = dppadd<0x140>(p);  // row_mirror -> 16-lane row sum (all lanes)
            (&yv.x)[j] = f2bf((p + dp * xj) * bf2f((&zz.x)[j]));
        }
        if (i == 0) {
#pragma unroll
            for (int j = 0; j < 4; j++)
                y_bf[(size_t)(l0 + 4 * gq + j) * DI + e] = (&yv.x)[j];
        }
    }
}

extern "C" void kernel_launch(void* const* d_in, const int* in_sizes, int n_in,
                              void* d_out, int out_size, void* d_ws, size_t ws_size,
                              hipStream_t stream) {
    const float* x      = (const float*)d_in[0];
    const float* ln_g   = (const float*)d_in[1];
    const float* ln_b   = (const float*)d_in[2];
    const float* Win    = (const float*)d_in[3];
    const float* conv_w = (const float*)d_in[4];
    const float* conv_b = (const float*)d_in[5];
    const float* Wx     = (const float*)d_in[6];
    const float* Wdt    = (const float*)d_in[7];
    const float* bdt    = (const float*)d_in[8];
    const float* A_log  = (const float*)d_in[9];
    const float* Dp     = (const float*)d_in[10];
    const float* Wout   = (const float*)d_in[11];
    float* out = (float*)d_out;

    // Workspace map (30.2 MB peak; 31.5 MB proven safe). Lifetimes:
    //  0- 8: xi_raw (steps 2-3) -> deltaT (5-8)
    //  8-12: Win_bf (1-2) -> xi2bf (3-4) -> y_bf (8-9)   [stream-ordered]
    // 12-16: szT (2-8, read-only in passB)
    // 16-20: xi2T (3-8)
    // 20-28: xn_bf (1-2) -> hend/h_in fp32 [NCHUNK][DI][DS] (6-8)
    // 28-29: Wout_bf (1-9)
    // 29+  : sumd 128K | Wx_bf 320K | dtc 256K | bci 512K
    char* W = (char*)d_ws;
    unsigned short* xi_raw  = (unsigned short*)W;
    float*          deltaT  = (float*)W;
    unsigned short* Win_bf  = (unsigned short*)(W + 8 * MB);
    unsigned short* xi2bf   = (unsigned short*)(W + 8 * MB);
    unsigned short* y_bf    = (unsigned short*)(W + 8 * MB);
    unsigned short* szT     = (unsigned short*)(W + 12 * MB);
    unsigned short* xi2T    = (unsigned short*)(W + 16 * MB);
    unsigned short* xn_bf   = (unsigned short*)(W + 20 * MB);
    float*          hend    = (float*)(W + 20 * MB);
    unsigned short* Wout_bf = (unsigned short*)(W + 28 * MB);
    float*          sumd    = (float*)(W + 29 * MB);
    unsigned short* Wx_bf   = (unsigned short*)(W + 29 * MB + 128 * 1024);
    float*          dtc     = (float*)(W + 29 * MB + 448 * 1024);
    unsigned short* bci     = (unsigned short*)(W + 29 * MB + 704 * 1024);

    // 1. fused: weights -> bf16 (Win 1,048,576 / Wx 163,840 / Wout 524,288) + LN
    cvt_ln<<<NCVT + SEQ, 256, 0, stream>>>(Win, Win_bf, Wx, Wx_bf, Wout, Wout_bf,
                                           x, ln_g, ln_b, xn_bf);

    // 2. fused in-proj [2048 x 2048 x 512], 128x64 tile (512 blocks = 2/CU):
    //    lower half -> xi_raw bf16, upper half -> silu -> szT bf16 transposed
    gemm_bf<1><<<dim3(SEQ / 128, 2048 / 64), 256, 0, stream>>>(
        xn_bf, DM, Win_bf, DM, 2048, DM, nullptr, nullptr, 0, nullptr, nullptr,
        xi_raw, szT);

    // 3. fused conv + SiLU + transpose -> xi2bf [SEQ][DI] + xi2T [DI][SEQ]
    conv_t<<<dim3(SEQ / 64, DI / 64), 256, 0, stream>>>(xi_raw, conv_w, conv_b, xi2bf, xi2T);

    // 4. x-proj split epilogue: dtc fp32 [SEQ][32] + bci bf16 interleaved [SEQ][128]
    gemm_bf<4><<<dim3(SEQ / 128, 3), 256, 0, stream>>>(
        xi2bf, DI, Wx_bf, DI, 160, DI, nullptr, nullptr, 0, dtc, bci, nullptr, nullptr);

    // 5. deltaT = softplus(dtc @ Wdt^T + bdt)^T  [DI][SEQ] fp32
    gemm_dt_t<<<dim3(SEQ / 64, DI / 64), 256, 0, stream>>>(dtc, Wdt, bdt, deltaT);

    // 6. chunked scan (4 ch/wave, 32 chunks): A (0..30) -> carry -> B
    scan_passA<<<(DI / 4) * (NCHUNK - 1) / 4, 256, 0, stream>>>(deltaT, xi2T, bci, A_log, sumd, hend);
    scan_carry<<<DI / 4, 256, 0, stream>>>(hend, sumd, A_log);
    scan_passB<<<(DI / 4) * NCHUNK / 4, 256, 0, stream>>>(deltaT, xi2T, bci, szT,
                                                          A_log, Dp, hend, y_bf);

    // 7. out = y @ Wout^T + x  fp32  (y_bf written directly by passB)
    gemm_bf<2><<<dim3(SEQ / 128, DM / 64), 256, 0, stream>>>(
        y_bf, DI, Wout_bf, DI, DM, DI, out, x, DM, nullptr, nullptr, nullptr, nullptr);
}